// Round 1
// baseline (2716.424 us; speedup 1.0000x reference)
//
#include <hip/hip_runtime.h>
#include <math.h>

#define N_NODES 20000
#define N_EDGES 320000
#define N_GRAPHS 256
#define HID 128
#define NLAYERS 4
#define AVG_LOG 2.833213344056216f
#define EPS 1e-5f

static __device__ __forceinline__ float leaky(float v){ return v > 0.f ? v : 0.01f*v; }

// ---------------- CSR build ----------------
__global__ void k_count(const int* __restrict__ dst, int* __restrict__ deg){
  int e = blockIdx.x*blockDim.x + threadIdx.x;
  if (e < N_EDGES) atomicAdd(&deg[dst[e]], 1);
}

__global__ void k_scan(const int* __restrict__ deg, int* __restrict__ off){
  __shared__ int buf[1024];
  int tid = threadIdx.x;
  int carry = 0;
  for (int base = 0; base < N_NODES; base += 1024){
    int i = base + tid;
    int v = (i < N_NODES) ? deg[i] : 0;
    buf[tid] = v;
    __syncthreads();
    for (int ofs = 1; ofs < 1024; ofs <<= 1){
      int tadd = (tid >= ofs) ? buf[tid-ofs] : 0;
      __syncthreads();
      buf[tid] += tadd;
      __syncthreads();
    }
    if (i < N_NODES) off[i] = carry + buf[tid] - v;  // exclusive
    carry += buf[1023];
    __syncthreads();
  }
  if (tid == 0) off[N_NODES] = carry;
}

__global__ void k_fill(const int* __restrict__ src, const int* __restrict__ dst,
                       const int* __restrict__ eattr, const int* __restrict__ off,
                       int* __restrict__ cursor,
                       int* __restrict__ dstS, int* __restrict__ srcS, int* __restrict__ eaS){
  int e = blockIdx.x*blockDim.x + threadIdx.x;
  if (e < N_EDGES){
    int d = dst[e];
    int pos = off[d] + atomicAdd(&cursor[d], 1);
    dstS[pos] = d; srcS[pos] = src[e]; eaS[pos] = eattr[e];
  }
}

__global__ void k_scalars(const int* __restrict__ deg, float* __restrict__ invd,
                          float* __restrict__ amp, float* __restrict__ att){
  int n = blockIdx.x*blockDim.x + threadIdx.x;
  if (n < N_NODES){
    float d = (float)deg[n];
    invd[n] = 1.f / fmaxf(d, 1.f);
    float ld = log1pf(d);
    amp[n] = ld / AVG_LOG;
    att[n] = AVG_LOG / fmaxf(ld, EPS);
  }
}

__global__ void k_hinit(const int* __restrict__ x, const float* __restrict__ atom_emb,
                        float* __restrict__ h){
  int idx = blockIdx.x*blockDim.x + threadIdx.x;
  if (idx < N_NODES*32){
    int n = idx >> 5, q = idx & 31;
    ((float4*)h)[(size_t)n*32 + q] = ((const float4*)atom_emb)[(size_t)x[n]*32 + q];
  }
}

// ---------------- fused tiled GEMM ----------------
// MODE 0: pretrans  A[e,k] = concat(h[dst], h[src], bond[ea])   K=384, M=E
// MODE 1: posttrans A[n,k] = concat(h, agg, agg*amp, agg*att)   K=1664, M=N
// MODE 2: mix       A[n,k] = ph[n,k]                            K=128, M=N
// BM=128 rows, BN=128 cols, BK=32, 256 threads, 8x8 per-thread tile.
template<int MODE>
__global__ __launch_bounds__(256) void k_gemm(
    const float* __restrict__ W, const float* __restrict__ bias,
    const float* __restrict__ hA, const float* __restrict__ agg,
    const float* __restrict__ amp, const float* __restrict__ att,
    const int* __restrict__ dstS, const int* __restrict__ srcS, const int* __restrict__ eaS,
    const float* __restrict__ bond, const float* __restrict__ snorm,
    float* __restrict__ out)
{
  const int K = (MODE==0) ? 384 : ((MODE==1) ? 1664 : 128);
  __shared__ float As[32][128];
  __shared__ float Bs[32][128];
  int tid = threadIdx.x;
  int tx = tid & 15, ty = tid >> 4;
  int mbase = blockIdx.x * 128;

  // loader assignment: each thread stages 16 consecutive k for one row
  int lr  = tid & 127;
  int lkh = tid >> 7;       // 0/1
  int grow = mbase + lr;
  int nrow = grow;
  if (MODE != 0) nrow = min(grow, N_NODES-1);

  int e_dst=0, e_src=0, e_ea=0; float ampv=0.f, attv=0.f;
  if (MODE == 0){ e_dst = dstS[grow]; e_src = srcS[grow]; e_ea = eaS[grow]; }
  if (MODE == 1){ ampv = amp[nrow]; attv = att[nrow]; }

  float acc[8][8];
  #pragma unroll
  for (int i=0;i<8;++i){
    #pragma unroll
    for (int j=0;j<8;++j) acc[i][j]=0.f;
  }

  for (int kt = 0; kt < K; kt += 32){
    // stage B (flat copy of 32x128 chunk of W)
    {
      const float4* bsrc = (const float4*)(W + (size_t)kt*128);
      float4* bdst = (float4*)(&Bs[0][0]);
      #pragma unroll
      for (int i=0;i<4;++i) bdst[tid + 256*i] = bsrc[tid + 256*i];
    }
    // stage A (transposed, built on the fly)
    {
      int k0 = kt + lkh*16;
      const float* srcp; float scale = 1.f;
      if (MODE == 0){
        if (k0 < 128)      srcp = hA + (size_t)e_dst*HID + k0;
        else if (k0 < 256) srcp = hA + (size_t)e_src*HID + (k0-128);
        else               srcp = bond + (size_t)e_ea*HID + (k0-256);
      } else if (MODE == 1){
        if (k0 < 128)       srcp = hA  + (size_t)nrow*HID + k0;
        else if (k0 < 640)  srcp = agg + (size_t)nrow*512 + (k0-128);
        else if (k0 < 1152){ srcp = agg + (size_t)nrow*512 + (k0-640);  scale = ampv; }
        else               { srcp = agg + (size_t)nrow*512 + (k0-1152); scale = attv; }
      } else {
        srcp = hA + (size_t)nrow*HID + k0;
      }
      float4 f[4];
      #pragma unroll
      for (int i=0;i<4;++i) f[i] = ((const float4*)srcp)[i];
      #pragma unroll
      for (int j=0;j<16;++j){
        As[lkh*16 + j][lr] = ((const float*)f)[j] * scale;
      }
    }
    __syncthreads();
    #pragma unroll
    for (int k=0;k<32;++k){
      float a[8], b[8];
      *(float4*)&a[0] = *(const float4*)&As[k][ty*8];
      *(float4*)&a[4] = *(const float4*)&As[k][ty*8+4];
      *(float4*)&b[0] = *(const float4*)&Bs[k][tx*4];
      *(float4*)&b[4] = *(const float4*)&Bs[k][64 + tx*4];
      #pragma unroll
      for (int i=0;i<8;++i){
        #pragma unroll
        for (int j=0;j<8;++j) acc[i][j] = fmaf(a[i], b[j], acc[i][j]);
      }
    }
    __syncthreads();
  }

  // epilogue: bias + leaky (+snorm for MODE 2), columns tx*4..+3 and 64+tx*4..+3
  float bj[8];
  #pragma unroll
  for (int j=0;j<4;++j){ bj[j] = bias[tx*4+j]; bj[4+j] = bias[64+tx*4+j]; }
  #pragma unroll
  for (int i=0;i<8;++i){
    int row = mbase + ty*8 + i;
    if (MODE == 0 || row < N_NODES){
      float sn = 1.f;
      if (MODE == 2) sn = snorm[row];
      float tmp[8];
      #pragma unroll
      for (int j=0;j<8;++j){
        float v = leaky(acc[i][j] + bj[j]);
        if (MODE == 2) v *= sn;
        tmp[j] = v;
      }
      float4 o0 = make_float4(tmp[0],tmp[1],tmp[2],tmp[3]);
      float4 o1 = make_float4(tmp[4],tmp[5],tmp[6],tmp[7]);
      ((float4*)(out + (size_t)row*HID))[tx] = o0;
      ((float4*)(out + (size_t)row*HID + 64))[tx] = o1;
    }
  }
}

// ---------------- aggregation (CSR, dst-sorted m) ----------------
__global__ void k_agg(const float* __restrict__ msort, const int* __restrict__ off,
                      const float* __restrict__ invd, float* __restrict__ agg){
  int tid = threadIdx.x;
  int node = blockIdx.x*2 + (tid >> 7);
  int c = tid & 127;
  if (node >= N_NODES) return;
  int s = off[node], e2 = off[node+1];
  float sum = 0.f, sq = 0.f, mx = -3.4e38f, mn = 3.4e38f;
  for (int i = s; i < e2; ++i){
    float v = msort[(size_t)i*HID + c];
    sum += v; sq += v*v;
    mx = fmaxf(mx, v); mn = fminf(mn, v);
  }
  bool has = (e2 > s);
  float iv = invd[node];
  float mean = sum * iv;
  float msq  = sq * iv;
  float var = fmaxf(msq - mean*mean, 0.f) + EPS;
  float sd = has ? sqrtf(var) : 0.f;
  mx = has ? mx : 0.f;
  mn = has ? mn : 0.f;
  size_t base = (size_t)node*512 + c;
  agg[base]       = mean;
  agg[base + 128] = mx;
  agg[base + 256] = mn;
  agg[base + 384] = sd;
}

// ---------------- BatchNorm ----------------
__global__ void k_bnreduce(const float* __restrict__ t, double* __restrict__ bnsum,
                           double* __restrict__ bnsq){
  int tid = threadIdx.x;
  int c = tid & 127, half = tid >> 7;
  float s = 0.f, sq = 0.f;
  for (int r = blockIdx.x*2 + half; r < N_NODES; r += 512){
    float v = t[(size_t)r*HID + c];
    s += v; sq += v*v;
  }
  __shared__ float shs[2][128], shq[2][128];
  shs[half][c] = s; shq[half][c] = sq;
  __syncthreads();
  if (half == 0){
    atomicAdd(&bnsum[c], (double)(s + shs[1][c]));
    atomicAdd(&bnsq[c],  (double)(sq + shq[1][c]));
  }
}

__global__ void k_bnfinal(const double* __restrict__ bnsum, const double* __restrict__ bnsq,
                          float* __restrict__ mu, float* __restrict__ rstd){
  int c = threadIdx.x;
  double mean = bnsum[c] / (double)N_NODES;
  double var  = bnsq[c] / (double)N_NODES - mean*mean;
  mu[c] = (float)mean;
  rstd[c] = rsqrtf((float)var + EPS);
}

__global__ void k_apply(const float* __restrict__ t, const float* __restrict__ mu,
                        const float* __restrict__ rstd, const float* __restrict__ gamma,
                        const float* __restrict__ beta, float* __restrict__ h){
  int idx = blockIdx.x*blockDim.x + threadIdx.x;
  if (idx < N_NODES*32){
    int n = idx >> 5, q = idx & 31;
    float4 tv = ((const float4*)t)[(size_t)n*32 + q];
    float4 hv = ((float4*)h)[(size_t)n*32 + q];
    float4 g4 = ((const float4*)gamma)[q], b4 = ((const float4*)beta)[q];
    float4 m4 = ((const float4*)mu)[q],    r4 = ((const float4*)rstd)[q];
    hv.x += g4.x*(tv.x-m4.x)*r4.x + b4.x;
    hv.y += g4.y*(tv.y-m4.y)*r4.y + b4.y;
    hv.z += g4.z*(tv.z-m4.z)*r4.z + b4.z;
    hv.w += g4.w*(tv.w-m4.w)*r4.w + b4.w;
    ((float4*)h)[(size_t)n*32 + q] = hv;
  }
}

// ---------------- readout ----------------
__global__ void k_pool(const int* __restrict__ batch, const float* __restrict__ h,
                       float* __restrict__ gsum, float* __restrict__ gcnt){
  int idx = blockIdx.x*blockDim.x + threadIdx.x;
  if (idx < N_NODES*HID){
    int n = idx >> 7, c = idx & 127;
    int g = batch[n];
    atomicAdd(&gsum[(size_t)g*HID + c], h[(size_t)n*HID + c]);
    if (c == 0) atomicAdd(&gcnt[g], 1.f);
  }
}

__global__ void k_readout(const float* __restrict__ gsum, const float* __restrict__ gcnt,
                          const float* __restrict__ W1, const float* __restrict__ b1,
                          const float* __restrict__ W2, const float* __restrict__ b2,
                          const float* __restrict__ W3, const float* __restrict__ b3,
                          float* __restrict__ out){
  __shared__ float gl[128];
  __shared__ float a1[64];
  __shared__ float a2[32];
  int g = blockIdx.x, tid = threadIdx.x;
  float inv = 1.f / fmaxf(gcnt[g], 1.f);
  gl[tid]      = gsum[(size_t)g*HID + tid] * inv;
  gl[tid + 64] = gsum[(size_t)g*HID + 64 + tid] * inv;
  __syncthreads();
  {
    float s = b1[tid];
    for (int k = 0; k < 128; ++k) s = fmaf(gl[k], W1[k*64 + tid], s);
    a1[tid] = fmaxf(s, 0.f);
  }
  __syncthreads();
  if (tid < 32){
    float s = b2[tid];
    for (int k = 0; k < 64; ++k) s = fmaf(a1[k], W2[k*32 + tid], s);
    a2[tid] = fmaxf(s, 0.f);
  }
  __syncthreads();
  if (tid == 0){
    float s = b3[0];
    for (int k = 0; k < 32; ++k) s = fmaf(a2[k], W3[k], s);
    out[g] = s;
  }
}

// ---------------- launch ----------------
extern "C" void kernel_launch(void* const* d_in, const int* in_sizes, int n_in,
                              void* d_out, int out_size, void* d_ws, size_t ws_size,
                              hipStream_t stream) {
  const int*   x        = (const int*)  d_in[0];
  const int*   batch    = (const int*)  d_in[1];
  const int*   ei       = (const int*)  d_in[2];
  const float* snorm    = (const float*)d_in[3];
  const int*   eattr    = (const int*)  d_in[4];
  const float* atom_emb = (const float*)d_in[5];
  const float* bond_emb = (const float*)d_in[6];
  const float* pre_W    = (const float*)d_in[7];
  const float* pre_b    = (const float*)d_in[8];
  const float* post_W   = (const float*)d_in[9];
  const float* post_b   = (const float*)d_in[10];
  const float* mix_W    = (const float*)d_in[11];
  const float* mix_b    = (const float*)d_in[12];
  const float* bn_g     = (const float*)d_in[13];
  const float* bn_b     = (const float*)d_in[14];
  const float* rW1      = (const float*)d_in[15];
  const float* rb1      = (const float*)d_in[16];
  const float* rW2      = (const float*)d_in[17];
  const float* rb2      = (const float*)d_in[18];
  const float* rW3      = (const float*)d_in[19];
  const float* rb3      = (const float*)d_in[20];
  float* outp = (float*)d_out;

  const int* srcI = ei;            // edge_index[0]
  const int* dstI = ei + N_EDGES;  // edge_index[1]

  char* ws = (char*)d_ws;
  size_t o = 0;
  auto alloc = [&](size_t bytes)->char* {
    char* p = ws + o;
    o = (o + bytes + 255) & ~(size_t)255;
    return p;
  };
  int*    deg    = (int*)   alloc((size_t)N_NODES*4);
  int*    off    = (int*)   alloc((size_t)(N_NODES+1)*4);
  int*    cursor = (int*)   alloc((size_t)N_NODES*4);
  int*    dstS   = (int*)   alloc((size_t)N_EDGES*4);
  int*    srcS   = (int*)   alloc((size_t)N_EDGES*4);
  int*    eaS    = (int*)   alloc((size_t)N_EDGES*4);
  float*  invd   = (float*) alloc((size_t)N_NODES*4);
  float*  ampb   = (float*) alloc((size_t)N_NODES*4);
  float*  attb   = (float*) alloc((size_t)N_NODES*4);
  float*  h      = (float*) alloc((size_t)N_NODES*HID*4);
  float*  msort  = (float*) alloc((size_t)N_EDGES*HID*4);
  float*  agg    = (float*) alloc((size_t)N_NODES*512*4);
  float*  ph     = (float*) alloc((size_t)N_NODES*HID*4);
  float*  tb     = (float*) alloc((size_t)N_NODES*HID*4);
  double* bnsum  = (double*)alloc(128*8);
  double* bnsq   = (double*)alloc(128*8);
  float*  mu     = (float*) alloc(128*4);
  float*  rstd   = (float*) alloc(128*4);
  float*  gsum   = (float*) alloc((size_t)N_GRAPHS*HID*4);
  float*  gcnt   = (float*) alloc((size_t)N_GRAPHS*4);

  hipMemsetAsync(deg, 0, (size_t)N_NODES*4, stream);
  hipMemsetAsync(cursor, 0, (size_t)N_NODES*4, stream);
  k_count<<<(N_EDGES+255)/256, 256, 0, stream>>>(dstI, deg);
  k_scan<<<1, 1024, 0, stream>>>(deg, off);
  k_fill<<<(N_EDGES+255)/256, 256, 0, stream>>>(srcI, dstI, eattr, off, cursor, dstS, srcS, eaS);
  k_scalars<<<(N_NODES+255)/256, 256, 0, stream>>>(deg, invd, ampb, attb);
  k_hinit<<<(N_NODES*32+255)/256, 256, 0, stream>>>(x, atom_emb, h);

  for (int l = 0; l < NLAYERS; ++l){
    k_gemm<0><<<N_EDGES/128, 256, 0, stream>>>(
        pre_W + (size_t)l*384*128, pre_b + (size_t)l*128,
        h, nullptr, nullptr, nullptr, dstS, srcS, eaS, bond_emb, nullptr, msort);
    k_agg<<<N_NODES/2, 256, 0, stream>>>(msort, off, invd, agg);
    k_gemm<1><<<(N_NODES+127)/128, 256, 0, stream>>>(
        post_W + (size_t)l*1664*128, post_b + (size_t)l*128,
        h, agg, ampb, attb, nullptr, nullptr, nullptr, nullptr, nullptr, ph);
    k_gemm<2><<<(N_NODES+127)/128, 256, 0, stream>>>(
        mix_W + (size_t)l*128*128, mix_b + (size_t)l*128,
        ph, nullptr, nullptr, nullptr, nullptr, nullptr, nullptr, nullptr, snorm, tb);
    hipMemsetAsync(bnsum, 0, 128*8, stream);
    hipMemsetAsync(bnsq, 0, 128*8, stream);
    k_bnreduce<<<256, 256, 0, stream>>>(tb, bnsum, bnsq);
    k_bnfinal<<<1, 128, 0, stream>>>(bnsum, bnsq, mu, rstd);
    k_apply<<<(N_NODES*32+255)/256, 256, 0, stream>>>(tb, mu, rstd,
        bn_g + (size_t)l*128, bn_b + (size_t)l*128, h);
  }

  hipMemsetAsync(gsum, 0, (size_t)N_GRAPHS*HID*4, stream);
  hipMemsetAsync(gcnt, 0, (size_t)N_GRAPHS*4, stream);
  k_pool<<<(N_NODES*HID+255)/256, 256, 0, stream>>>(batch, h, gsum, gcnt);
  k_readout<<<N_GRAPHS, 64, 0, stream>>>(gsum, gcnt, rW1, rb1, rW2, rb2, rW3, rb3, outp);
}

// Round 2
// 1289.476 us; speedup vs baseline: 2.1066x; 2.1066x over previous
//
#include <hip/hip_runtime.h>
#include <math.h>

#define N_NODES 20000
#define N_EDGES 320000
#define N_GRAPHS 256
#define HID 128
#define NLAYERS 4
#define AVG_LOG 2.833213344056216f
#define EPS 1e-5f

static __device__ __forceinline__ float leaky(float v){ return v > 0.f ? v : 0.01f*v; }

// ---------------- CSR build ----------------
__global__ void k_count(const int* __restrict__ dst, int* __restrict__ deg){
  int e = blockIdx.x*blockDim.x + threadIdx.x;
  if (e < N_EDGES) atomicAdd(&deg[dst[e]], 1);
}

__global__ void k_scan(const int* __restrict__ deg, int* __restrict__ off){
  __shared__ int buf[1024];
  int tid = threadIdx.x;
  int carry = 0;
  for (int base = 0; base < N_NODES; base += 1024){
    int i = base + tid;
    int v = (i < N_NODES) ? deg[i] : 0;
    buf[tid] = v;
    __syncthreads();
    for (int ofs = 1; ofs < 1024; ofs <<= 1){
      int tadd = (tid >= ofs) ? buf[tid-ofs] : 0;
      __syncthreads();
      buf[tid] += tadd;
      __syncthreads();
    }
    if (i < N_NODES) off[i] = carry + buf[tid] - v;  // exclusive
    carry += buf[1023];
    __syncthreads();
  }
  if (tid == 0) off[N_NODES] = carry;
}

__global__ void k_fill(const int* __restrict__ src, const int* __restrict__ dst,
                       const int* __restrict__ eattr, const int* __restrict__ off,
                       int* __restrict__ cursor,
                       int* __restrict__ srcS, int* __restrict__ eaS){
  int e = blockIdx.x*blockDim.x + threadIdx.x;
  if (e < N_EDGES){
    int d = dst[e];
    int pos = off[d] + atomicAdd(&cursor[d], 1);
    srcS[pos] = src[e]; eaS[pos] = eattr[e];
  }
}

__global__ void k_scalars(const int* __restrict__ deg, float* __restrict__ invd,
                          float* __restrict__ amp, float* __restrict__ att){
  int n = blockIdx.x*blockDim.x + threadIdx.x;
  if (n < N_NODES){
    float d = (float)deg[n];
    invd[n] = 1.f / fmaxf(d, 1.f);
    float ld = log1pf(d);
    amp[n] = ld / AVG_LOG;
    att[n] = AVG_LOG / fmaxf(ld, EPS);
  }
}

__global__ void k_hinit(const int* __restrict__ x, const float* __restrict__ atom_emb,
                        float* __restrict__ h){
  int idx = blockIdx.x*blockDim.x + threadIdx.x;
  if (idx < N_NODES*32){
    int n = idx >> 5, q = idx & 31;
    ((float4*)h)[(size_t)n*32 + q] = ((const float4*)atom_emb)[(size_t)x[n]*32 + q];
  }
}

// bond table: BW3[r][c] = bond_emb[r]@W3[:,c] + pre_b[c]   (4 x 128)
__global__ void k_bond(const float* __restrict__ bond_emb, const float* __restrict__ W3,
                       const float* __restrict__ pre_b, float* __restrict__ BW3){
  int tid = threadIdx.x;               // 512
  int r = tid >> 7, c = tid & 127;
  float s = pre_b[c];
  for (int k = 0; k < 128; ++k) s = fmaf(bond_emb[r*128 + k], W3[k*128 + c], s);
  BW3[tid] = s;
}

// ---------------- node-level tiled GEMM (BM=64, BN=128, BK=32) ----------------
// MODE 3: dual  H1 = h@W[0:128], H2 = h@W[128:256]  (gridDim.y=2, no bias/act)
// MODE 1: posttrans A = cat(h, agg, agg*amp, agg*att)  K=1664, bias+leaky
// MODE 2: mix       A = ph                              K=128,  bias+leaky, *snorm
template<int MODE>
__global__ __launch_bounds__(256) void k_gemmN(
    const float* __restrict__ W, const float* __restrict__ bias,
    const float* __restrict__ hA, const float* __restrict__ agg,
    const float* __restrict__ amp, const float* __restrict__ att,
    const float* __restrict__ snorm,
    float* __restrict__ out0, float* __restrict__ out1)
{
  const int K = (MODE==1) ? 1664 : 128;
  __shared__ float As[32][64];
  __shared__ float Bs[32][128];
  int tid = threadIdx.x;
  int tx = tid & 15, ty = tid >> 4;
  int mbase = blockIdx.x * 64;

  const float* Wp = W;
  float* outp = out0;
  if (MODE == 3){
    Wp = W + (size_t)blockIdx.y*128*128;
    if (blockIdx.y) outp = out1;
  }

  int lr  = tid & 63;          // row this thread stages
  int lkq = tid >> 6;          // which 8-wide k chunk
  int nrow = min(mbase + lr, N_NODES-1);
  float ampv = 1.f, attv = 1.f;
  if (MODE == 1){ ampv = amp[nrow]; attv = att[nrow]; }

  float acc[4][8];
  #pragma unroll
  for (int i=0;i<4;++i){
    #pragma unroll
    for (int j=0;j<8;++j) acc[i][j] = 0.f;
  }

  for (int kt = 0; kt < K; kt += 32){
    // stage B (32x128 chunk of W)
    {
      const float4* bsrc = (const float4*)(Wp + (size_t)kt*128);
      float4* bdst = (float4*)(&Bs[0][0]);
      #pragma unroll
      for (int i=0;i<4;++i) bdst[tid + 256*i] = bsrc[tid + 256*i];
    }
    // stage A transposed, built on the fly (8 consecutive k per thread)
    {
      int k0 = kt + lkq*8;
      const float* srcp; float scale = 1.f;
      if (MODE == 1){
        if (k0 < 128)       srcp = hA  + (size_t)nrow*HID + k0;
        else if (k0 < 640)  srcp = agg + (size_t)nrow*512 + (k0-128);
        else if (k0 < 1152){ srcp = agg + (size_t)nrow*512 + (k0-640);  scale = ampv; }
        else               { srcp = agg + (size_t)nrow*512 + (k0-1152); scale = attv; }
      } else {
        srcp = hA + (size_t)nrow*HID + k0;
      }
      float4 f0 = ((const float4*)srcp)[0];
      float4 f1 = ((const float4*)srcp)[1];
      float tv[8] = {f0.x,f0.y,f0.z,f0.w,f1.x,f1.y,f1.z,f1.w};
      #pragma unroll
      for (int j=0;j<8;++j) As[lkq*8 + j][lr] = tv[j] * scale;
    }
    __syncthreads();
    #pragma unroll
    for (int k=0;k<32;++k){
      float a[4], b[8];
      *(float4*)&a[0] = *(const float4*)&As[k][ty*4];
      *(float4*)&b[0] = *(const float4*)&Bs[k][tx*4];
      *(float4*)&b[4] = *(const float4*)&Bs[k][64 + tx*4];
      #pragma unroll
      for (int i=0;i<4;++i){
        #pragma unroll
        for (int j=0;j<8;++j) acc[i][j] = fmaf(a[i], b[j], acc[i][j]);
      }
    }
    __syncthreads();
  }

  float bj[8];
  if (MODE != 3){
    #pragma unroll
    for (int j=0;j<4;++j){ bj[j] = bias[tx*4+j]; bj[4+j] = bias[64+tx*4+j]; }
  }
  #pragma unroll
  for (int i=0;i<4;++i){
    int row = mbase + ty*4 + i;
    if (row < N_NODES){
      float sn = (MODE==2) ? snorm[row] : 1.f;
      float tmp[8];
      #pragma unroll
      for (int j=0;j<8;++j){
        float v = acc[i][j];
        if (MODE != 3) v = leaky(v + bj[j]);
        if (MODE == 2) v *= sn;
        tmp[j] = v;
      }
      ((float4*)(outp + (size_t)row*HID))[tx]      = make_float4(tmp[0],tmp[1],tmp[2],tmp[3]);
      ((float4*)(outp + (size_t)row*HID + 64))[tx] = make_float4(tmp[4],tmp[5],tmp[6],tmp[7]);
    }
  }
}

// ---------------- fused edge-message + aggregation ----------------
// per node n, over CSR edges i: v = leaky(H1[n] + H2[src_i] + BW3[ea_i])
// accumulate mean / max / min / std into agg[n][512]
__global__ __launch_bounds__(256) void k_fusedagg(
    const float* __restrict__ H1, const float* __restrict__ H2,
    const float* __restrict__ BW3,
    const int* __restrict__ srcS, const int* __restrict__ eaS,
    const int* __restrict__ off, const float* __restrict__ invd,
    float* __restrict__ agg)
{
  __shared__ float bw[4][128];
  int tid = threadIdx.x;
  bw[tid>>7][tid&127]     = BW3[tid];
  bw[2+(tid>>7)][tid&127] = BW3[256+tid];
  __syncthreads();

  int node = blockIdx.x*8 + (tid>>5);
  int q = tid & 31;
  float4 c4 = ((const float4*)(H1 + (size_t)node*HID))[q];
  int s = off[node], e = off[node+1];
  float4 sum = make_float4(0,0,0,0), sq = make_float4(0,0,0,0);
  float4 mx = make_float4(-3.4e38f,-3.4e38f,-3.4e38f,-3.4e38f);
  float4 mn = make_float4( 3.4e38f, 3.4e38f, 3.4e38f, 3.4e38f);
  for (int i = s; i < e; ++i){
    int sv = srcS[i], ev = eaS[i];
    float4 t  = ((const float4*)(H2 + (size_t)sv*HID))[q];
    float4 b4 = ((const float4*)(&bw[ev][0]))[q];
    float vx = leaky(c4.x + t.x + b4.x);
    float vy = leaky(c4.y + t.y + b4.y);
    float vz = leaky(c4.z + t.z + b4.z);
    float vw = leaky(c4.w + t.w + b4.w);
    sum.x += vx; sum.y += vy; sum.z += vz; sum.w += vw;
    sq.x += vx*vx; sq.y += vy*vy; sq.z += vz*vz; sq.w += vw*vw;
    mx.x = fmaxf(mx.x, vx); mx.y = fmaxf(mx.y, vy); mx.z = fmaxf(mx.z, vz); mx.w = fmaxf(mx.w, vw);
    mn.x = fminf(mn.x, vx); mn.y = fminf(mn.y, vy); mn.z = fminf(mn.z, vz); mn.w = fminf(mn.w, vw);
  }
  bool has = (e > s);
  float iv = invd[node];
  float4 mean = make_float4(sum.x*iv, sum.y*iv, sum.z*iv, sum.w*iv);
  float4 msq  = make_float4(sq.x*iv,  sq.y*iv,  sq.z*iv,  sq.w*iv);
  float4 sd;
  sd.x = has ? sqrtf(fmaxf(msq.x - mean.x*mean.x, 0.f) + EPS) : 0.f;
  sd.y = has ? sqrtf(fmaxf(msq.y - mean.y*mean.y, 0.f) + EPS) : 0.f;
  sd.z = has ? sqrtf(fmaxf(msq.z - mean.z*mean.z, 0.f) + EPS) : 0.f;
  sd.w = has ? sqrtf(fmaxf(msq.w - mean.w*mean.w, 0.f) + EPS) : 0.f;
  if (!has){ mx = make_float4(0,0,0,0); mn = make_float4(0,0,0,0); }
  size_t base = (size_t)node*512;
  ((float4*)(agg + base      ))[q] = mean;
  ((float4*)(agg + base + 128))[q] = mx;
  ((float4*)(agg + base + 256))[q] = mn;
  ((float4*)(agg + base + 384))[q] = sd;
}

// ---------------- BatchNorm ----------------
__global__ void k_bnreduce(const float* __restrict__ t, double* __restrict__ bnsum,
                           double* __restrict__ bnsq){
  int tid = threadIdx.x;
  int c = tid & 127, half = tid >> 7;
  float s = 0.f, sq = 0.f;
  for (int r = blockIdx.x*2 + half; r < N_NODES; r += 512){
    float v = t[(size_t)r*HID + c];
    s += v; sq += v*v;
  }
  __shared__ float shs[2][128], shq[2][128];
  shs[half][c] = s; shq[half][c] = sq;
  __syncthreads();
  if (half == 0){
    atomicAdd(&bnsum[c], (double)(s + shs[1][c]));
    atomicAdd(&bnsq[c],  (double)(sq + shq[1][c]));
  }
}

__global__ void k_bnfinal(const double* __restrict__ bnsum, const double* __restrict__ bnsq,
                          float* __restrict__ mu, float* __restrict__ rstd){
  int c = threadIdx.x;
  double mean = bnsum[c] / (double)N_NODES;
  double var  = bnsq[c] / (double)N_NODES - mean*mean;
  mu[c] = (float)mean;
  rstd[c] = rsqrtf((float)var + EPS);
}

__global__ void k_apply(const float* __restrict__ t, const float* __restrict__ mu,
                        const float* __restrict__ rstd, const float* __restrict__ gamma,
                        const float* __restrict__ beta, float* __restrict__ h){
  int idx = blockIdx.x*blockDim.x + threadIdx.x;
  if (idx < N_NODES*32){
    int n = idx >> 5, q = idx & 31;
    float4 tv = ((const float4*)t)[(size_t)n*32 + q];
    float4 hv = ((float4*)h)[(size_t)n*32 + q];
    float4 g4 = ((const float4*)gamma)[q], b4 = ((const float4*)beta)[q];
    float4 m4 = ((const float4*)mu)[q],    r4 = ((const float4*)rstd)[q];
    hv.x += g4.x*(tv.x-m4.x)*r4.x + b4.x;
    hv.y += g4.y*(tv.y-m4.y)*r4.y + b4.y;
    hv.z += g4.z*(tv.z-m4.z)*r4.z + b4.z;
    hv.w += g4.w*(tv.w-m4.w)*r4.w + b4.w;
    ((float4*)h)[(size_t)n*32 + q] = hv;
  }
}

// ---------------- readout ----------------
__global__ void k_pool(const int* __restrict__ batch, const float* __restrict__ h,
                       float* __restrict__ gsum, float* __restrict__ gcnt){
  int idx = blockIdx.x*blockDim.x + threadIdx.x;
  if (idx < N_NODES*HID){
    int n = idx >> 7, c = idx & 127;
    int g = batch[n];
    atomicAdd(&gsum[(size_t)g*HID + c], h[(size_t)n*HID + c]);
    if (c == 0) atomicAdd(&gcnt[g], 1.f);
  }
}

__global__ void k_readout(const float* __restrict__ gsum, const float* __restrict__ gcnt,
                          const float* __restrict__ W1, const float* __restrict__ b1,
                          const float* __restrict__ W2, const float* __restrict__ b2,
                          const float* __restrict__ W3, const float* __restrict__ b3,
                          float* __restrict__ out){
  __shared__ float gl[128];
  __shared__ float a1[64];
  __shared__ float a2[32];
  int g = blockIdx.x, tid = threadIdx.x;
  float inv = 1.f / fmaxf(gcnt[g], 1.f);
  gl[tid]      = gsum[(size_t)g*HID + tid] * inv;
  gl[tid + 64] = gsum[(size_t)g*HID + 64 + tid] * inv;
  __syncthreads();
  {
    float s = b1[tid];
    for (int k = 0; k < 128; ++k) s = fmaf(gl[k], W1[k*64 + tid], s);
    a1[tid] = fmaxf(s, 0.f);
  }
  __syncthreads();
  if (tid < 32){
    float s = b2[tid];
    for (int k = 0; k < 64; ++k) s = fmaf(a1[k], W2[k*32 + tid], s);
    a2[tid] = fmaxf(s, 0.f);
  }
  __syncthreads();
  if (tid == 0){
    float s = b3[0];
    for (int k = 0; k < 32; ++k) s = fmaf(a2[k], W3[k], s);
    out[g] = s;
  }
}

// ---------------- launch ----------------
extern "C" void kernel_launch(void* const* d_in, const int* in_sizes, int n_in,
                              void* d_out, int out_size, void* d_ws, size_t ws_size,
                              hipStream_t stream) {
  const int*   x        = (const int*)  d_in[0];
  const int*   batch    = (const int*)  d_in[1];
  const int*   ei       = (const int*)  d_in[2];
  const float* snorm    = (const float*)d_in[3];
  const int*   eattr    = (const int*)  d_in[4];
  const float* atom_emb = (const float*)d_in[5];
  const float* bond_emb = (const float*)d_in[6];
  const float* pre_W    = (const float*)d_in[7];
  const float* pre_b    = (const float*)d_in[8];
  const float* post_W   = (const float*)d_in[9];
  const float* post_b   = (const float*)d_in[10];
  const float* mix_W    = (const float*)d_in[11];
  const float* mix_b    = (const float*)d_in[12];
  const float* bn_g     = (const float*)d_in[13];
  const float* bn_b     = (const float*)d_in[14];
  const float* rW1      = (const float*)d_in[15];
  const float* rb1      = (const float*)d_in[16];
  const float* rW2      = (const float*)d_in[17];
  const float* rb2      = (const float*)d_in[18];
  const float* rW3      = (const float*)d_in[19];
  const float* rb3      = (const float*)d_in[20];
  float* outp = (float*)d_out;

  const int* srcI = ei;            // edge_index[0]
  const int* dstI = ei + N_EDGES;  // edge_index[1]

  char* ws = (char*)d_ws;
  size_t o = 0;
  auto alloc = [&](size_t bytes)->char* {
    char* p = ws + o;
    o = (o + bytes + 255) & ~(size_t)255;
    return p;
  };
  int*    deg    = (int*)   alloc((size_t)N_NODES*4);
  int*    off    = (int*)   alloc((size_t)(N_NODES+1)*4);
  int*    cursor = (int*)   alloc((size_t)N_NODES*4);
  int*    srcS   = (int*)   alloc((size_t)N_EDGES*4);
  int*    eaS    = (int*)   alloc((size_t)N_EDGES*4);
  float*  invd   = (float*) alloc((size_t)N_NODES*4);
  float*  ampb   = (float*) alloc((size_t)N_NODES*4);
  float*  attb   = (float*) alloc((size_t)N_NODES*4);
  float*  h      = (float*) alloc((size_t)N_NODES*HID*4);
  float*  H1     = (float*) alloc((size_t)N_NODES*HID*4);
  float*  H2     = (float*) alloc((size_t)N_NODES*HID*4);
  float*  BW3    = (float*) alloc(512*4);
  float*  agg    = (float*) alloc((size_t)N_NODES*512*4);
  float*  ph     = (float*) alloc((size_t)N_NODES*HID*4);
  float*  tb     = (float*) alloc((size_t)N_NODES*HID*4);
  double* bnsum  = (double*)alloc(128*8);
  double* bnsq   = (double*)alloc(128*8);
  float*  mu     = (float*) alloc(128*4);
  float*  rstd   = (float*) alloc(128*4);
  float*  gsum   = (float*) alloc((size_t)N_GRAPHS*HID*4);
  float*  gcnt   = (float*) alloc((size_t)N_GRAPHS*4);

  hipMemsetAsync(deg, 0, (size_t)N_NODES*4, stream);
  hipMemsetAsync(cursor, 0, (size_t)N_NODES*4, stream);
  k_count<<<(N_EDGES+255)/256, 256, 0, stream>>>(dstI, deg);
  k_scan<<<1, 1024, 0, stream>>>(deg, off);
  k_fill<<<(N_EDGES+255)/256, 256, 0, stream>>>(srcI, dstI, eattr, off, cursor, srcS, eaS);
  k_scalars<<<(N_NODES+255)/256, 256, 0, stream>>>(deg, invd, ampb, attb);
  k_hinit<<<(N_NODES*32+255)/256, 256, 0, stream>>>(x, atom_emb, h);

  const int MB = (N_NODES + 63) / 64;   // 313
  for (int l = 0; l < NLAYERS; ++l){
    const float* preWl = pre_W + (size_t)l*384*128;
    // H1 = h@W1, H2 = h@W2 (dual-output node GEMM)
    k_gemmN<3><<<dim3(MB,2), 256, 0, stream>>>(
        preWl, nullptr, h, nullptr, nullptr, nullptr, nullptr, H1, H2);
    // 4-row bond table (+ pre_b folded in)
    k_bond<<<1, 512, 0, stream>>>(bond_emb, preWl + 256*128, pre_b + (size_t)l*128, BW3);
    // fused edge message + aggregation
    k_fusedagg<<<N_NODES/8, 256, 0, stream>>>(H1, H2, BW3, srcS, eaS, off, invd, agg);
    // posttrans
    k_gemmN<1><<<MB, 256, 0, stream>>>(
        post_W + (size_t)l*1664*128, post_b + (size_t)l*128,
        h, agg, ampb, attb, nullptr, ph, nullptr);
    // mix (+snorm)
    k_gemmN<2><<<MB, 256, 0, stream>>>(
        mix_W + (size_t)l*128*128, mix_b + (size_t)l*128,
        ph, nullptr, nullptr, nullptr, snorm, tb, nullptr);
    // BatchNorm + residual
    hipMemsetAsync(bnsum, 0, 128*8, stream);
    hipMemsetAsync(bnsq, 0, 128*8, stream);
    k_bnreduce<<<256, 256, 0, stream>>>(tb, bnsum, bnsq);
    k_bnfinal<<<1, 128, 0, stream>>>(bnsum, bnsq, mu, rstd);
    k_apply<<<(N_NODES*32+255)/256, 256, 0, stream>>>(tb, mu, rstd,
        bn_g + (size_t)l*128, bn_b + (size_t)l*128, h);
  }

  hipMemsetAsync(gsum, 0, (size_t)N_GRAPHS*HID*4, stream);
  hipMemsetAsync(gcnt, 0, (size_t)N_GRAPHS*4, stream);
  k_pool<<<(N_NODES*HID+255)/256, 256, 0, stream>>>(batch, h, gsum, gcnt);
  k_readout<<<N_GRAPHS, 64, 0, stream>>>(gsum, gcnt, rW1, rb1, rW2, rb2, rW3, rb3, outp);
}

// Round 3
// 1102.251 us; speedup vs baseline: 2.4644x; 1.1699x over previous
//
#include <hip/hip_runtime.h>
#include <math.h>

#define N_NODES 20000
#define N_EDGES 320000
#define N_GRAPHS 256
#define HID 128
#define NLAYERS 4
#define AVG_LOG 2.833213344056216f
#define EPS 1e-5f

static __device__ __forceinline__ float leaky(float v){ return v > 0.f ? v : 0.01f*v; }

// ---------------- CSR build ----------------
__global__ void k_count(const int* __restrict__ dst, int* __restrict__ deg){
  int e = blockIdx.x*blockDim.x + threadIdx.x;
  if (e < N_EDGES) atomicAdd(&deg[dst[e]], 1);
}

__global__ void k_scan(const int* __restrict__ deg, int* __restrict__ off){
  __shared__ int buf[1024];
  int tid = threadIdx.x;
  int carry = 0;
  for (int base = 0; base < N_NODES; base += 1024){
    int i = base + tid;
    int v = (i < N_NODES) ? deg[i] : 0;
    buf[tid] = v;
    __syncthreads();
    for (int ofs = 1; ofs < 1024; ofs <<= 1){
      int tadd = (tid >= ofs) ? buf[tid-ofs] : 0;
      __syncthreads();
      buf[tid] += tadd;
      __syncthreads();
    }
    if (i < N_NODES) off[i] = carry + buf[tid] - v;  // exclusive
    carry += buf[1023];
    __syncthreads();
  }
  if (tid == 0) off[N_NODES] = carry;
}

__global__ void k_fill(const int* __restrict__ src, const int* __restrict__ dst,
                       const int* __restrict__ eattr, const int* __restrict__ off,
                       int* __restrict__ cursor,
                       int* __restrict__ srcS, int* __restrict__ eaS){
  int e = blockIdx.x*blockDim.x + threadIdx.x;
  if (e < N_EDGES){
    int d = dst[e];
    int pos = off[d] + atomicAdd(&cursor[d], 1);
    srcS[pos] = src[e]; eaS[pos] = eattr[e];
  }
}

__global__ void k_scalars(const int* __restrict__ deg, float* __restrict__ invd,
                          float* __restrict__ amp, float* __restrict__ att){
  int n = blockIdx.x*blockDim.x + threadIdx.x;
  if (n < N_NODES){
    float d = (float)deg[n];
    invd[n] = 1.f / fmaxf(d, 1.f);
    float ld = log1pf(d);
    amp[n] = ld / AVG_LOG;
    att[n] = AVG_LOG / fmaxf(ld, EPS);
  }
}

__global__ void k_hinit(const int* __restrict__ x, const float* __restrict__ atom_emb,
                        float* __restrict__ h){
  int idx = blockIdx.x*blockDim.x + threadIdx.x;
  if (idx < N_NODES*32){
    int n = idx >> 5, q = idx & 31;
    ((float4*)h)[(size_t)n*32 + q] = ((const float4*)atom_emb)[(size_t)x[n]*32 + q];
  }
}

// bond table: BW3[r][c] = bond_emb[r]@W3[:,c] + pre_b[c]   (4 x 128)
__global__ void k_bond(const float* __restrict__ bond_emb, const float* __restrict__ W3,
                       const float* __restrict__ pre_b, float* __restrict__ BW3){
  int tid = threadIdx.x;               // 512
  int r = tid >> 7, c = tid & 127;
  float s = pre_b[c];
  for (int k = 0; k < 128; ++k) s = fmaf(bond_emb[r*128 + k], W3[k*128 + c], s);
  BW3[tid] = s;
}

// ---------------- node-level tiled GEMM ----------------
// MODE 0: triple head, K=128, A=h:      y=0: H1=h@W0; y=1: H2=h@W1; y=2: Yh=h@W2. raw store.
// MODE 1: agg GEMM,  K=512, A=agg:      Wp = W0 + y*512*128; out0[row*384 + y*128 + c]. raw store.
// MODE 2: mix,       K=128, A=ph:       out = leaky(acc+bias)*snorm, stride 128.
template<int MODE, int BM>
__global__ __launch_bounds__(256) void k_gemm(
    const float* __restrict__ W0, const float* __restrict__ W1, const float* __restrict__ W2,
    const float* __restrict__ bias, const float* __restrict__ A,
    const float* __restrict__ snorm,
    float* __restrict__ out0, float* __restrict__ out1, float* __restrict__ out2)
{
  const int K    = (MODE==1) ? 512 : 128;
  const int ASTR = (MODE==1) ? 512 : 128;
  const int OSTR = (MODE==1) ? 384 : 128;
  const int RPT  = BM/16;       // rows per thread
  const int CH   = BM/8;        // consecutive k staged per thread
  __shared__ float As[32][BM];
  __shared__ float Bs[32][128];
  int tid = threadIdx.x;
  int tx = tid & 15, ty = tid >> 4;
  int mbase = blockIdx.x * BM;
  int y = blockIdx.y;

  const float* Wp = W0; float* outp = out0; int ocol = 0;
  if (MODE == 0){
    Wp   = (y==0) ? W0   : ((y==1) ? W1   : W2);
    outp = (y==0) ? out0 : ((y==1) ? out1 : out2);
  } else if (MODE == 1){
    Wp = W0 + (size_t)y*512*128;
    ocol = y*128;
  }

  int lr  = tid % BM;
  int lkq = tid / BM;
  int nrow = min(mbase + lr, N_NODES-1);
  const float* arow = A + (size_t)nrow*ASTR;

  float acc[RPT][8];
  #pragma unroll
  for (int i=0;i<RPT;++i){
    #pragma unroll
    for (int j=0;j<8;++j) acc[i][j] = 0.f;
  }

  for (int kt = 0; kt < K; kt += 32){
    // stage B (32x128 chunk of Wp)
    {
      const float4* bsrc = (const float4*)(Wp + (size_t)kt*128);
      float4* bdst = (float4*)(&Bs[0][0]);
      #pragma unroll
      for (int i=0;i<4;++i) bdst[tid + 256*i] = bsrc[tid + 256*i];
    }
    // stage A transposed (CH consecutive k per thread)
    {
      int k0 = kt + lkq*CH;
      #pragma unroll
      for (int c4 = 0; c4 < CH/4; ++c4){
        float4 f = ((const float4*)(arow + k0))[c4];
        As[k0 - kt + c4*4 + 0][lr] = f.x;
        As[k0 - kt + c4*4 + 1][lr] = f.y;
        As[k0 - kt + c4*4 + 2][lr] = f.z;
        As[k0 - kt + c4*4 + 3][lr] = f.w;
      }
    }
    __syncthreads();
    #pragma unroll
    for (int k=0;k<32;++k){
      float a[RPT], b[8];
      #pragma unroll
      for (int i=0;i<RPT;++i) a[i] = As[k][ty*RPT + i];
      *(float4*)&b[0] = *(const float4*)&Bs[k][tx*4];
      *(float4*)&b[4] = *(const float4*)&Bs[k][64 + tx*4];
      #pragma unroll
      for (int i=0;i<RPT;++i){
        #pragma unroll
        for (int j=0;j<8;++j) acc[i][j] = fmaf(a[i], b[j], acc[i][j]);
      }
    }
    __syncthreads();
  }

  float bj[8];
  if (MODE == 2){
    #pragma unroll
    for (int j=0;j<4;++j){ bj[j] = bias[tx*4+j]; bj[4+j] = bias[64+tx*4+j]; }
  }
  #pragma unroll
  for (int i=0;i<RPT;++i){
    int row = mbase + ty*RPT + i;
    if (row < N_NODES){
      float tmp[8];
      if (MODE == 2){
        float sn = snorm[row];
        #pragma unroll
        for (int j=0;j<8;++j) tmp[j] = leaky(acc[i][j] + bj[j]) * sn;
      } else {
        #pragma unroll
        for (int j=0;j<8;++j) tmp[j] = acc[i][j];
      }
      float* op = outp + (size_t)row*OSTR + ocol;
      ((float4*)op)[tx]               = make_float4(tmp[0],tmp[1],tmp[2],tmp[3]);
      ((float4*)(op + 64))[tx]        = make_float4(tmp[4],tmp[5],tmp[6],tmp[7]);
    }
  }
}

// combine: ph = leaky(Yh + Ya + amp*Ym + att*Yt + post_b)
__global__ void k_combine(const float* __restrict__ Yh, const float* __restrict__ Yamt,
                          const float* __restrict__ amp, const float* __restrict__ att,
                          const float* __restrict__ post_b, float* __restrict__ ph){
  int idx = blockIdx.x*blockDim.x + threadIdx.x;
  if (idx < N_NODES*32){
    int n = idx >> 5, q = idx & 31;
    float av = amp[n], tv = att[n];
    float4 yh = ((const float4*)(Yh + (size_t)n*128))[q];
    const float4* yr = (const float4*)(Yamt + (size_t)n*384);
    float4 ya = yr[q], ym = yr[q+32], yt = yr[q+64];
    float4 b4 = ((const float4*)post_b)[q];
    float4 r;
    r.x = leaky(yh.x + ya.x + av*ym.x + tv*yt.x + b4.x);
    r.y = leaky(yh.y + ya.y + av*ym.y + tv*yt.y + b4.y);
    r.z = leaky(yh.z + ya.z + av*ym.z + tv*yt.z + b4.z);
    r.w = leaky(yh.w + ya.w + av*ym.w + tv*yt.w + b4.w);
    ((float4*)(ph + (size_t)n*128))[q] = r;
  }
}

// ---------------- fused edge-message + aggregation ----------------
__global__ __launch_bounds__(256) void k_fusedagg(
    const float* __restrict__ H1, const float* __restrict__ H2,
    const float* __restrict__ BW3,
    const int* __restrict__ srcS, const int* __restrict__ eaS,
    const int* __restrict__ off, const float* __restrict__ invd,
    float* __restrict__ agg)
{
  __shared__ float bw[4][128];
  int tid = threadIdx.x;
  bw[tid>>7][tid&127]     = BW3[tid];
  bw[2+(tid>>7)][tid&127] = BW3[256+tid];
  __syncthreads();

  int node = blockIdx.x*8 + (tid>>5);
  int q = tid & 31;
  float4 c4 = ((const float4*)(H1 + (size_t)node*HID))[q];
  int s = off[node], e = off[node+1];
  float4 sum = make_float4(0,0,0,0), sq = make_float4(0,0,0,0);
  float4 mx = make_float4(-3.4e38f,-3.4e38f,-3.4e38f,-3.4e38f);
  float4 mn = make_float4( 3.4e38f, 3.4e38f, 3.4e38f, 3.4e38f);
  for (int i = s; i < e; ++i){
    int sv = srcS[i], ev = eaS[i];
    float4 t  = ((const float4*)(H2 + (size_t)sv*HID))[q];
    float4 b4 = ((const float4*)(&bw[ev][0]))[q];
    float vx = leaky(c4.x + t.x + b4.x);
    float vy = leaky(c4.y + t.y + b4.y);
    float vz = leaky(c4.z + t.z + b4.z);
    float vw = leaky(c4.w + t.w + b4.w);
    sum.x += vx; sum.y += vy; sum.z += vz; sum.w += vw;
    sq.x += vx*vx; sq.y += vy*vy; sq.z += vz*vz; sq.w += vw*vw;
    mx.x = fmaxf(mx.x, vx); mx.y = fmaxf(mx.y, vy); mx.z = fmaxf(mx.z, vz); mx.w = fmaxf(mx.w, vw);
    mn.x = fminf(mn.x, vx); mn.y = fminf(mn.y, vy); mn.z = fminf(mn.z, vz); mn.w = fminf(mn.w, vw);
  }
  bool has = (e > s);
  float iv = invd[node];
  float4 mean = make_float4(sum.x*iv, sum.y*iv, sum.z*iv, sum.w*iv);
  float4 msq  = make_float4(sq.x*iv,  sq.y*iv,  sq.z*iv,  sq.w*iv);
  float4 sd;
  sd.x = has ? sqrtf(fmaxf(msq.x - mean.x*mean.x, 0.f) + EPS) : 0.f;
  sd.y = has ? sqrtf(fmaxf(msq.y - mean.y*mean.y, 0.f) + EPS) : 0.f;
  sd.z = has ? sqrtf(fmaxf(msq.z - mean.z*mean.z, 0.f) + EPS) : 0.f;
  sd.w = has ? sqrtf(fmaxf(msq.w - mean.w*mean.w, 0.f) + EPS) : 0.f;
  if (!has){ mx = make_float4(0,0,0,0); mn = make_float4(0,0,0,0); }
  size_t base = (size_t)node*512;
  ((float4*)(agg + base      ))[q] = mean;
  ((float4*)(agg + base + 128))[q] = mx;
  ((float4*)(agg + base + 256))[q] = mn;
  ((float4*)(agg + base + 384))[q] = sd;
}

// ---------------- BatchNorm ----------------
__global__ void k_bnreduce(const float* __restrict__ t, double* __restrict__ bnsum,
                           double* __restrict__ bnsq){
  int tid = threadIdx.x;
  int c = tid & 127, half = tid >> 7;
  float s = 0.f, sq = 0.f;
  for (int r = blockIdx.x*2 + half; r < N_NODES; r += 512){
    float v = t[(size_t)r*HID + c];
    s += v; sq += v*v;
  }
  __shared__ float shs[2][128], shq[2][128];
  shs[half][c] = s; shq[half][c] = sq;
  __syncthreads();
  if (half == 0){
    atomicAdd(&bnsum[c], (double)(s + shs[1][c]));
    atomicAdd(&bnsq[c],  (double)(sq + shq[1][c]));
  }
}

__global__ void k_bnfinal(const double* __restrict__ bnsum, const double* __restrict__ bnsq,
                          float* __restrict__ mu, float* __restrict__ rstd){
  int c = threadIdx.x;
  double mean = bnsum[c] / (double)N_NODES;
  double var  = bnsq[c] / (double)N_NODES - mean*mean;
  mu[c] = (float)mean;
  rstd[c] = rsqrtf((float)var + EPS);
}

__global__ void k_apply(const float* __restrict__ t, const float* __restrict__ mu,
                        const float* __restrict__ rstd, const float* __restrict__ gamma,
                        const float* __restrict__ beta, float* __restrict__ h){
  int idx = blockIdx.x*blockDim.x + threadIdx.x;
  if (idx < N_NODES*32){
    int n = idx >> 5, q = idx & 31;
    float4 tv = ((const float4*)t)[(size_t)n*32 + q];
    float4 hv = ((float4*)h)[(size_t)n*32 + q];
    float4 g4 = ((const float4*)gamma)[q], b4 = ((const float4*)beta)[q];
    float4 m4 = ((const float4*)mu)[q],    r4 = ((const float4*)rstd)[q];
    hv.x += g4.x*(tv.x-m4.x)*r4.x + b4.x;
    hv.y += g4.y*(tv.y-m4.y)*r4.y + b4.y;
    hv.z += g4.z*(tv.z-m4.z)*r4.z + b4.z;
    hv.w += g4.w*(tv.w-m4.w)*r4.w + b4.w;
    ((float4*)h)[(size_t)n*32 + q] = hv;
  }
}

// ---------------- readout ----------------
__global__ void k_pool(const int* __restrict__ batch, const float* __restrict__ h,
                       float* __restrict__ gsum, float* __restrict__ gcnt){
  int idx = blockIdx.x*blockDim.x + threadIdx.x;
  if (idx < N_NODES*HID){
    int n = idx >> 7, c = idx & 127;
    int g = batch[n];
    atomicAdd(&gsum[(size_t)g*HID + c], h[(size_t)n*HID + c]);
    if (c == 0) atomicAdd(&gcnt[g], 1.f);
  }
}

__global__ void k_readout(const float* __restrict__ gsum, const float* __restrict__ gcnt,
                          const float* __restrict__ W1, const float* __restrict__ b1,
                          const float* __restrict__ W2, const float* __restrict__ b2,
                          const float* __restrict__ W3, const float* __restrict__ b3,
                          float* __restrict__ out){
  __shared__ float gl[128];
  __shared__ float a1[64];
  __shared__ float a2[32];
  int g = blockIdx.x, tid = threadIdx.x;
  float inv = 1.f / fmaxf(gcnt[g], 1.f);
  gl[tid]      = gsum[(size_t)g*HID + tid] * inv;
  gl[tid + 64] = gsum[(size_t)g*HID + 64 + tid] * inv;
  __syncthreads();
  {
    float s = b1[tid];
    for (int k = 0; k < 128; ++k) s = fmaf(gl[k], W1[k*64 + tid], s);
    a1[tid] = fmaxf(s, 0.f);
  }
  __syncthreads();
  if (tid < 32){
    float s = b2[tid];
    for (int k = 0; k < 64; ++k) s = fmaf(a1[k], W2[k*32 + tid], s);
    a2[tid] = fmaxf(s, 0.f);
  }
  __syncthreads();
  if (tid == 0){
    float s = b3[0];
    for (int k = 0; k < 32; ++k) s = fmaf(a2[k], W3[k], s);
    out[g] = s;
  }
}

// ---------------- launch ----------------
extern "C" void kernel_launch(void* const* d_in, const int* in_sizes, int n_in,
                              void* d_out, int out_size, void* d_ws, size_t ws_size,
                              hipStream_t stream) {
  const int*   x        = (const int*)  d_in[0];
  const int*   batch    = (const int*)  d_in[1];
  const int*   ei       = (const int*)  d_in[2];
  const float* snorm    = (const float*)d_in[3];
  const int*   eattr    = (const int*)  d_in[4];
  const float* atom_emb = (const float*)d_in[5];
  const float* bond_emb = (const float*)d_in[6];
  const float* pre_W    = (const float*)d_in[7];
  const float* pre_b    = (const float*)d_in[8];
  const float* post_W   = (const float*)d_in[9];
  const float* post_b   = (const float*)d_in[10];
  const float* mix_W    = (const float*)d_in[11];
  const float* mix_b    = (const float*)d_in[12];
  const float* bn_g     = (const float*)d_in[13];
  const float* bn_b     = (const float*)d_in[14];
  const float* rW1      = (const float*)d_in[15];
  const float* rb1      = (const float*)d_in[16];
  const float* rW2      = (const float*)d_in[17];
  const float* rb2      = (const float*)d_in[18];
  const float* rW3      = (const float*)d_in[19];
  const float* rb3      = (const float*)d_in[20];
  float* outp = (float*)d_out;

  const int* srcI = ei;            // edge_index[0]
  const int* dstI = ei + N_EDGES;  // edge_index[1]

  char* ws = (char*)d_ws;
  size_t o = 0;
  auto alloc = [&](size_t bytes)->char* {
    char* p = ws + o;
    o = (o + bytes + 255) & ~(size_t)255;
    return p;
  };
  int*    deg    = (int*)   alloc((size_t)N_NODES*4);
  int*    off    = (int*)   alloc((size_t)(N_NODES+1)*4);
  int*    cursor = (int*)   alloc((size_t)N_NODES*4);
  int*    srcS   = (int*)   alloc((size_t)N_EDGES*4);
  int*    eaS    = (int*)   alloc((size_t)N_EDGES*4);
  float*  invd   = (float*) alloc((size_t)N_NODES*4);
  float*  ampb   = (float*) alloc((size_t)N_NODES*4);
  float*  attb   = (float*) alloc((size_t)N_NODES*4);
  float*  h      = (float*) alloc((size_t)N_NODES*HID*4);
  float*  H1     = (float*) alloc((size_t)N_NODES*HID*4);
  float*  H2     = (float*) alloc((size_t)N_NODES*HID*4);
  float*  Yh     = (float*) alloc((size_t)N_NODES*HID*4);
  float*  Yamt   = (float*) alloc((size_t)N_NODES*384*4);
  float*  BW3    = (float*) alloc(512*4);
  float*  agg    = (float*) alloc((size_t)N_NODES*512*4);
  float*  ph     = (float*) alloc((size_t)N_NODES*HID*4);
  float*  tb     = (float*) alloc((size_t)N_NODES*HID*4);
  double* bnsum  = (double*)alloc(128*8);
  double* bnsq   = (double*)alloc(128*8);
  float*  mu     = (float*) alloc(128*4);
  float*  rstd   = (float*) alloc(128*4);
  float*  gsum   = (float*) alloc((size_t)N_GRAPHS*HID*4);
  float*  gcnt   = (float*) alloc((size_t)N_GRAPHS*4);

  hipMemsetAsync(deg, 0, (size_t)N_NODES*4, stream);
  hipMemsetAsync(cursor, 0, (size_t)N_NODES*4, stream);
  k_count<<<(N_EDGES+255)/256, 256, 0, stream>>>(dstI, deg);
  k_scan<<<1, 1024, 0, stream>>>(deg, off);
  k_fill<<<(N_EDGES+255)/256, 256, 0, stream>>>(srcI, dstI, eattr, off, cursor, srcS, eaS);
  k_scalars<<<(N_NODES+255)/256, 256, 0, stream>>>(deg, invd, ampb, attb);
  k_hinit<<<(N_NODES*32+255)/256, 256, 0, stream>>>(x, atom_emb, h);

  const int MB64 = (N_NODES + 63) / 64;   // 313
  const int MB32 = (N_NODES + 31) / 32;   // 625
  for (int l = 0; l < NLAYERS; ++l){
    const float* preWl  = pre_W  + (size_t)l*384*128;
    const float* postWl = post_W + (size_t)l*1664*128;
    // triple head GEMM on h: H1, H2, Yh
    k_gemm<0,32><<<dim3(MB32,3), 256, 0, stream>>>(
        preWl, preWl + 128*128, postWl, nullptr, h, nullptr, H1, H2, Yh);
    // 4-row bond table (+ pre_b folded in)
    k_bond<<<1, 512, 0, stream>>>(bond_emb, preWl + 256*128, pre_b + (size_t)l*128, BW3);
    // fused edge message + aggregation
    k_fusedagg<<<N_NODES/8, 256, 0, stream>>>(H1, H2, BW3, srcS, eaS, off, invd, agg);
    // agg GEMM: Yamt = agg @ [W_a | W_m | W_t]
    k_gemm<1,64><<<dim3(MB64,3), 256, 0, stream>>>(
        postWl + 128*128, nullptr, nullptr, nullptr, agg, nullptr, Yamt, nullptr, nullptr);
    // combine -> ph
    k_combine<<<(N_NODES*32+255)/256, 256, 0, stream>>>(
        Yh, Yamt, ampb, attb, post_b + (size_t)l*128, ph);
    // mix (+snorm)
    k_gemm<2,32><<<dim3(MB32,1), 256, 0, stream>>>(
        mix_W + (size_t)l*128*128, nullptr, nullptr, mix_b + (size_t)l*128,
        ph, snorm, tb, nullptr, nullptr);
    // BatchNorm + residual
    hipMemsetAsync(bnsum, 0, 128*8, stream);
    hipMemsetAsync(bnsq, 0, 128*8, stream);
    k_bnreduce<<<256, 256, 0, stream>>>(tb, bnsum, bnsq);
    k_bnfinal<<<1, 128, 0, stream>>>(bnsum, bnsq, mu, rstd);
    k_apply<<<(N_NODES*32+255)/256, 256, 0, stream>>>(tb, mu, rstd,
        bn_g + (size_t)l*128, bn_b + (size_t)l*128, h);
  }

  hipMemsetAsync(gsum, 0, (size_t)N_GRAPHS*HID*4, stream);
  hipMemsetAsync(gcnt, 0, (size_t)N_GRAPHS*4, stream);
  k_pool<<<(N_NODES*HID+255)/256, 256, 0, stream>>>(batch, h, gsum, gcnt);
  k_readout<<<N_GRAPHS, 64, 0, stream>>>(gsum, gcnt, rW1, rb1, rW2, rb2, rW3, rb3, outp);
}

// Round 4
// 739.042 us; speedup vs baseline: 3.6756x; 1.4915x over previous
//
#include <hip/hip_runtime.h>
#include <math.h>

#define N_NODES 20000
#define N_EDGES 320000
#define N_GRAPHS 256
#define HID 128
#define NLAYERS 4
#define AVG_LOG 2.833213344056216f
#define EPS 1e-5f

typedef __attribute__((ext_vector_type(8))) short short8;
typedef __attribute__((ext_vector_type(4))) float f32x4;

static __device__ __forceinline__ float leaky(float v){ return v > 0.f ? v : 0.01f*v; }

// round-to-nearest-even fp32 -> (hi, lo) bf16 pair, f ~= hi + lo
static __device__ __forceinline__ void bsplit(float f, unsigned short& hi, unsigned short& lo){
  unsigned int u = __float_as_uint(f);
  unsigned int r = u + 0x7FFFu + ((u>>16)&1u);
  hi = (unsigned short)(r>>16);
  float hf = __uint_as_float(((unsigned int)hi)<<16);
  float l = f - hf;
  unsigned int v = __float_as_uint(l);
  unsigned int s = v + 0x7FFFu + ((v>>16)&1u);
  lo = (unsigned short)(s>>16);
}

static __device__ __forceinline__ int sw4(int r){ return (r + (r>>2)) & 3; }

// ---------------- CSR build ----------------
__global__ void k_count(const int* __restrict__ dst, int* __restrict__ deg){
  int e = blockIdx.x*blockDim.x + threadIdx.x;
  if (e < N_EDGES) atomicAdd(&deg[dst[e]], 1);
}

__global__ void k_scan(const int* __restrict__ deg, int* __restrict__ off){
  __shared__ int buf[1024];
  int tid = threadIdx.x;
  int carry = 0;
  for (int base = 0; base < N_NODES; base += 1024){
    int i = base + tid;
    int v = (i < N_NODES) ? deg[i] : 0;
    buf[tid] = v;
    __syncthreads();
    for (int ofs = 1; ofs < 1024; ofs <<= 1){
      int tadd = (tid >= ofs) ? buf[tid-ofs] : 0;
      __syncthreads();
      buf[tid] += tadd;
      __syncthreads();
    }
    if (i < N_NODES) off[i] = carry + buf[tid] - v;  // exclusive
    carry += buf[1023];
    __syncthreads();
  }
  if (tid == 0) off[N_NODES] = carry;
}

__global__ void k_fill(const int* __restrict__ src, const int* __restrict__ dst,
                       const int* __restrict__ eattr, const int* __restrict__ off,
                       int* __restrict__ cursor,
                       int* __restrict__ srcS, int* __restrict__ eaS){
  int e = blockIdx.x*blockDim.x + threadIdx.x;
  if (e < N_EDGES){
    int d = dst[e];
    int pos = off[d] + atomicAdd(&cursor[d], 1);
    srcS[pos] = src[e]; eaS[pos] = eattr[e];
  }
}

__global__ void k_scalars(const int* __restrict__ deg, float* __restrict__ invd,
                          float* __restrict__ amp, float* __restrict__ att){
  int n = blockIdx.x*blockDim.x + threadIdx.x;
  if (n < N_NODES){
    float d = (float)deg[n];
    invd[n] = 1.f / fmaxf(d, 1.f);
    float ld = log1pf(d);
    amp[n] = ld / AVG_LOG;
    att[n] = AVG_LOG / fmaxf(ld, EPS);
  }
}

__global__ void k_hinit(const int* __restrict__ x, const float* __restrict__ atom_emb,
                        float* __restrict__ h){
  int idx = blockIdx.x*blockDim.x + threadIdx.x;
  if (idx < N_NODES*32){
    int n = idx >> 5, q = idx & 31;
    ((float4*)h)[(size_t)n*32 + q] = ((const float4*)atom_emb)[(size_t)x[n]*32 + q];
  }
}

// bond table: BW3[r][c] = bond_emb[r]@W3[:,c] + pre_b[c]   (4 x 128)
__global__ void k_bond(const float* __restrict__ bond_emb, const float* __restrict__ W3,
                       const float* __restrict__ pre_b, float* __restrict__ BW3){
  int tid = threadIdx.x;               // 512
  int r = tid >> 7, c = tid & 127;
  float s = pre_b[c];
  for (int k = 0; k < 128; ++k) s = fmaf(bond_emb[r*128 + k], W3[k*128 + c], s);
  BW3[tid] = s;
}

// ---------------- weight pre-transpose + bf16 hi/lo split ----------------
// per layer (262144 u16 per plane):
//   TH heads 0..2 (K=128): off = t*16384     src: preW[0:128], preW[128:256], postW[0:128]
//   AG heads 0..2 (K=512): off = 49152 + a*65536   src: postW[128+a*512 : ...]
//   MX (K=128):            off = 245760
// dst layout: [col 0..127][k 0..K-1]
__global__ void k_wt(const float* __restrict__ pre_W, const float* __restrict__ post_W,
                     const float* __restrict__ mix_W,
                     unsigned short* __restrict__ whi, unsigned short* __restrict__ wlo){
  int y = blockIdx.y; int l = y/7, j = y%7;
  int K = (j>=3 && j<6) ? 512 : 128;
  const float* src; size_t off;
  if (j < 2)      { src = pre_W  + (size_t)l*384*128  + (size_t)j*128*128;            off = (size_t)j*16384; }
  else if (j == 2){ src = post_W + (size_t)l*1664*128;                                off = 2*16384; }
  else if (j < 6) { src = post_W + (size_t)l*1664*128 + (size_t)(128+(j-3)*512)*128;  off = 49152 + (size_t)(j-3)*65536; }
  else            { src = mix_W  + (size_t)l*128*128;                                 off = 245760; }
  unsigned short* dh = whi + (size_t)l*262144 + off;
  unsigned short* dl = wlo + (size_t)l*262144 + off;
  int kq8 = K/8;
  int ntask = 128*kq8;
  int t = blockIdx.x*256 + threadIdx.x;
  if (t >= ntask) return;
  int c  = t / kq8;
  int k0 = (t % kq8)*8;
  unsigned short h8[8] __attribute__((aligned(16)));
  unsigned short l8[8] __attribute__((aligned(16)));
  #pragma unroll
  for (int i=0;i<8;++i) bsplit(src[(size_t)(k0+i)*128 + c], h8[i], l8[i]);
  *(uint4*)(dh + (size_t)c*K + k0) = *(const uint4*)h8;
  *(uint4*)(dl + (size_t)c*K + k0) = *(const uint4*)l8;
}

// ---------------- split-bf16 MFMA GEMM: out[M x 128] = A[M x K] @ W[K x 128] ----------------
// MODE 0: triple head, K=128, A=h, y selects head; out plane y (raw store)
// MODE 1: agg GEMM,  K=512, A=agg, y selects head; out col-block y of Yamt[.][384] (raw)
// MODE 2: mix,       K=128, A=ph; out = leaky(acc+bias)*snorm
// block: 256 thr = 4 waves (2x2), tile 64x128, wave tile 32x64 (2x4 frags of 16x16)
template<int MODE>
__global__ __launch_bounds__(256) void k_mf(
    const unsigned short* __restrict__ whi, const unsigned short* __restrict__ wlo,
    const float* __restrict__ A, const float* __restrict__ bias,
    const float* __restrict__ snorm, float* __restrict__ out)
{
  const int K    = (MODE==1) ? 512 : 128;
  const int ASTR = (MODE==1) ? 512 : 128;
  const int OSTR = (MODE==1) ? 384 : 128;
  __shared__ unsigned short Ah[64*32], Al[64*32], Bh[128*32], Bl[128*32];
  int tid = threadIdx.x;
  int lane = tid & 63;
  int wv = tid >> 6;
  int wm = (wv>>1)*32, wn = (wv&1)*64;
  int mbase = blockIdx.x*64;
  int y = blockIdx.y;
  const unsigned short* wh = whi + (size_t)y*K*128;
  const unsigned short* wl = wlo + (size_t)y*K*128;
  float* outp = out; int ocol = 0;
  if (MODE == 0) outp = out + (size_t)y*N_NODES*128;
  if (MODE == 1) ocol = y*128;

  // A staging assignment: one (row, 8k) task per thread
  int a_row = tid >> 2, a_kg = tid & 3;
  int a_nrow = min(mbase + a_row, N_NODES-1);
  const float* a_src = A + (size_t)a_nrow*ASTR + a_kg*8;
  int a_slot = a_kg ^ sw4(a_row);
  unsigned short* a_dh = Ah + a_row*32 + a_slot*8;
  unsigned short* a_dl = Al + a_row*32 + a_slot*8;

  f32x4 acc[2][4];
  #pragma unroll
  for (int mi=0;mi<2;++mi)
    #pragma unroll
    for (int ni=0;ni<4;++ni)
      acc[mi][ni] = (f32x4){0.f,0.f,0.f,0.f};

  int lr = lane & 15, lk = lane >> 4;

  for (int kt = 0; kt < K; kt += 32){
    // stage B (both planes), 2 16B-slots per thread per plane
    #pragma unroll
    for (int i=0;i<2;++i){
      int s = tid + 256*i;
      int col = s >> 2, kg = s & 3;
      int slot = kg ^ sw4(col);
      *(uint4*)(Bh + col*32 + slot*8) = *(const uint4*)(wh + (size_t)col*K + kt + kg*8);
      *(uint4*)(Bl + col*32 + slot*8) = *(const uint4*)(wl + (size_t)col*K + kt + kg*8);
    }
    // stage A: read 8 fp32, split, write hi/lo b128
    {
      float4 f0 = *(const float4*)(a_src + kt);
      float4 f1 = *(const float4*)(a_src + kt + 4);
      float fv[8] = {f0.x,f0.y,f0.z,f0.w,f1.x,f1.y,f1.z,f1.w};
      unsigned short h8[8] __attribute__((aligned(16)));
      unsigned short l8[8] __attribute__((aligned(16)));
      #pragma unroll
      for (int i=0;i<8;++i) bsplit(fv[i], h8[i], l8[i]);
      *(uint4*)a_dh = *(const uint4*)h8;
      *(uint4*)a_dl = *(const uint4*)l8;
    }
    __syncthreads();
    // fragment loads
    short8 ah[2], al[2], bh4[4], bl4[4];
    #pragma unroll
    for (int mi=0;mi<2;++mi){
      int row = wm + mi*16 + lr;
      int idx = row*32 + ((lk ^ sw4(row))*8);
      ah[mi] = *(const short8*)(Ah + idx);
      al[mi] = *(const short8*)(Al + idx);
    }
    #pragma unroll
    for (int ni=0;ni<4;++ni){
      int col = wn + ni*16 + lr;
      int idx = col*32 + ((lk ^ sw4(col))*8);
      bh4[ni] = *(const short8*)(Bh + idx);
      bl4[ni] = *(const short8*)(Bl + idx);
    }
    // 3-term split-bf16 MFMA
    #pragma unroll
    for (int mi=0;mi<2;++mi){
      #pragma unroll
      for (int ni=0;ni<4;++ni){
        acc[mi][ni] = __builtin_amdgcn_mfma_f32_16x16x32_bf16(ah[mi], bh4[ni], acc[mi][ni], 0,0,0);
        acc[mi][ni] = __builtin_amdgcn_mfma_f32_16x16x32_bf16(ah[mi], bl4[ni], acc[mi][ni], 0,0,0);
        acc[mi][ni] = __builtin_amdgcn_mfma_f32_16x16x32_bf16(al[mi], bh4[ni], acc[mi][ni], 0,0,0);
      }
    }
    __syncthreads();
  }

  // epilogue: D mapping col=lane&15, row=(lane>>4)*4+reg
  #pragma unroll
  for (int mi=0;mi<2;++mi){
    #pragma unroll
    for (int ni=0;ni<4;++ni){
      int gcol = wn + ni*16 + lr;
      float bv = 0.f;
      if (MODE == 2) bv = bias[gcol];
      #pragma unroll
      for (int r=0;r<4;++r){
        int grow = mbase + wm + mi*16 + lk*4 + r;
        if (grow < N_NODES){
          float v = acc[mi][ni][r];
          if (MODE == 2) v = leaky(v + bv) * snorm[grow];
          outp[(size_t)grow*OSTR + ocol + gcol] = v;
        }
      }
    }
  }
}

// combine: ph = leaky(Yh + Ya + amp*Ym + att*Yt + post_b)
__global__ void k_combine(const float* __restrict__ Yh, const float* __restrict__ Yamt,
                          const float* __restrict__ amp, const float* __restrict__ att,
                          const float* __restrict__ post_b, float* __restrict__ ph){
  int idx = blockIdx.x*blockDim.x + threadIdx.x;
  if (idx < N_NODES*32){
    int n = idx >> 5, q = idx & 31;
    float av = amp[n], tv = att[n];
    float4 yh = ((const float4*)(Yh + (size_t)n*128))[q];
    const float4* yr = (const float4*)(Yamt + (size_t)n*384);
    float4 ya = yr[q], ym = yr[q+32], yt = yr[q+64];
    float4 b4 = ((const float4*)post_b)[q];
    float4 r;
    r.x = leaky(yh.x + ya.x + av*ym.x + tv*yt.x + b4.x);
    r.y = leaky(yh.y + ya.y + av*ym.y + tv*yt.y + b4.y);
    r.z = leaky(yh.z + ya.z + av*ym.z + tv*yt.z + b4.z);
    r.w = leaky(yh.w + ya.w + av*ym.w + tv*yt.w + b4.w);
    ((float4*)(ph + (size_t)n*128))[q] = r;
  }
}

// ---------------- fused edge-message + aggregation ----------------
__global__ __launch_bounds__(256) void k_fusedagg(
    const float* __restrict__ H1, const float* __restrict__ H2,
    const float* __restrict__ BW3,
    const int* __restrict__ srcS, const int* __restrict__ eaS,
    const int* __restrict__ off, const float* __restrict__ invd,
    float* __restrict__ agg)
{
  __shared__ float bw[4][128];
  int tid = threadIdx.x;
  bw[tid>>7][tid&127]     = BW3[tid];
  bw[2+(tid>>7)][tid&127] = BW3[256+tid];
  __syncthreads();

  int node = blockIdx.x*8 + (tid>>5);
  int q = tid & 31;
  float4 c4 = ((const float4*)(H1 + (size_t)node*HID))[q];
  int s = off[node], e = off[node+1];
  float4 sum = make_float4(0,0,0,0), sq = make_float4(0,0,0,0);
  float4 mx = make_float4(-3.4e38f,-3.4e38f,-3.4e38f,-3.4e38f);
  float4 mn = make_float4( 3.4e38f, 3.4e38f, 3.4e38f, 3.4e38f);
  for (int i = s; i < e; ++i){
    int sv = srcS[i], ev = eaS[i];
    float4 t  = ((const float4*)(H2 + (size_t)sv*HID))[q];
    float4 b4 = ((const float4*)(&bw[ev][0]))[q];
    float vx = leaky(c4.x + t.x + b4.x);
    float vy = leaky(c4.y + t.y + b4.y);
    float vz = leaky(c4.z + t.z + b4.z);
    float vw = leaky(c4.w + t.w + b4.w);
    sum.x += vx; sum.y += vy; sum.z += vz; sum.w += vw;
    sq.x += vx*vx; sq.y += vy*vy; sq.z += vz*vz; sq.w += vw*vw;
    mx.x = fmaxf(mx.x, vx); mx.y = fmaxf(mx.y, vy); mx.z = fmaxf(mx.z, vz); mx.w = fmaxf(mx.w, vw);
    mn.x = fminf(mn.x, vx); mn.y = fminf(mn.y, vy); mn.z = fminf(mn.z, vz); mn.w = fminf(mn.w, vw);
  }
  bool has = (e > s);
  float iv = invd[node];
  float4 mean = make_float4(sum.x*iv, sum.y*iv, sum.z*iv, sum.w*iv);
  float4 msq  = make_float4(sq.x*iv,  sq.y*iv,  sq.z*iv,  sq.w*iv);
  float4 sd;
  sd.x = has ? sqrtf(fmaxf(msq.x - mean.x*mean.x, 0.f) + EPS) : 0.f;
  sd.y = has ? sqrtf(fmaxf(msq.y - mean.y*mean.y, 0.f) + EPS) : 0.f;
  sd.z = has ? sqrtf(fmaxf(msq.z - mean.z*mean.z, 0.f) + EPS) : 0.f;
  sd.w = has ? sqrtf(fmaxf(msq.w - mean.w*mean.w, 0.f) + EPS) : 0.f;
  if (!has){ mx = make_float4(0,0,0,0); mn = make_float4(0,0,0,0); }
  size_t base = (size_t)node*512;
  ((float4*)(agg + base      ))[q] = mean;
  ((float4*)(agg + base + 128))[q] = mx;
  ((float4*)(agg + base + 256))[q] = mn;
  ((float4*)(agg + base + 384))[q] = sd;
}

// ---------------- BatchNorm ----------------
__global__ void k_bnreduce(const float* __restrict__ t, double* __restrict__ bnsum,
                           double* __restrict__ bnsq){
  int tid = threadIdx.x;
  int c = tid & 127, half = tid >> 7;
  float s = 0.f, sq = 0.f;
  for (int r = blockIdx.x*2 + half; r < N_NODES; r += 512){
    float v = t[(size_t)r*HID + c];
    s += v; sq += v*v;
  }
  __shared__ float shs[2][128], shq[2][128];
  shs[half][c] = s; shq[half][c] = sq;
  __syncthreads();
  if (half == 0){
    atomicAdd(&bnsum[c], (double)(s + shs[1][c]));
    atomicAdd(&bnsq[c],  (double)(sq + shq[1][c]));
  }
}

__global__ void k_bnfinal(const double* __restrict__ bnsum, const double* __restrict__ bnsq,
                          float* __restrict__ mu, float* __restrict__ rstd){
  int c = threadIdx.x;
  double mean = bnsum[c] / (double)N_NODES;
  double var  = bnsq[c] / (double)N_NODES - mean*mean;
  mu[c] = (float)mean;
  rstd[c] = rsqrtf((float)var + EPS);
}

__global__ void k_apply(const float* __restrict__ t, const float* __restrict__ mu,
                        const float* __restrict__ rstd, const float* __restrict__ gamma,
                        const float* __restrict__ beta, float* __restrict__ h){
  int idx = blockIdx.x*blockDim.x + threadIdx.x;
  if (idx < N_NODES*32){
    int n = idx >> 5, q = idx & 31;
    float4 tv = ((const float4*)t)[(size_t)n*32 + q];
    float4 hv = ((float4*)h)[(size_t)n*32 + q];
    float4 g4 = ((const float4*)gamma)[q], b4 = ((const float4*)beta)[q];
    float4 m4 = ((const float4*)mu)[q],    r4 = ((const float4*)rstd)[q];
    hv.x += g4.x*(tv.x-m4.x)*r4.x + b4.x;
    hv.y += g4.y*(tv.y-m4.y)*r4.y + b4.y;
    hv.z += g4.z*(tv.z-m4.z)*r4.z + b4.z;
    hv.w += g4.w*(tv.w-m4.w)*r4.w + b4.w;
    ((float4*)h)[(size_t)n*32 + q] = hv;
  }
}

// ---------------- readout ----------------
__global__ void k_pool(const int* __restrict__ batch, const float* __restrict__ h,
                       float* __restrict__ gsum, float* __restrict__ gcnt){
  int idx = blockIdx.x*blockDim.x + threadIdx.x;
  if (idx < N_NODES*HID){
    int n = idx >> 7, c = idx & 127;
    int g = batch[n];
    atomicAdd(&gsum[(size_t)g*HID + c], h[(size_t)n*HID + c]);
    if (c == 0) atomicAdd(&gcnt[g], 1.f);
  }
}

__global__ void k_readout(const float* __restrict__ gsum, const float* __restrict__ gcnt,
                          const float* __restrict__ W1, const float* __restrict__ b1,
                          const float* __restrict__ W2, const float* __restrict__ b2,
                          const float* __restrict__ W3, const float* __restrict__ b3,
                          float* __restrict__ out){
  __shared__ float gl[128];
  __shared__ float a1[64];
  __shared__ float a2[32];
  int g = blockIdx.x, tid = threadIdx.x;
  float inv = 1.f / fmaxf(gcnt[g], 1.f);
  gl[tid]      = gsum[(size_t)g*HID + tid] * inv;
  gl[tid + 64] = gsum[(size_t)g*HID + 64 + tid] * inv;
  __syncthreads();
  {
    float s = b1[tid];
    for (int k = 0; k < 128; ++k) s = fmaf(gl[k], W1[k*64 + tid], s);
    a1[tid] = fmaxf(s, 0.f);
  }
  __syncthreads();
  if (tid < 32){
    float s = b2[tid];
    for (int k = 0; k < 64; ++k) s = fmaf(a1[k], W2[k*32 + tid], s);
    a2[tid] = fmaxf(s, 0.f);
  }
  __syncthreads();
  if (tid == 0){
    float s = b3[0];
    for (int k = 0; k < 32; ++k) s = fmaf(a2[k], W3[k], s);
    out[g] = s;
  }
}

// ---------------- launch ----------------
extern "C" void kernel_launch(void* const* d_in, const int* in_sizes, int n_in,
                              void* d_out, int out_size, void* d_ws, size_t ws_size,
                              hipStream_t stream) {
  const int*   x        = (const int*)  d_in[0];
  const int*   batch    = (const int*)  d_in[1];
  const int*   ei       = (const int*)  d_in[2];
  const float* snorm    = (const float*)d_in[3];
  const int*   eattr    = (const int*)  d_in[4];
  const float* atom_emb = (const float*)d_in[5];
  const float* bond_emb = (const float*)d_in[6];
  const float* pre_W    = (const float*)d_in[7];
  const float* pre_b    = (const float*)d_in[8];
  const float* post_W   = (const float*)d_in[9];
  const float* post_b   = (const float*)d_in[10];
  const float* mix_W    = (const float*)d_in[11];
  const float* mix_b    = (const float*)d_in[12];
  const float* bn_g     = (const float*)d_in[13];
  const float* bn_b     = (const float*)d_in[14];
  const float* rW1      = (const float*)d_in[15];
  const float* rb1      = (const float*)d_in[16];
  const float* rW2      = (const float*)d_in[17];
  const float* rb2      = (const float*)d_in[18];
  const float* rW3      = (const float*)d_in[19];
  const float* rb3      = (const float*)d_in[20];
  float* outp = (float*)d_out;

  const int* srcI = ei;            // edge_index[0]
  const int* dstI = ei + N_EDGES;  // edge_index[1]

  char* ws = (char*)d_ws;
  size_t o = 0;
  auto alloc = [&](size_t bytes)->char* {
    char* p = ws + o;
    o = (o + bytes + 255) & ~(size_t)255;
    return p;
  };
  int*    deg    = (int*)   alloc((size_t)N_NODES*4);
  int*    off    = (int*)   alloc((size_t)(N_NODES+1)*4);
  int*    cursor = (int*)   alloc((size_t)N_NODES*4);
  int*    srcS   = (int*)   alloc((size_t)N_EDGES*4);
  int*    eaS    = (int*)   alloc((size_t)N_EDGES*4);
  float*  invd   = (float*) alloc((size_t)N_NODES*4);
  float*  ampb   = (float*) alloc((size_t)N_NODES*4);
  float*  attb   = (float*) alloc((size_t)N_NODES*4);
  float*  h      = (float*) alloc((size_t)N_NODES*HID*4);
  float*  H3     = (float*) alloc((size_t)3*N_NODES*HID*4);   // H1 | H2 | Yh
  float*  Yamt   = (float*) alloc((size_t)N_NODES*384*4);
  float*  BW3    = (float*) alloc(512*4);
  float*  agg    = (float*) alloc((size_t)N_NODES*512*4);
  float*  ph     = (float*) alloc((size_t)N_NODES*HID*4);
  float*  tb     = (float*) alloc((size_t)N_NODES*HID*4);
  unsigned short* whi = (unsigned short*)alloc((size_t)NLAYERS*262144*2);
  unsigned short* wlo = (unsigned short*)alloc((size_t)NLAYERS*262144*2);
  double* bnsum  = (double*)alloc(128*8);
  double* bnsq   = (double*)alloc(128*8);
  float*  mu     = (float*) alloc(128*4);
  float*  rstd   = (float*) alloc(128*4);
  float*  gsum   = (float*) alloc((size_t)N_GRAPHS*HID*4);
  float*  gcnt   = (float*) alloc((size_t)N_GRAPHS*4);

  hipMemsetAsync(deg, 0, (size_t)N_NODES*4, stream);
  hipMemsetAsync(cursor, 0, (size_t)N_NODES*4, stream);
  k_count<<<(N_EDGES+255)/256, 256, 0, stream>>>(dstI, deg);
  k_scan<<<1, 1024, 0, stream>>>(deg, off);
  k_fill<<<(N_EDGES+255)/256, 256, 0, stream>>>(srcI, dstI, eattr, off, cursor, srcS, eaS);
  k_scalars<<<(N_NODES+255)/256, 256, 0, stream>>>(deg, invd, ampb, attb);
  k_hinit<<<(N_NODES*32+255)/256, 256, 0, stream>>>(x, atom_emb, h);
  k_wt<<<dim3(32, NLAYERS*7), 256, 0, stream>>>(pre_W, post_W, mix_W, whi, wlo);

  const int MB64 = (N_NODES + 63) / 64;   // 313
  float* H1 = H3;
  float* H2 = H3 + (size_t)N_NODES*HID;
  float* Yh = H3 + (size_t)2*N_NODES*HID;
  for (int l = 0; l < NLAYERS; ++l){
    const unsigned short* whl = whi + (size_t)l*262144;
    const unsigned short* wll = wlo + (size_t)l*262144;
    const float* preWl  = pre_W  + (size_t)l*384*128;
    // triple head GEMM on h: H1, H2, Yh
    k_mf<0><<<dim3(MB64,3), 256, 0, stream>>>(whl, wll, h, nullptr, nullptr, H3);
    // 4-row bond table (+ pre_b folded in)
    k_bond<<<1, 512, 0, stream>>>(bond_emb, preWl + 256*128, pre_b + (size_t)l*128, BW3);
    // fused edge message + aggregation
    k_fusedagg<<<N_NODES/8, 256, 0, stream>>>(H1, H2, BW3, srcS, eaS, off, invd, agg);
    // agg GEMM: Yamt = agg @ [W_a | W_m | W_t]
    k_mf<1><<<dim3(MB64,3), 256, 0, stream>>>(whl + 49152, wll + 49152, agg, nullptr, nullptr, Yamt);
    // combine -> ph
    k_combine<<<(N_NODES*32+255)/256, 256, 0, stream>>>(
        Yh, Yamt, ampb, attb, post_b + (size_t)l*128, ph);
    // mix (+snorm)
    k_mf<2><<<dim3(MB64,1), 256, 0, stream>>>(whl + 245760, wll + 245760, ph,
        mix_b + (size_t)l*128, snorm, tb);
    // BatchNorm + residual
    hipMemsetAsync(bnsum, 0, 128*8, stream);
    hipMemsetAsync(bnsq, 0, 128*8, stream);
    k_bnreduce<<<256, 256, 0, stream>>>(tb, bnsum, bnsq);
    k_bnfinal<<<1, 128, 0, stream>>>(bnsum, bnsq, mu, rstd);
    k_apply<<<(N_NODES*32+255)/256, 256, 0, stream>>>(tb, mu, rstd,
        bn_g + (size_t)l*128, bn_b + (size_t)l*128, h);
  }

  hipMemsetAsync(gsum, 0, (size_t)N_GRAPHS*HID*4, stream);
  hipMemsetAsync(gcnt, 0, (size_t)N_GRAPHS*4, stream);
  k_pool<<<(N_NODES*HID+255)/256, 256, 0, stream>>>(batch, h, gsum, gcnt);
  k_readout<<<N_GRAPHS, 64, 0, stream>>>(gsum, gcnt, rW1, rb1, rW2, rb2, rW3, rb3, outp);
}

// Round 5
// 721.657 us; speedup vs baseline: 3.7642x; 1.0241x over previous
//
#include <hip/hip_runtime.h>
#include <math.h>

#define N_NODES 20000
#define N_EDGES 320000
#define N_GRAPHS 256
#define HID 128
#define NLAYERS 4
#define AVG_LOG 2.833213344056216f
#define EPS 1e-5f
#define MB64 313   // ceil(N_NODES/64)

typedef __attribute__((ext_vector_type(8))) short short8;
typedef __attribute__((ext_vector_type(4))) float f32x4;

static __device__ __forceinline__ float leaky(float v){ return v > 0.f ? v : 0.01f*v; }

// round-to-nearest-even fp32 -> (hi, lo) bf16 pair, f ~= hi + lo
static __device__ __forceinline__ void bsplit(float f, unsigned short& hi, unsigned short& lo){
  unsigned int u = __float_as_uint(f);
  unsigned int r = u + 0x7FFFu + ((u>>16)&1u);
  hi = (unsigned short)(r>>16);
  float hf = __uint_as_float(((unsigned int)hi)<<16);
  float l = f - hf;
  unsigned int v = __float_as_uint(l);
  unsigned int s = v + 0x7FFFu + ((v>>16)&1u);
  lo = (unsigned short)(s>>16);
}

static __device__ __forceinline__ int sw4(int r){ return (r + (r>>2)) & 3; }

// ---------------- CSR build ----------------
__global__ void k_count(const int* __restrict__ dst, int* __restrict__ deg){
  int e = blockIdx.x*blockDim.x + threadIdx.x;
  if (e < N_EDGES) atomicAdd(&deg[dst[e]], 1);
}

// single-pass scan (20 elems/thread) + degree scalers
__global__ __launch_bounds__(1024) void k_scanscal(
    const int* __restrict__ deg, int* __restrict__ off,
    float* __restrict__ invd, float* __restrict__ amp, float* __restrict__ att){
  __shared__ int buf[1024];
  int tid = threadIdx.x;
  int base = tid*20;
  int loc[20]; int tot = 0;
  if (tid < 1000){
    #pragma unroll
    for (int i=0;i<20;++i){ loc[i] = tot; tot += deg[base+i]; }
  }
  buf[tid] = tot;
  __syncthreads();
  for (int ofs = 1; ofs < 1024; ofs <<= 1){
    int t2 = (tid >= ofs) ? buf[tid-ofs] : 0;
    __syncthreads();
    buf[tid] += t2;
    __syncthreads();
  }
  int excl = buf[tid] - tot;
  if (tid < 1000){
    for (int i=0;i<20;++i){
      int idx = base + i;
      off[idx] = excl + loc[i];
      float d = (float)deg[idx];
      invd[idx] = 1.f / fmaxf(d, 1.f);
      float ld = log1pf(d);
      amp[idx] = ld / AVG_LOG;
      att[idx] = AVG_LOG / fmaxf(ld, EPS);
    }
  }
  if (tid == 1023) off[N_NODES] = buf[1023];
}

__global__ void k_fill(const int* __restrict__ src, const int* __restrict__ dst,
                       const int* __restrict__ eattr, const int* __restrict__ off,
                       int* __restrict__ cursor,
                       int* __restrict__ srcS, int* __restrict__ eaS){
  int e = blockIdx.x*blockDim.x + threadIdx.x;
  if (e < N_EDGES){
    int d = dst[e];
    int pos = off[d] + atomicAdd(&cursor[d], 1);
    srcS[pos] = src[e]; eaS[pos] = eattr[e];
  }
}

// graph offsets via binary search on sorted batch
__global__ void k_goff(const int* __restrict__ batch, int* __restrict__ goff){
  int g = threadIdx.x;
  if (g <= N_GRAPHS){
    int lo = 0, hi = N_NODES;
    while (lo < hi){ int mid = (lo+hi)>>1; if (batch[mid] < g) lo = mid+1; else hi = mid; }
    goff[g] = lo;
  }
}

__global__ void k_hinit(const int* __restrict__ x, const float* __restrict__ atom_emb,
                        float* __restrict__ h){
  int idx = blockIdx.x*blockDim.x + threadIdx.x;
  if (idx < N_NODES*32){
    int n = idx >> 5, q = idx & 31;
    ((float4*)h)[(size_t)n*32 + q] = ((const float4*)atom_emb)[(size_t)x[n]*32 + q];
  }
}

// bond table: BW3[r][c] = bond_emb[r]@W3[:,c] + pre_b[c]   (4 x 128)
__global__ void k_bond(const float* __restrict__ bond_emb, const float* __restrict__ W3,
                       const float* __restrict__ pre_b, float* __restrict__ BW3){
  int tid = threadIdx.x;               // 512
  int r = tid >> 7, c = tid & 127;
  float s = pre_b[c];
  for (int k = 0; k < 128; ++k) s = fmaf(bond_emb[r*128 + k], W3[k*128 + c], s);
  BW3[tid] = s;
}

// ---------------- weight pre-transpose + bf16 hi/lo split ----------------
__global__ void k_wt(const float* __restrict__ pre_W, const float* __restrict__ post_W,
                     const float* __restrict__ mix_W,
                     unsigned short* __restrict__ whi, unsigned short* __restrict__ wlo){
  int y = blockIdx.y; int l = y/7, j = y%7;
  int K = (j>=3 && j<6) ? 512 : 128;
  const float* src; size_t off;
  if (j < 2)      { src = pre_W  + (size_t)l*384*128  + (size_t)j*128*128;            off = (size_t)j*16384; }
  else if (j == 2){ src = post_W + (size_t)l*1664*128;                                off = 2*16384; }
  else if (j < 6) { src = post_W + (size_t)l*1664*128 + (size_t)(128+(j-3)*512)*128;  off = 49152 + (size_t)(j-3)*65536; }
  else            { src = mix_W  + (size_t)l*128*128;                                 off = 245760; }
  unsigned short* dh = whi + (size_t)l*262144 + off;
  unsigned short* dl = wlo + (size_t)l*262144 + off;
  int kq8 = K/8;
  int ntask = 128*kq8;
  int t = blockIdx.x*256 + threadIdx.x;
  if (t >= ntask) return;
  int c  = t / kq8;
  int k0 = (t % kq8)*8;
  unsigned short h8[8] __attribute__((aligned(16)));
  unsigned short l8[8] __attribute__((aligned(16)));
  #pragma unroll
  for (int i=0;i<8;++i) bsplit(src[(size_t)(k0+i)*128 + c], h8[i], l8[i]);
  *(uint4*)(dh + (size_t)c*K + k0) = *(const uint4*)h8;
  *(uint4*)(dl + (size_t)c*K + k0) = *(const uint4*)l8;
}

// ---------------- split-bf16 MFMA GEMM (MODE 0: triple head K=128; MODE 1: agg K=512) ----------------
template<int MODE>
__global__ __launch_bounds__(256) void k_mf(
    const unsigned short* __restrict__ whi, const unsigned short* __restrict__ wlo,
    const float* __restrict__ A, float* __restrict__ out)
{
  const int K    = (MODE==1) ? 512 : 128;
  const int ASTR = (MODE==1) ? 512 : 128;
  const int OSTR = (MODE==1) ? 384 : 128;
  __shared__ unsigned short Ah[64*32], Al[64*32], Bh[128*32], Bl[128*32];
  int tid = threadIdx.x;
  int lane = tid & 63;
  int wv = tid >> 6;
  int wm = (wv>>1)*32, wn = (wv&1)*64;
  int mbase = blockIdx.x*64;
  int y = blockIdx.y;
  const unsigned short* wh = whi + (size_t)y*K*128;
  const unsigned short* wl = wlo + (size_t)y*K*128;
  float* outp = out; int ocol = 0;
  if (MODE == 0) outp = out + (size_t)y*N_NODES*128;
  if (MODE == 1) ocol = y*128;

  int a_row = tid >> 2, a_kg = tid & 3;
  int a_nrow = min(mbase + a_row, N_NODES-1);
  const float* a_src = A + (size_t)a_nrow*ASTR + a_kg*8;
  int a_slot = a_kg ^ sw4(a_row);
  unsigned short* a_dh = Ah + a_row*32 + a_slot*8;
  unsigned short* a_dl = Al + a_row*32 + a_slot*8;

  f32x4 acc[2][4];
  #pragma unroll
  for (int mi=0;mi<2;++mi)
    #pragma unroll
    for (int ni=0;ni<4;++ni)
      acc[mi][ni] = (f32x4){0.f,0.f,0.f,0.f};

  int lr = lane & 15, lk = lane >> 4;

  for (int kt = 0; kt < K; kt += 32){
    #pragma unroll
    for (int i=0;i<2;++i){
      int s = tid + 256*i;
      int col = s >> 2, kg = s & 3;
      int slot = kg ^ sw4(col);
      *(uint4*)(Bh + col*32 + slot*8) = *(const uint4*)(wh + (size_t)col*K + kt + kg*8);
      *(uint4*)(Bl + col*32 + slot*8) = *(const uint4*)(wl + (size_t)col*K + kt + kg*8);
    }
    {
      float4 f0 = *(const float4*)(a_src + kt);
      float4 f1 = *(const float4*)(a_src + kt + 4);
      float fv[8] = {f0.x,f0.y,f0.z,f0.w,f1.x,f1.y,f1.z,f1.w};
      unsigned short h8[8] __attribute__((aligned(16)));
      unsigned short l8[8] __attribute__((aligned(16)));
      #pragma unroll
      for (int i=0;i<8;++i) bsplit(fv[i], h8[i], l8[i]);
      *(uint4*)a_dh = *(const uint4*)h8;
      *(uint4*)a_dl = *(const uint4*)l8;
    }
    __syncthreads();
    short8 ah[2], al[2], bh4[4], bl4[4];
    #pragma unroll
    for (int mi=0;mi<2;++mi){
      int row = wm + mi*16 + lr;
      int idx = row*32 + ((lk ^ sw4(row))*8);
      ah[mi] = *(const short8*)(Ah + idx);
      al[mi] = *(const short8*)(Al + idx);
    }
    #pragma unroll
    for (int ni=0;ni<4;++ni){
      int col = wn + ni*16 + lr;
      int idx = col*32 + ((lk ^ sw4(col))*8);
      bh4[ni] = *(const short8*)(Bh + idx);
      bl4[ni] = *(const short8*)(Bl + idx);
    }
    #pragma unroll
    for (int mi=0;mi<2;++mi){
      #pragma unroll
      for (int ni=0;ni<4;++ni){
        acc[mi][ni] = __builtin_amdgcn_mfma_f32_16x16x32_bf16(ah[mi], bh4[ni], acc[mi][ni], 0,0,0);
        acc[mi][ni] = __builtin_amdgcn_mfma_f32_16x16x32_bf16(ah[mi], bl4[ni], acc[mi][ni], 0,0,0);
        acc[mi][ni] = __builtin_amdgcn_mfma_f32_16x16x32_bf16(al[mi], bh4[ni], acc[mi][ni], 0,0,0);
      }
    }
    __syncthreads();
  }

  #pragma unroll
  for (int mi=0;mi<2;++mi){
    #pragma unroll
    for (int ni=0;ni<4;++ni){
      int gcol = wn + ni*16 + lr;
      #pragma unroll
      for (int r=0;r<4;++r){
        int grow = mbase + wm + mi*16 + lk*4 + r;
        if (grow < N_NODES)
          outp[(size_t)grow*OSTR + ocol + gcol] = acc[mi][ni][r];
      }
    }
  }
}

// ---------------- mix GEMM with fused combine (A-staging) + fused BN partials ----------------
// A[n][c] = leaky(Yh[n][c] + Ya[n][c] + amp[n]*Ym[n][c] + att[n]*Yt[n][c] + post_b[c])
// out tb[n][c] = leaky(acc + mix_b[c]) * snorm[n];  bnpart[bid][0:128]=colsum, [128:256]=colsumsq
__global__ __launch_bounds__(256) void k_mix(
    const unsigned short* __restrict__ wh, const unsigned short* __restrict__ wl,
    const float* __restrict__ Yh, const float* __restrict__ Yamt,
    const float* __restrict__ amp, const float* __restrict__ att,
    const float* __restrict__ post_b, const float* __restrict__ mix_b,
    const float* __restrict__ snorm,
    float* __restrict__ tb, float* __restrict__ bnpart)
{
  __shared__ unsigned short Ah[64*32], Al[64*32], Bh[128*32], Bl[128*32];
  __shared__ float bns[2][128], bnq[2][128];
  int tid = threadIdx.x;
  int lane = tid & 63;
  int wv = tid >> 6;
  int wm = (wv>>1)*32, wn = (wv&1)*64;
  int mbase = blockIdx.x*64;

  int a_row = tid >> 2, a_kg = tid & 3;
  int a_nrow = min(mbase + a_row, N_NODES-1);
  float av = amp[a_nrow], tv2 = att[a_nrow];
  const float* yhp = Yh   + (size_t)a_nrow*128;
  const float* yap = Yamt + (size_t)a_nrow*384;
  int a_slot = a_kg ^ sw4(a_row);
  unsigned short* a_dh = Ah + a_row*32 + a_slot*8;
  unsigned short* a_dl = Al + a_row*32 + a_slot*8;

  f32x4 acc[2][4];
  #pragma unroll
  for (int mi=0;mi<2;++mi)
    #pragma unroll
    for (int ni=0;ni<4;++ni)
      acc[mi][ni] = (f32x4){0.f,0.f,0.f,0.f};

  int lr = lane & 15, lk = lane >> 4;

  for (int kt = 0; kt < 128; kt += 32){
    #pragma unroll
    for (int i=0;i<2;++i){
      int s = tid + 256*i;
      int col = s >> 2, kg = s & 3;
      int slot = kg ^ sw4(col);
      *(uint4*)(Bh + col*32 + slot*8) = *(const uint4*)(wh + (size_t)col*128 + kt + kg*8);
      *(uint4*)(Bl + col*32 + slot*8) = *(const uint4*)(wl + (size_t)col*128 + kt + kg*8);
    }
    {
      int c0 = kt + a_kg*8;
      float4 h0 = *(const float4*)(yhp + c0),       h1 = *(const float4*)(yhp + c0 + 4);
      float4 a0 = *(const float4*)(yap + c0),       a1 = *(const float4*)(yap + c0 + 4);
      float4 m0 = *(const float4*)(yap + 128 + c0), m1 = *(const float4*)(yap + 132 + c0);
      float4 t0 = *(const float4*)(yap + 256 + c0), t1 = *(const float4*)(yap + 260 + c0);
      float4 p0 = *(const float4*)(post_b + c0),    p1 = *(const float4*)(post_b + c0 + 4);
      float fv[8];
      fv[0] = leaky(h0.x + a0.x + av*m0.x + tv2*t0.x + p0.x);
      fv[1] = leaky(h0.y + a0.y + av*m0.y + tv2*t0.y + p0.y);
      fv[2] = leaky(h0.z + a0.z + av*m0.z + tv2*t0.z + p0.z);
      fv[3] = leaky(h0.w + a0.w + av*m0.w + tv2*t0.w + p0.w);
      fv[4] = leaky(h1.x + a1.x + av*m1.x + tv2*t1.x + p1.x);
      fv[5] = leaky(h1.y + a1.y + av*m1.y + tv2*t1.y + p1.y);
      fv[6] = leaky(h1.z + a1.z + av*m1.z + tv2*t1.z + p1.z);
      fv[7] = leaky(h1.w + a1.w + av*m1.w + tv2*t1.w + p1.w);
      unsigned short h8[8] __attribute__((aligned(16)));
      unsigned short l8[8] __attribute__((aligned(16)));
      #pragma unroll
      for (int i=0;i<8;++i) bsplit(fv[i], h8[i], l8[i]);
      *(uint4*)a_dh = *(const uint4*)h8;
      *(uint4*)a_dl = *(const uint4*)l8;
    }
    __syncthreads();
    short8 ah[2], al[2], bh4[4], bl4[4];
    #pragma unroll
    for (int mi=0;mi<2;++mi){
      int row = wm + mi*16 + lr;
      int idx = row*32 + ((lk ^ sw4(row))*8);
      ah[mi] = *(const short8*)(Ah + idx);
      al[mi] = *(const short8*)(Al + idx);
    }
    #pragma unroll
    for (int ni=0;ni<4;++ni){
      int col = wn + ni*16 + lr;
      int idx = col*32 + ((lk ^ sw4(col))*8);
      bh4[ni] = *(const short8*)(Bh + idx);
      bl4[ni] = *(const short8*)(Bl + idx);
    }
    #pragma unroll
    for (int mi=0;mi<2;++mi){
      #pragma unroll
      for (int ni=0;ni<4;++ni){
        acc[mi][ni] = __builtin_amdgcn_mfma_f32_16x16x32_bf16(ah[mi], bh4[ni], acc[mi][ni], 0,0,0);
        acc[mi][ni] = __builtin_amdgcn_mfma_f32_16x16x32_bf16(ah[mi], bl4[ni], acc[mi][ni], 0,0,0);
        acc[mi][ni] = __builtin_amdgcn_mfma_f32_16x16x32_bf16(al[mi], bh4[ni], acc[mi][ni], 0,0,0);
      }
    }
    __syncthreads();
  }

  // epilogue: store tb + per-block BN column partials
  float sn[2][4]; bool vld[2][4];
  #pragma unroll
  for (int mi=0;mi<2;++mi)
    #pragma unroll
    for (int r=0;r<4;++r){
      int grow = mbase + wm + mi*16 + lk*4 + r;
      vld[mi][r] = (grow < N_NODES);
      sn[mi][r] = vld[mi][r] ? snorm[grow] : 0.f;
    }
  int half = wv >> 1;
  #pragma unroll
  for (int ni=0;ni<4;++ni){
    int gcol = wn + ni*16 + lr;
    float bv = mix_b[gcol];
    float s = 0.f, q = 0.f;
    #pragma unroll
    for (int mi=0;mi<2;++mi){
      #pragma unroll
      for (int r=0;r<4;++r){
        if (vld[mi][r]){
          int grow = mbase + wm + mi*16 + lk*4 + r;
          float v = leaky(acc[mi][ni][r] + bv) * sn[mi][r];
          tb[(size_t)grow*128 + gcol] = v;
          s += v; q += v*v;
        }
      }
    }
    s += __shfl_xor(s, 16); s += __shfl_xor(s, 32);
    q += __shfl_xor(q, 16); q += __shfl_xor(q, 32);
    if (lk == 0){ bns[half][gcol] = s; bnq[half][gcol] = q; }
  }
  __syncthreads();
  if (tid < 128){
    bnpart[(size_t)blockIdx.x*256 + tid]       = bns[0][tid] + bns[1][tid];
    bnpart[(size_t)blockIdx.x*256 + 128 + tid] = bnq[0][tid] + bnq[1][tid];
  }
}

// ---------------- fused edge-message + aggregation ----------------
__global__ __launch_bounds__(256) void k_fusedagg(
    const float* __restrict__ H1, const float* __restrict__ H2,
    const float* __restrict__ BW3,
    const int* __restrict__ srcS, const int* __restrict__ eaS,
    const int* __restrict__ off, const float* __restrict__ invd,
    float* __restrict__ agg)
{
  __shared__ float bw[4][128];
  int tid = threadIdx.x;
  bw[tid>>7][tid&127]     = BW3[tid];
  bw[2+(tid>>7)][tid&127] = BW3[256+tid];
  __syncthreads();

  int node = blockIdx.x*8 + (tid>>5);
  int q = tid & 31;
  float4 c4 = ((const float4*)(H1 + (size_t)node*HID))[q];
  int s = off[node], e = off[node+1];
  float4 sum = make_float4(0,0,0,0), sq = make_float4(0,0,0,0);
  float4 mx = make_float4(-3.4e38f,-3.4e38f,-3.4e38f,-3.4e38f);
  float4 mn = make_float4( 3.4e38f, 3.4e38f, 3.4e38f, 3.4e38f);
  for (int i = s; i < e; ++i){
    int sv = srcS[i], ev = eaS[i];
    float4 t  = ((const float4*)(H2 + (size_t)sv*HID))[q];
    float4 b4 = ((const float4*)(&bw[ev][0]))[q];
    float vx = leaky(c4.x + t.x + b4.x);
    float vy = leaky(c4.y + t.y + b4.y);
    float vz = leaky(c4.z + t.z + b4.z);
    float vw = leaky(c4.w + t.w + b4.w);
    sum.x += vx; sum.y += vy; sum.z += vz; sum.w += vw;
    sq.x += vx*vx; sq.y += vy*vy; sq.z += vz*vz; sq.w += vw*vw;
    mx.x = fmaxf(mx.x, vx); mx.y = fmaxf(mx.y, vy); mx.z = fmaxf(mx.z, vz); mx.w = fmaxf(mx.w, vw);
    mn.x = fminf(mn.x, vx); mn.y = fminf(mn.y, vy); mn.z = fminf(mn.z, vz); mn.w = fminf(mn.w, vw);
  }
  bool has = (e > s);
  float iv = invd[node];
  float4 mean = make_float4(sum.x*iv, sum.y*iv, sum.z*iv, sum.w*iv);
  float4 msq  = make_float4(sq.x*iv,  sq.y*iv,  sq.z*iv,  sq.w*iv);
  float4 sd;
  sd.x = has ? sqrtf(fmaxf(msq.x - mean.x*mean.x, 0.f) + EPS) : 0.f;
  sd.y = has ? sqrtf(fmaxf(msq.y - mean.y*mean.y, 0.f) + EPS) : 0.f;
  sd.z = has ? sqrtf(fmaxf(msq.z - mean.z*mean.z, 0.f) + EPS) : 0.f;
  sd.w = has ? sqrtf(fmaxf(msq.w - mean.w*mean.w, 0.f) + EPS) : 0.f;
  if (!has){ mx = make_float4(0,0,0,0); mn = make_float4(0,0,0,0); }
  size_t base = (size_t)node*512;
  ((float4*)(agg + base      ))[q] = mean;
  ((float4*)(agg + base + 128))[q] = mx;
  ((float4*)(agg + base + 256))[q] = mn;
  ((float4*)(agg + base + 384))[q] = sd;
}

// ---------------- BN finalize (reduce block partials) ----------------
__global__ void k_bnfinal(const float* __restrict__ bnpart,
                          float* __restrict__ mu, float* __restrict__ rstd){
  int c = threadIdx.x;   // 128
  double s = 0.0, q = 0.0;
  for (int b = 0; b < MB64; ++b){
    s += (double)bnpart[(size_t)b*256 + c];
    q += (double)bnpart[(size_t)b*256 + 128 + c];
  }
  double mean = s / (double)N_NODES;
  double var  = q / (double)N_NODES - mean*mean;
  mu[c] = (float)mean;
  rstd[c] = rsqrtf((float)var + EPS);
}

__global__ void k_apply(const float* __restrict__ t, const float* __restrict__ mu,
                        const float* __restrict__ rstd, const float* __restrict__ gamma,
                        const float* __restrict__ beta, float* __restrict__ h){
  int idx = blockIdx.x*blockDim.x + threadIdx.x;
  if (idx < N_NODES*32){
    int n = idx >> 5, q = idx & 31;
    float4 tv = ((const float4*)t)[(size_t)n*32 + q];
    float4 hv = ((float4*)h)[(size_t)n*32 + q];
    float4 g4 = ((const float4*)gamma)[q], b4 = ((const float4*)beta)[q];
    float4 m4 = ((const float4*)mu)[q],    r4 = ((const float4*)rstd)[q];
    hv.x += g4.x*(tv.x-m4.x)*r4.x + b4.x;
    hv.y += g4.y*(tv.y-m4.y)*r4.y + b4.y;
    hv.z += g4.z*(tv.z-m4.z)*r4.z + b4.z;
    hv.w += g4.w*(tv.w-m4.w)*r4.w + b4.w;
    ((float4*)h)[(size_t)n*32 + q] = hv;
  }
}

// ---------------- fused mean-pool + MLP readout (one block per graph) ----------------
__global__ __launch_bounds__(128) void k_poolread(
    const int* __restrict__ goff, const float* __restrict__ h,
    const float* __restrict__ W1, const float* __restrict__ b1,
    const float* __restrict__ W2, const float* __restrict__ b2,
    const float* __restrict__ W3, const float* __restrict__ b3,
    float* __restrict__ out){
  __shared__ float gl[128];
  __shared__ float a1[64];
  __shared__ float a2[32];
  int g = blockIdx.x, tid = threadIdx.x;
  int s = goff[g], e = goff[g+1];
  float sum = 0.f;
  for (int r = s; r < e; ++r) sum += h[(size_t)r*128 + tid];
  gl[tid] = sum / fmaxf((float)(e - s), 1.f);
  __syncthreads();
  if (tid < 64){
    float s1 = b1[tid];
    for (int k = 0; k < 128; ++k) s1 = fmaf(gl[k], W1[k*64 + tid], s1);
    a1[tid] = fmaxf(s1, 0.f);
  }
  __syncthreads();
  if (tid < 32){
    float s2 = b2[tid];
    for (int k = 0; k < 64; ++k) s2 = fmaf(a1[k], W2[k*32 + tid], s2);
    a2[tid] = fmaxf(s2, 0.f);
  }
  __syncthreads();
  if (tid == 0){
    float s3 = b3[0];
    for (int k = 0; k < 32; ++k) s3 = fmaf(a2[k], W3[k], s3);
    out[g] = s3;
  }
}

// ---------------- launch ----------------
extern "C" void kernel_launch(void* const* d_in, const int* in_sizes, int n_in,
                              void* d_out, int out_size, void* d_ws, size_t ws_size,
                              hipStream_t stream) {
  const int*   x        = (const int*)  d_in[0];
  const int*   batch    = (const int*)  d_in[1];
  const int*   ei       = (const int*)  d_in[2];
  const float* snorm    = (const float*)d_in[3];
  const int*   eattr    = (const int*)  d_in[4];
  const float* atom_emb = (const float*)d_in[5];
  const float* bond_emb = (const float*)d_in[6];
  const float* pre_W    = (const float*)d_in[7];
  const float* pre_b    = (const float*)d_in[8];
  const float* post_W   = (const float*)d_in[9];
  const float* post_b   = (const float*)d_in[10];
  const float* mix_W    = (const float*)d_in[11];
  const float* mix_b    = (const float*)d_in[12];
  const float* bn_g     = (const float*)d_in[13];
  const float* bn_b     = (const float*)d_in[14];
  const float* rW1      = (const float*)d_in[15];
  const float* rb1      = (const float*)d_in[16];
  const float* rW2      = (const float*)d_in[17];
  const float* rb2      = (const float*)d_in[18];
  const float* rW3      = (const float*)d_in[19];
  const float* rb3      = (const float*)d_in[20];
  float* outp = (float*)d_out;

  const int* srcI = ei;            // edge_index[0]
  const int* dstI = ei + N_EDGES;  // edge_index[1]

  char* ws = (char*)d_ws;
  size_t o = 0;
  auto alloc = [&](size_t bytes)->char* {
    char* p = ws + o;
    o = (o + bytes + 255) & ~(size_t)255;
    return p;
  };
  int*    deg    = (int*)   alloc((size_t)N_NODES*4);
  int*    cursor = (int*)   alloc((size_t)N_NODES*4);
  int*    off    = (int*)   alloc((size_t)(N_NODES+1)*4);
  int*    goff   = (int*)   alloc((size_t)(N_GRAPHS+1)*4);
  int*    srcS   = (int*)   alloc((size_t)N_EDGES*4);
  int*    eaS    = (int*)   alloc((size_t)N_EDGES*4);
  float*  invd   = (float*) alloc((size_t)N_NODES*4);
  float*  ampb   = (float*) alloc((size_t)N_NODES*4);
  float*  attb   = (float*) alloc((size_t)N_NODES*4);
  float*  h      = (float*) alloc((size_t)N_NODES*HID*4);
  float*  H3     = (float*) alloc((size_t)3*N_NODES*HID*4);   // H1 | H2 | Yh
  float*  Yamt   = (float*) alloc((size_t)N_NODES*384*4);
  float*  BW3    = (float*) alloc(512*4);
  float*  agg    = (float*) alloc((size_t)N_NODES*512*4);
  float*  tb     = (float*) alloc((size_t)N_NODES*HID*4);
  unsigned short* whi = (unsigned short*)alloc((size_t)NLAYERS*262144*2);
  unsigned short* wlo = (unsigned short*)alloc((size_t)NLAYERS*262144*2);
  float*  bnpart = (float*) alloc((size_t)MB64*256*4);
  float*  mu     = (float*) alloc(128*4);
  float*  rstd   = (float*) alloc(128*4);

  // zero deg + cursor (adjacent) in one memset
  hipMemsetAsync(deg, 0, (size_t)((char*)cursor - (char*)deg) + (size_t)N_NODES*4, stream);
  k_count<<<(N_EDGES+255)/256, 256, 0, stream>>>(dstI, deg);
  k_scanscal<<<1, 1024, 0, stream>>>(deg, off, invd, ampb, attb);
  k_fill<<<(N_EDGES+255)/256, 256, 0, stream>>>(srcI, dstI, eattr, off, cursor, srcS, eaS);
  k_goff<<<1, 512, 0, stream>>>(batch, goff);
  k_hinit<<<(N_NODES*32+255)/256, 256, 0, stream>>>(x, atom_emb, h);
  k_wt<<<dim3(32, NLAYERS*7), 256, 0, stream>>>(pre_W, post_W, mix_W, whi, wlo);

  float* H1 = H3;
  float* H2 = H3 + (size_t)N_NODES*HID;
  float* Yh = H3 + (size_t)2*N_NODES*HID;
  for (int l = 0; l < NLAYERS; ++l){
    const unsigned short* whl = whi + (size_t)l*262144;
    const unsigned short* wll = wlo + (size_t)l*262144;
    const float* preWl  = pre_W  + (size_t)l*384*128;
    // triple head GEMM on h: H1, H2, Yh
    k_mf<0><<<dim3(MB64,3), 256, 0, stream>>>(whl, wll, h, H3);
    // 4-row bond table (+ pre_b folded in)
    k_bond<<<1, 512, 0, stream>>>(bond_emb, preWl + 256*128, pre_b + (size_t)l*128, BW3);
    // fused edge message + aggregation
    k_fusedagg<<<N_NODES/8, 256, 0, stream>>>(H1, H2, BW3, srcS, eaS, off, invd, agg);
    // agg GEMM: Yamt = agg @ [W_a | W_m | W_t]
    k_mf<1><<<dim3(MB64,3), 256, 0, stream>>>(whl + 49152, wll + 49152, agg, Yamt);
    // mix with fused combine + BN partials
    k_mix<<<MB64, 256, 0, stream>>>(whl + 245760, wll + 245760,
        Yh, Yamt, ampb, attb, post_b + (size_t)l*128, mix_b + (size_t)l*128,
        snorm, tb, bnpart);
    k_bnfinal<<<1, 128, 0, stream>>>(bnpart, mu, rstd);
    k_apply<<<(N_NODES*32+255)/256, 256, 0, stream>>>(tb, mu, rstd,
        bn_g + (size_t)l*128, bn_b + (size_t)l*128, h);
  }

  k_poolread<<<N_GRAPHS, 128, 0, stream>>>(goff, h, rW1, rb1, rW2, rb2, rW3, rb3, outp);
}

// Round 7
// 615.744 us; speedup vs baseline: 4.4116x; 1.1720x over previous
//
#include <hip/hip_runtime.h>
#include <math.h>

#define N_NODES 20000
#define N_EDGES 320000
#define N_GRAPHS 256
#define HID 128
#define NLAYERS 4
#define AVG_LOG 2.833213344056216f
#define EPS 1e-5f
#define MB64 313   // ceil(N_NODES/64)
#define SCANB 20   // ceil(N_NODES/1024)

typedef __attribute__((ext_vector_type(8))) short short8;
typedef __attribute__((ext_vector_type(4))) float f32x4;

static __device__ __forceinline__ float leaky(float v){ return v > 0.f ? v : 0.01f*v; }

// round-to-nearest-even fp32 -> (hi, lo) bf16 pair, f ~= hi + lo
static __device__ __forceinline__ void bsplit(float f, unsigned short& hi, unsigned short& lo){
  unsigned int u = __float_as_uint(f);
  unsigned int r = u + 0x7FFFu + ((u>>16)&1u);
  hi = (unsigned short)(r>>16);
  float hf = __uint_as_float(((unsigned int)hi)<<16);
  float l = f - hf;
  unsigned int v = __float_as_uint(l);
  unsigned int s = v + 0x7FFFu + ((v>>16)&1u);
  lo = (unsigned short)(s>>16);
}

static __device__ __forceinline__ int sw4(int r){ return (r + (r>>2)) & 3; }

// ---------------- CSR build ----------------
__global__ void k_count(const int* __restrict__ dst, int* __restrict__ deg){
  int e = blockIdx.x*blockDim.x + threadIdx.x;
  if (e < N_EDGES) atomicAdd(&deg[dst[e]], 1);
}

// hierarchical scan, stage 1: per-chunk exclusive scan + chunk totals
__global__ __launch_bounds__(1024) void k_scan1(const int* __restrict__ deg,
                                                int* __restrict__ excl, int* __restrict__ btot){
  __shared__ int buf[1024];
  int b = blockIdx.x, tid = threadIdx.x;
  int i = b*1024 + tid;
  int v = (i < N_NODES) ? deg[i] : 0;
  buf[tid] = v;
  __syncthreads();
  for (int ofs = 1; ofs < 1024; ofs <<= 1){
    int t = (tid >= ofs) ? buf[tid-ofs] : 0;
    __syncthreads();
    buf[tid] += t;
    __syncthreads();
  }
  excl[i] = buf[tid] - v;
  if (tid == 1023) btot[b] = buf[1023];
}

// stage 2: add chunk carries, write off + degree scalers
__global__ __launch_bounds__(1024) void k_scan2(
    const int* __restrict__ deg, const int* __restrict__ excl, const int* __restrict__ btot,
    int* __restrict__ off, float* __restrict__ invd,
    float* __restrict__ amp, float* __restrict__ att){
  __shared__ int carry_s;
  int b = blockIdx.x, tid = threadIdx.x;
  if (tid == 0){
    int c = 0;
    for (int j = 0; j < b; ++j) c += btot[j];
    carry_s = c;
  }
  __syncthreads();
  int i = b*1024 + tid;
  if (i <= N_NODES){
    off[i] = carry_s + excl[i];
    if (i < N_NODES){
      float d = (float)deg[i];
      invd[i] = 1.f / fmaxf(d, 1.f);
      float ld = log1pf(d);
      amp[i] = ld / AVG_LOG;
      att[i] = AVG_LOG / fmaxf(ld, EPS);
    }
  }
}

__global__ void k_fill(const int* __restrict__ src, const int* __restrict__ dst,
                       const int* __restrict__ eattr, const int* __restrict__ off,
                       int* __restrict__ cursor,
                       int* __restrict__ srcS, int* __restrict__ eaS){
  int e = blockIdx.x*blockDim.x + threadIdx.x;
  if (e < N_EDGES){
    int d = dst[e];
    int pos = off[d] + atomicAdd(&cursor[d], 1);
    srcS[pos] = src[e]; eaS[pos] = eattr[e];
  }
}

// graph offsets via binary search on sorted batch
__global__ void k_goff(const int* __restrict__ batch, int* __restrict__ goff){
  int g = threadIdx.x;
  if (g <= N_GRAPHS){
    int lo = 0, hi = N_NODES;
    while (lo < hi){ int mid = (lo+hi)>>1; if (batch[mid] < g) lo = mid+1; else hi = mid; }
    goff[g] = lo;
  }
}

__global__ void k_hinit(const int* __restrict__ x, const float* __restrict__ atom_emb,
                        float* __restrict__ h){
  int idx = blockIdx.x*blockDim.x + threadIdx.x;
  if (idx < N_NODES*32){
    int n = idx >> 5, q = idx & 31;
    ((float4*)h)[(size_t)n*32 + q] = ((const float4*)atom_emb)[(size_t)x[n]*32 + q];
  }
}

// bond tables for ALL layers: BW3all[l][r][c] = bond_emb[r]@preW3_l[:,c] + pre_b_l[c]
__global__ void k_bondall(const float* __restrict__ bond_emb, const float* __restrict__ pre_W,
                          const float* __restrict__ pre_b, float* __restrict__ BW3all){
  int l = blockIdx.x, tid = threadIdx.x;   // 4 blocks x 512
  int r = tid >> 7, c = tid & 127;
  const float* W3 = pre_W + (size_t)l*384*128 + 256*128;
  float s = pre_b[l*128 + c];
  for (int k = 0; k < 128; ++k) s = fmaf(bond_emb[r*128 + k], W3[k*128 + c], s);
  BW3all[l*512 + tid] = s;
}

// ---------------- weight pre-transpose + bf16 hi/lo split ----------------
__global__ void k_wt(const float* __restrict__ pre_W, const float* __restrict__ post_W,
                     const float* __restrict__ mix_W,
                     unsigned short* __restrict__ whi, unsigned short* __restrict__ wlo){
  int y = blockIdx.y; int l = y/7, j = y%7;
  int K = (j>=3 && j<6) ? 512 : 128;
  const float* src; size_t off;
  if (j < 2)      { src = pre_W  + (size_t)l*384*128  + (size_t)j*128*128;            off = (size_t)j*16384; }
  else if (j == 2){ src = post_W + (size_t)l*1664*128;                                off = 2*16384; }
  else if (j < 6) { src = post_W + (size_t)l*1664*128 + (size_t)(128+(j-3)*512)*128;  off = 49152 + (size_t)(j-3)*65536; }
  else            { src = mix_W  + (size_t)l*128*128;                                 off = 245760; }
  unsigned short* dh = whi + (size_t)l*262144 + off;
  unsigned short* dl = wlo + (size_t)l*262144 + off;
  int kq8 = K/8;
  int ntask = 128*kq8;
  int t = blockIdx.x*256 + threadIdx.x;
  if (t >= ntask) return;
  int c  = t / kq8;
  int k0 = (t % kq8)*8;
  unsigned short h8[8] __attribute__((aligned(16)));
  unsigned short l8[8] __attribute__((aligned(16)));
  #pragma unroll
  for (int i=0;i<8;++i) bsplit(src[(size_t)(k0+i)*128 + c], h8[i], l8[i]);
  *(uint4*)(dh + (size_t)c*K + k0) = *(const uint4*)h8;
  *(uint4*)(dl + (size_t)c*K + k0) = *(const uint4*)l8;
}

// ---------------- split-bf16 MFMA GEMM (MODE 0: triple head K=128; MODE 1: agg K=512) ----------------
template<int MODE>
__global__ __launch_bounds__(256) void k_mf(
    const unsigned short* __restrict__ whi, const unsigned short* __restrict__ wlo,
    const float* __restrict__ A, float* __restrict__ out)
{
  const int K    = (MODE==1) ? 512 : 128;
  const int ASTR = (MODE==1) ? 512 : 128;
  const int OSTR = (MODE==1) ? 384 : 128;
  __shared__ unsigned short Ah[64*32], Al[64*32], Bh[128*32], Bl[128*32];
  int tid = threadIdx.x;
  int lane = tid & 63;
  int wv = tid >> 6;
  int wm = (wv>>1)*32, wn = (wv&1)*64;
  int mbase = blockIdx.x*64;
  int y = blockIdx.y;
  const unsigned short* wh = whi + (size_t)y*K*128;
  const unsigned short* wl = wlo + (size_t)y*K*128;
  float* outp = out; int ocol = 0;
  if (MODE == 0) outp = out + (size_t)y*N_NODES*128;
  if (MODE == 1) ocol = y*128;

  int a_row = tid >> 2, a_kg = tid & 3;
  int a_nrow = min(mbase + a_row, N_NODES-1);
  const float* a_src = A + (size_t)a_nrow*ASTR + a_kg*8;
  int a_slot = a_kg ^ sw4(a_row);
  unsigned short* a_dh = Ah + a_row*32 + a_slot*8;
  unsigned short* a_dl = Al + a_row*32 + a_slot*8;

  f32x4 acc[2][4];
  #pragma unroll
  for (int mi=0;mi<2;++mi)
    #pragma unroll
    for (int ni=0;ni<4;++ni)
      acc[mi][ni] = (f32x4){0.f,0.f,0.f,0.f};

  int lr = lane & 15, lk = lane >> 4;

  for (int kt = 0; kt < K; kt += 32){
    #pragma unroll
    for (int i=0;i<2;++i){
      int s = tid + 256*i;
      int col = s >> 2, kg = s & 3;
      int slot = kg ^ sw4(col);
      *(uint4*)(Bh + col*32 + slot*8) = *(const uint4*)(wh + (size_t)col*K + kt + kg*8);
      *(uint4*)(Bl + col*32 + slot*8) = *(const uint4*)(wl + (size_t)col*K + kt + kg*8);
    }
    {
      float4 f0 = *(const float4*)(a_src + kt);
      float4 f1 = *(const float4*)(a_src + kt + 4);
      float fv[8] = {f0.x,f0.y,f0.z,f0.w,f1.x,f1.y,f1.z,f1.w};
      unsigned short h8[8] __attribute__((aligned(16)));
      unsigned short l8[8] __attribute__((aligned(16)));
      #pragma unroll
      for (int i=0;i<8;++i) bsplit(fv[i], h8[i], l8[i]);
      *(uint4*)a_dh = *(const uint4*)h8;
      *(uint4*)a_dl = *(const uint4*)l8;
    }
    __syncthreads();
    short8 ah[2], al[2], bh4[4], bl4[4];
    #pragma unroll
    for (int mi=0;mi<2;++mi){
      int row = wm + mi*16 + lr;
      int idx = row*32 + ((lk ^ sw4(row))*8);
      ah[mi] = *(const short8*)(Ah + idx);
      al[mi] = *(const short8*)(Al + idx);
    }
    #pragma unroll
    for (int ni=0;ni<4;++ni){
      int col = wn + ni*16 + lr;
      int idx = col*32 + ((lk ^ sw4(col))*8);
      bh4[ni] = *(const short8*)(Bh + idx);
      bl4[ni] = *(const short8*)(Bl + idx);
    }
    #pragma unroll
    for (int mi=0;mi<2;++mi){
      #pragma unroll
      for (int ni=0;ni<4;++ni){
        acc[mi][ni] = __builtin_amdgcn_mfma_f32_16x16x32_bf16(ah[mi], bh4[ni], acc[mi][ni], 0,0,0);
        acc[mi][ni] = __builtin_amdgcn_mfma_f32_16x16x32_bf16(ah[mi], bl4[ni], acc[mi][ni], 0,0,0);
        acc[mi][ni] = __builtin_amdgcn_mfma_f32_16x16x32_bf16(al[mi], bh4[ni], acc[mi][ni], 0,0,0);
      }
    }
    __syncthreads();
  }

  #pragma unroll
  for (int mi=0;mi<2;++mi){
    #pragma unroll
    for (int ni=0;ni<4;++ni){
      int gcol = wn + ni*16 + lr;
      #pragma unroll
      for (int r=0;r<4;++r){
        int grow = mbase + wm + mi*16 + lk*4 + r;
        if (grow < N_NODES)
          outp[(size_t)grow*OSTR + ocol + gcol] = acc[mi][ni][r];
      }
    }
  }
}

// ---------------- mix GEMM with fused combine (A-staging) + fused BN partials ----------------
__global__ __launch_bounds__(256) void k_mix(
    const unsigned short* __restrict__ wh, const unsigned short* __restrict__ wl,
    const float* __restrict__ Yh, const float* __restrict__ Yamt,
    const float* __restrict__ amp, const float* __restrict__ att,
    const float* __restrict__ post_b, const float* __restrict__ mix_b,
    const float* __restrict__ snorm,
    float* __restrict__ tb, float* __restrict__ bnpart)
{
  __shared__ unsigned short Ah[64*32], Al[64*32], Bh[128*32], Bl[128*32];
  __shared__ float bns[2][128], bnq[2][128];
  int tid = threadIdx.x;
  int lane = tid & 63;
  int wv = tid >> 6;
  int wm = (wv>>1)*32, wn = (wv&1)*64;
  int mbase = blockIdx.x*64;

  int a_row = tid >> 2, a_kg = tid & 3;
  int a_nrow = min(mbase + a_row, N_NODES-1);
  float av = amp[a_nrow], tv2 = att[a_nrow];
  const float* yhp = Yh   + (size_t)a_nrow*128;
  const float* yap = Yamt + (size_t)a_nrow*384;
  int a_slot = a_kg ^ sw4(a_row);
  unsigned short* a_dh = Ah + a_row*32 + a_slot*8;
  unsigned short* a_dl = Al + a_row*32 + a_slot*8;

  f32x4 acc[2][4];
  #pragma unroll
  for (int mi=0;mi<2;++mi)
    #pragma unroll
    for (int ni=0;ni<4;++ni)
      acc[mi][ni] = (f32x4){0.f,0.f,0.f,0.f};

  int lr = lane & 15, lk = lane >> 4;

  for (int kt = 0; kt < 128; kt += 32){
    #pragma unroll
    for (int i=0;i<2;++i){
      int s = tid + 256*i;
      int col = s >> 2, kg = s & 3;
      int slot = kg ^ sw4(col);
      *(uint4*)(Bh + col*32 + slot*8) = *(const uint4*)(wh + (size_t)col*128 + kt + kg*8);
      *(uint4*)(Bl + col*32 + slot*8) = *(const uint4*)(wl + (size_t)col*128 + kt + kg*8);
    }
    {
      int c0 = kt + a_kg*8;
      float4 h0 = *(const float4*)(yhp + c0),       h1 = *(const float4*)(yhp + c0 + 4);
      float4 a0 = *(const float4*)(yap + c0),       a1 = *(const float4*)(yap + c0 + 4);
      float4 m0 = *(const float4*)(yap + 128 + c0), m1 = *(const float4*)(yap + 132 + c0);
      float4 t0 = *(const float4*)(yap + 256 + c0), t1 = *(const float4*)(yap + 260 + c0);
      float4 p0 = *(const float4*)(post_b + c0),    p1 = *(const float4*)(post_b + c0 + 4);
      float fv[8];
      fv[0] = leaky(h0.x + a0.x + av*m0.x + tv2*t0.x + p0.x);
      fv[1] = leaky(h0.y + a0.y + av*m0.y + tv2*t0.y + p0.y);
      fv[2] = leaky(h0.z + a0.z + av*m0.z + tv2*t0.z + p0.z);
      fv[3] = leaky(h0.w + a0.w + av*m0.w + tv2*t0.w + p0.w);
      fv[4] = leaky(h1.x + a1.x + av*m1.x + tv2*t1.x + p1.x);
      fv[5] = leaky(h1.y + a1.y + av*m1.y + tv2*t1.y + p1.y);
      fv[6] = leaky(h1.z + a1.z + av*m1.z + tv2*t1.z + p1.z);
      fv[7] = leaky(h1.w + a1.w + av*m1.w + tv2*t1.w + p1.w);
      unsigned short h8[8] __attribute__((aligned(16)));
      unsigned short l8[8] __attribute__((aligned(16)));
      #pragma unroll
      for (int i=0;i<8;++i) bsplit(fv[i], h8[i], l8[i]);
      *(uint4*)a_dh = *(const uint4*)h8;
      *(uint4*)a_dl = *(const uint4*)l8;
    }
    __syncthreads();
    short8 ah[2], al[2], bh4[4], bl4[4];
    #pragma unroll
    for (int mi=0;mi<2;++mi){
      int row = wm + mi*16 + lr;
      int idx = row*32 + ((lk ^ sw4(row))*8);
      ah[mi] = *(const short8*)(Ah + idx);
      al[mi] = *(const short8*)(Al + idx);
    }
    #pragma unroll
    for (int ni=0;ni<4;++ni){
      int col = wn + ni*16 + lr;
      int idx = col*32 + ((lk ^ sw4(col))*8);
      bh4[ni] = *(const short8*)(Bh + idx);
      bl4[ni] = *(const short8*)(Bl + idx);
    }
    #pragma unroll
    for (int mi=0;mi<2;++mi){
      #pragma unroll
      for (int ni=0;ni<4;++ni){
        acc[mi][ni] = __builtin_amdgcn_mfma_f32_16x16x32_bf16(ah[mi], bh4[ni], acc[mi][ni], 0,0,0);
        acc[mi][ni] = __builtin_amdgcn_mfma_f32_16x16x32_bf16(ah[mi], bl4[ni], acc[mi][ni], 0,0,0);
        acc[mi][ni] = __builtin_amdgcn_mfma_f32_16x16x32_bf16(al[mi], bh4[ni], acc[mi][ni], 0,0,0);
      }
    }
    __syncthreads();
  }

  float sn[2][4]; bool vld[2][4];
  #pragma unroll
  for (int mi=0;mi<2;++mi)
    #pragma unroll
    for (int r=0;r<4;++r){
      int grow = mbase + wm + mi*16 + lk*4 + r;
      vld[mi][r] = (grow < N_NODES);
      sn[mi][r] = vld[mi][r] ? snorm[grow] : 0.f;
    }
  int half = wv >> 1;
  #pragma unroll
  for (int ni=0;ni<4;++ni){
    int gcol = wn + ni*16 + lr;
    float bv = mix_b[gcol];
    float s = 0.f, q = 0.f;
    #pragma unroll
    for (int mi=0;mi<2;++mi){
      #pragma unroll
      for (int r=0;r<4;++r){
        if (vld[mi][r]){
          int grow = mbase + wm + mi*16 + lk*4 + r;
          float v = leaky(acc[mi][ni][r] + bv) * sn[mi][r];
          tb[(size_t)grow*128 + gcol] = v;
          s += v; q += v*v;
        }
      }
    }
    s += __shfl_xor(s, 16); s += __shfl_xor(s, 32);
    q += __shfl_xor(q, 16); q += __shfl_xor(q, 32);
    if (lk == 0){ bns[half][gcol] = s; bnq[half][gcol] = q; }
  }
  __syncthreads();
  if (tid < 128){
    bnpart[(size_t)blockIdx.x*256 + tid]       = bns[0][tid] + bns[1][tid];
    bnpart[(size_t)blockIdx.x*256 + 128 + tid] = bnq[0][tid] + bnq[1][tid];
  }
}

// ---------------- fused edge-message + aggregation (x2 unrolled gather) ----------------
__global__ __launch_bounds__(256) void k_fusedagg(
    const float* __restrict__ H1, const float* __restrict__ H2,
    const float* __restrict__ BW3,
    const int* __restrict__ srcS, const int* __restrict__ eaS,
    const int* __restrict__ off, const float* __restrict__ invd,
    float* __restrict__ agg)
{
  __shared__ float bw[4][128];
  int tid = threadIdx.x;
  bw[tid>>7][tid&127]     = BW3[tid];
  bw[2+(tid>>7)][tid&127] = BW3[256+tid];
  __syncthreads();

  int node = blockIdx.x*8 + (tid>>5);
  int q = tid & 31;
  float4 c4 = ((const float4*)(H1 + (size_t)node*HID))[q];
  int s = off[node], e = off[node+1];
  float4 sum = make_float4(0,0,0,0), sq = make_float4(0,0,0,0);
  float4 mx = make_float4(-3.4e38f,-3.4e38f,-3.4e38f,-3.4e38f);
  float4 mn = make_float4( 3.4e38f, 3.4e38f, 3.4e38f, 3.4e38f);

  #define FA_BODY(T,B) { \
    float vx = leaky(c4.x + T.x + B.x); \
    float vy = leaky(c4.y + T.y + B.y); \
    float vz = leaky(c4.z + T.z + B.z); \
    float vw = leaky(c4.w + T.w + B.w); \
    sum.x += vx; sum.y += vy; sum.z += vz; sum.w += vw; \
    sq.x += vx*vx; sq.y += vy*vy; sq.z += vz*vz; sq.w += vw*vw; \
    mx.x = fmaxf(mx.x, vx); mx.y = fmaxf(mx.y, vy); mx.z = fmaxf(mx.z, vz); mx.w = fmaxf(mx.w, vw); \
    mn.x = fminf(mn.x, vx); mn.y = fminf(mn.y, vy); mn.z = fminf(mn.z, vz); mn.w = fminf(mn.w, vw); }

  int i = s;
  for (; i + 1 < e; i += 2){
    int sv0 = srcS[i],   ev0 = eaS[i];
    int sv1 = srcS[i+1], ev1 = eaS[i+1];
    float4 t0 = ((const float4*)(H2 + (size_t)sv0*HID))[q];
    float4 t1 = ((const float4*)(H2 + (size_t)sv1*HID))[q];
    float4 b0 = ((const float4*)(&bw[ev0][0]))[q];
    float4 b1 = ((const float4*)(&bw[ev1][0]))[q];
    FA_BODY(t0,b0)
    FA_BODY(t1,b1)
  }
  if (i < e){
    int sv = srcS[i], ev = eaS[i];
    float4 t  = ((const float4*)(H2 + (size_t)sv*HID))[q];
    float4 b4 = ((const float4*)(&bw[ev][0]))[q];
    FA_BODY(t,b4)
  }
  #undef FA_BODY

  bool has = (e > s);
  float iv = invd[node];
  float4 mean = make_float4(sum.x*iv, sum.y*iv, sum.z*iv, sum.w*iv);
  float4 msq  = make_float4(sq.x*iv,  sq.y*iv,  sq.z*iv,  sq.w*iv);
  float4 sd;
  sd.x = has ? sqrtf(fmaxf(msq.x - mean.x*mean.x, 0.f) + EPS) : 0.f;
  sd.y = has ? sqrtf(fmaxf(msq.y - mean.y*mean.y, 0.f) + EPS) : 0.f;
  sd.z = has ? sqrtf(fmaxf(msq.z - mean.z*mean.z, 0.f) + EPS) : 0.f;
  sd.w = has ? sqrtf(fmaxf(msq.w - mean.w*mean.w, 0.f) + EPS) : 0.f;
  if (!has){ mx = make_float4(0,0,0,0); mn = make_float4(0,0,0,0); }
  size_t base = (size_t)node*512;
  ((float4*)(agg + base      ))[q] = mean;
  ((float4*)(agg + base + 128))[q] = mx;
  ((float4*)(agg + base + 256))[q] = mn;
  ((float4*)(agg + base + 384))[q] = sd;
}

// ---------------- BN finalize (parallel reduce of block partials) ----------------
__global__ __launch_bounds__(512) void k_bnfinal(const float* __restrict__ bnpart,
                                                 float* __restrict__ mu, float* __restrict__ rstd){
  __shared__ double ss[4][128], qq[4][128];
  int tid = threadIdx.x;
  int c = tid & 127, p = tid >> 7;
  double s = 0.0, q = 0.0;
  for (int b = p; b < MB64; b += 4){
    s += (double)bnpart[(size_t)b*256 + c];
    q += (double)bnpart[(size_t)b*256 + 128 + c];
  }
  ss[p][c] = s; qq[p][c] = q;
  __syncthreads();
  if (p == 0){
    double S = ss[0][c] + ss[1][c] + ss[2][c] + ss[3][c];
    double Q = qq[0][c] + qq[1][c] + qq[2][c] + qq[3][c];
    double mean = S / (double)N_NODES;
    double var  = Q / (double)N_NODES - mean*mean;
    mu[c] = (float)mean;
    rstd[c] = rsqrtf((float)var + EPS);
  }
}

__global__ void k_apply(const float* __restrict__ t, const float* __restrict__ mu,
                        const float* __restrict__ rstd, const float* __restrict__ gamma,
                        const float* __restrict__ beta, float* __restrict__ h){
  int idx = blockIdx.x*blockDim.x + threadIdx.x;
  if (idx < N_NODES*32){
    int n = idx >> 5, q = idx & 31;
    float4 tv = ((const float4*)t)[(size_t)n*32 + q];
    float4 hv = ((float4*)h)[(size_t)n*32 + q];
    float4 g4 = ((const float4*)gamma)[q], b4 = ((const float4*)beta)[q];
    float4 m4 = ((const float4*)mu)[q],    r4 = ((const float4*)rstd)[q];
    hv.x += g4.x*(tv.x-m4.x)*r4.x + b4.x;
    hv.y += g4.y*(tv.y-m4.y)*r4.y + b4.y;
    hv.z += g4.z*(tv.z-m4.z)*r4.z + b4.z;
    hv.w += g4.w*(tv.w-m4.w)*r4.w + b4.w;
    ((float4*)h)[(size_t)n*32 + q] = hv;
  }
}

// ---------------- fused mean-pool + MLP readout (one block per graph) ----------------
__global__ __launch_bounds__(128) void k_poolread(
    const int* __restrict__ goff, const float* __restrict__ h,
    const float* __restrict__ W1, const float* __restrict__ b1,
    const float* __restrict__ W2, const float* __restrict__ b2,
    const float* __restrict__ W3, const float* __restrict__ b3,
    float* __restrict__ out){
  __shared__ float gl[128];
  __shared__ float a1[64];
  __shared__ float a2[32];
  int g = blockIdx.x, tid = threadIdx.x;
  int s = goff[g], e = goff[g+1];
  float sum = 0.f;
  for (int r = s; r < e; ++r) sum += h[(size_t)r*128 + tid];
  gl[tid] = sum / fmaxf((float)(e - s), 1.f);
  __syncthreads();
  if (tid < 64){
    float s1 = b1[tid];
    for (int k = 0; k < 128; ++k) s1 = fmaf(gl[k], W1[k*64 + tid], s1);
    a1[tid] = fmaxf(s1, 0.f);
  }
  __syncthreads();
  if (tid < 32){
    float s2 = b2[tid];
    for (int k = 0; k < 64; ++k) s2 = fmaf(a1[k], W2[k*32 + tid], s2);
    a2[tid] = fmaxf(s2, 0.f);
  }
  __syncthreads();
  if (tid == 0){
    float s3 = b3[0];
    for (int k = 0; k < 32; ++k) s3 = fmaf(a2[k], W3[k], s3);
    out[g] = s3;
  }
}

// ---------------- launch ----------------
extern "C" void kernel_launch(void* const* d_in, const int* in_sizes, int n_in,
                              void* d_out, int out_size, void* d_ws, size_t ws_size,
                              hipStream_t stream) {
  const int*   x        = (const int*)  d_in[0];
  const int*   batch    = (const int*)  d_in[1];
  const int*   ei       = (const int*)  d_in[2];
  const float* snorm    = (const float*)d_in[3];
  const int*   eattr    = (const int*)  d_in[4];
  const float* atom_emb = (const float*)d_in[5];
  const float* bond_emb = (const float*)d_in[6];
  const float* pre_W    = (const float*)d_in[7];
  const float* pre_b    = (const float*)d_in[8];
  const float* post_W   = (const float*)d_in[9];
  const float* post_b   = (const float*)d_in[10];
  const float* mix_W    = (const float*)d_in[11];
  const float* mix_b    = (const float*)d_in[12];
  const float* bn_g     = (const float*)d_in[13];
  const float* bn_b     = (const float*)d_in[14];
  const float* rW1      = (const float*)d_in[15];
  const float* rb1      = (const float*)d_in[16];
  const float* rW2      = (const float*)d_in[17];
  const float* rb2      = (const float*)d_in[18];
  const float* rW3      = (const float*)d_in[19];
  const float* rb3      = (const float*)d_in[20];
  float* outp = (float*)d_out;

  const int* srcI = ei;            // edge_index[0]
  const int* dstI = ei + N_EDGES;  // edge_index[1]

  char* ws = (char*)d_ws;
  size_t o = 0;
  auto alloc = [&](size_t bytes)->char* {
    char* p = ws + o;
    o = (o + bytes + 255) & ~(size_t)255;
    return p;
  };
  int*    deg    = (int*)   alloc((size_t)N_NODES*4);
  int*    cursor = (int*)   alloc((size_t)N_NODES*4);
  int*    excl   = (int*)   alloc((size_t)SCANB*1024*4);
  int*    btot   = (int*)   alloc((size_t)SCANB*4);
  int*    off    = (int*)   alloc((size_t)(N_NODES+1)*4);
  int*    goff   = (int*)   alloc((size_t)(N_GRAPHS+1)*4);
  int*    srcS   = (int*)   alloc((size_t)N_EDGES*4);
  int*    eaS    = (int*)   alloc((size_t)N_EDGES*4);
  float*  invd   = (float*) alloc((size_t)N_NODES*4);
  float*  ampb   = (float*) alloc((size_t)N_NODES*4);
  float*  attb   = (float*) alloc((size_t)N_NODES*4);
  float*  h      = (float*) alloc((size_t)N_NODES*HID*4);
  float*  H3     = (float*) alloc((size_t)3*N_NODES*HID*4);   // H1 | H2 | Yh
  float*  Yamt   = (float*) alloc((size_t)N_NODES*384*4);
  float*  BW3all = (float*) alloc((size_t)NLAYERS*512*4);
  float*  agg    = (float*) alloc((size_t)N_NODES*512*4);
  float*  tb     = (float*) alloc((size_t)N_NODES*HID*4);
  unsigned short* whi = (unsigned short*)alloc((size_t)NLAYERS*262144*2);
  unsigned short* wlo = (unsigned short*)alloc((size_t)NLAYERS*262144*2);
  float*  bnpart = (float*) alloc((size_t)MB64*256*4);
  float*  mu     = (float*) alloc(128*4);
  float*  rstd   = (float*) alloc(128*4);

  // zero deg + cursor: cursor is 256B-aligned after deg, so cover the full span
  hipMemsetAsync(deg, 0, (size_t)((char*)cursor - (char*)deg) + (size_t)N_NODES*4, stream);
  k_count<<<(N_EDGES+255)/256, 256, 0, stream>>>(dstI, deg);
  k_scan1<<<SCANB, 1024, 0, stream>>>(deg, excl, btot);
  k_scan2<<<SCANB, 1024, 0, stream>>>(deg, excl, btot, off, invd, ampb, attb);
  k_fill<<<(N_EDGES+255)/256, 256, 0, stream>>>(srcI, dstI, eattr, off, cursor, srcS, eaS);
  k_goff<<<1, 512, 0, stream>>>(batch, goff);
  k_hinit<<<(N_NODES*32+255)/256, 256, 0, stream>>>(x, atom_emb, h);
  k_wt<<<dim3(32, NLAYERS*7), 256, 0, stream>>>(pre_W, post_W, mix_W, whi, wlo);
  k_bondall<<<NLAYERS, 512, 0, stream>>>(bond_emb, pre_W, pre_b, BW3all);

  float* H1 = H3;
  float* H2 = H3 + (size_t)N_NODES*HID;
  float* Yh = H3 + (size_t)2*N_NODES*HID;
  for (int l = 0; l < NLAYERS; ++l){
    const unsigned short* whl = whi + (size_t)l*262144;
    const unsigned short* wll = wlo + (size_t)l*262144;
    // triple head GEMM on h: H1, H2, Yh
    k_mf<0><<<dim3(MB64,3), 256, 0, stream>>>(whl, wll, h, H3);
    // fused edge message + aggregation
    k_fusedagg<<<N_NODES/8, 256, 0, stream>>>(H1, H2, BW3all + (size_t)l*512,
        srcS, eaS, off, invd, agg);
    // agg GEMM: Yamt = agg @ [W_a | W_m | W_t]
    k_mf<1><<<dim3(MB64,3), 256, 0, stream>>>(whl + 49152, wll + 49152, agg, Yamt);
    // mix with fused combine + BN partials
    k_mix<<<MB64, 256, 0, stream>>>(whl + 245760, wll + 245760,
        Yh, Yamt, ampb, attb, post_b + (size_t)l*128, mix_b + (size_t)l*128,
        snorm, tb, bnpart);
    k_bnfinal<<<1, 512, 0, stream>>>(bnpart, mu, rstd);
    k_apply<<<(N_NODES*32+255)/256, 256, 0, stream>>>(tb, mu, rstd,
        bn_g + (size_t)l*128, bn_b + (size_t)l*128, h);
  }

  k_poolread<<<N_GRAPHS, 128, 0, stream>>>(goff, h, rW1, rb1, rW2, rb2, rW3, rb3, outp);
}

// Round 8
// 614.749 us; speedup vs baseline: 4.4188x; 1.0016x over previous
//
#include <hip/hip_runtime.h>
#include <math.h>

#define N_NODES 20000
#define N_EDGES 320000
#define N_GRAPHS 256
#define HID 128
#define NLAYERS 4
#define AVG_LOG 2.833213344056216f
#define EPS 1e-5f
#define MB64 313   // ceil(N_NODES/64)
#define SCANB 20   // ceil(N_NODES/1024)
#define PITCH 40   // LDS row pitch in u16 (80 B) -> conflict-free b128 reads

typedef __attribute__((ext_vector_type(8))) short short8;
typedef __attribute__((ext_vector_type(4))) float f32x4;

static __device__ __forceinline__ float leaky(float v){ return v > 0.f ? v : 0.01f*v; }

// round-to-nearest-even fp32 -> (hi, lo) bf16 pair, f ~= hi + lo
static __device__ __forceinline__ void bsplit(float f, unsigned short& hi, unsigned short& lo){
  unsigned int u = __float_as_uint(f);
  unsigned int r = u + 0x7FFFu + ((u>>16)&1u);
  hi = (unsigned short)(r>>16);
  float hf = __uint_as_float(((unsigned int)hi)<<16);
  float l = f - hf;
  unsigned int v = __float_as_uint(l);
  unsigned int s = v + 0x7FFFu + ((v>>16)&1u);
  lo = (unsigned short)(s>>16);
}

// ---------------- CSR build ----------------
__global__ void k_count(const int* __restrict__ dst, int* __restrict__ deg){
  int e = blockIdx.x*blockDim.x + threadIdx.x;
  if (e < N_EDGES) atomicAdd(&deg[dst[e]], 1);
}

// hierarchical scan, stage 1: per-chunk exclusive scan + chunk totals
__global__ __launch_bounds__(1024) void k_scan1(const int* __restrict__ deg,
                                                int* __restrict__ excl, int* __restrict__ btot){
  __shared__ int buf[1024];
  int b = blockIdx.x, tid = threadIdx.x;
  int i = b*1024 + tid;
  int v = (i < N_NODES) ? deg[i] : 0;
  buf[tid] = v;
  __syncthreads();
  for (int ofs = 1; ofs < 1024; ofs <<= 1){
    int t = (tid >= ofs) ? buf[tid-ofs] : 0;
    __syncthreads();
    buf[tid] += t;
    __syncthreads();
  }
  excl[i] = buf[tid] - v;
  if (tid == 1023) btot[b] = buf[1023];
}

// stage 2: add chunk carries, write off + degree scalers
__global__ __launch_bounds__(1024) void k_scan2(
    const int* __restrict__ deg, const int* __restrict__ excl, const int* __restrict__ btot,
    int* __restrict__ off, float* __restrict__ invd,
    float* __restrict__ amp, float* __restrict__ att){
  __shared__ int carry_s;
  int b = blockIdx.x, tid = threadIdx.x;
  if (tid == 0){
    int c = 0;
    for (int j = 0; j < b; ++j) c += btot[j];
    carry_s = c;
  }
  __syncthreads();
  int i = b*1024 + tid;
  if (i <= N_NODES){
    off[i] = carry_s + excl[i];
    if (i < N_NODES){
      float d = (float)deg[i];
      invd[i] = 1.f / fmaxf(d, 1.f);
      float ld = log1pf(d);
      amp[i] = ld / AVG_LOG;
      att[i] = AVG_LOG / fmaxf(ld, EPS);
    }
  }
}

__global__ void k_fill(const int* __restrict__ src, const int* __restrict__ dst,
                       const int* __restrict__ eattr, const int* __restrict__ off,
                       int* __restrict__ cursor,
                       int* __restrict__ srcS, int* __restrict__ eaS){
  int e = blockIdx.x*blockDim.x + threadIdx.x;
  if (e < N_EDGES){
    int d = dst[e];
    int pos = off[d] + atomicAdd(&cursor[d], 1);
    srcS[pos] = src[e]; eaS[pos] = eattr[e];
  }
}

// graph offsets via binary search on sorted batch
__global__ void k_goff(const int* __restrict__ batch, int* __restrict__ goff){
  int g = threadIdx.x;
  if (g <= N_GRAPHS){
    int lo = 0, hi = N_NODES;
    while (lo < hi){ int mid = (lo+hi)>>1; if (batch[mid] < g) lo = mid+1; else hi = mid; }
    goff[g] = lo;
  }
}

__global__ void k_hinit(const int* __restrict__ x, const float* __restrict__ atom_emb,
                        float* __restrict__ h){
  int idx = blockIdx.x*blockDim.x + threadIdx.x;
  if (idx < N_NODES*32){
    int n = idx >> 5, q = idx & 31;
    ((float4*)h)[(size_t)n*32 + q] = ((const float4*)atom_emb)[(size_t)x[n]*32 + q];
  }
}

// bond tables for ALL layers: BW3all[l][r][c] = bond_emb[r]@preW3_l[:,c] + pre_b_l[c]
__global__ void k_bondall(const float* __restrict__ bond_emb, const float* __restrict__ pre_W,
                          const float* __restrict__ pre_b, float* __restrict__ BW3all){
  int l = blockIdx.x, tid = threadIdx.x;   // 4 blocks x 512
  int r = tid >> 7, c = tid & 127;
  const float* W3 = pre_W + (size_t)l*384*128 + 256*128;
  float s = pre_b[l*128 + c];
  for (int k = 0; k < 128; ++k) s = fmaf(bond_emb[r*128 + k], W3[k*128 + c], s);
  BW3all[l*512 + tid] = s;
}

// ---------------- weight pre-transpose + bf16 hi/lo split ----------------
__global__ void k_wt(const float* __restrict__ pre_W, const float* __restrict__ post_W,
                     const float* __restrict__ mix_W,
                     unsigned short* __restrict__ whi, unsigned short* __restrict__ wlo){
  int y = blockIdx.y; int l = y/7, j = y%7;
  int K = (j>=3 && j<6) ? 512 : 128;
  const float* src; size_t off;
  if (j < 2)      { src = pre_W  + (size_t)l*384*128  + (size_t)j*128*128;            off = (size_t)j*16384; }
  else if (j == 2){ src = post_W + (size_t)l*1664*128;                                off = 2*16384; }
  else if (j < 6) { src = post_W + (size_t)l*1664*128 + (size_t)(128+(j-3)*512)*128;  off = 49152 + (size_t)(j-3)*65536; }
  else            { src = mix_W  + (size_t)l*128*128;                                 off = 245760; }
  unsigned short* dh = whi + (size_t)l*262144 + off;
  unsigned short* dl = wlo + (size_t)l*262144 + off;
  int kq8 = K/8;
  int ntask = 128*kq8;
  int t = blockIdx.x*256 + threadIdx.x;
  if (t >= ntask) return;
  int c  = t / kq8;
  int k0 = (t % kq8)*8;
  unsigned short h8[8] __attribute__((aligned(16)));
  unsigned short l8[8] __attribute__((aligned(16)));
  #pragma unroll
  for (int i=0;i<8;++i) bsplit(src[(size_t)(k0+i)*128 + c], h8[i], l8[i]);
  *(uint4*)(dh + (size_t)c*K + k0) = *(const uint4*)h8;
  *(uint4*)(dl + (size_t)c*K + k0) = *(const uint4*)l8;
}

// ---------------- split-bf16 MFMA GEMM (MODE 0: triple head K=128; MODE 1: agg K=512) ----------------
// 1-D grid MB64*3, heads innermost (y = bid%3) so the 3 heads of one row-tile
// are co-resident -> A-tile reads of heads 1,2 hit L2/L3.
template<int MODE>
__global__ __launch_bounds__(256) void k_mf(
    const unsigned short* __restrict__ whi, const unsigned short* __restrict__ wlo,
    const float* __restrict__ A, float* __restrict__ out)
{
  const int K    = (MODE==1) ? 512 : 128;
  const int ASTR = (MODE==1) ? 512 : 128;
  const int OSTR = (MODE==1) ? 384 : 128;
  __shared__ unsigned short Ah[64*PITCH], Al[64*PITCH], Bh[128*PITCH], Bl[128*PITCH];
  int tid = threadIdx.x;
  int lane = tid & 63;
  int wv = tid >> 6;
  int wm = (wv>>1)*32, wn = (wv&1)*64;
  int y = blockIdx.x % 3;
  int mbase = (blockIdx.x / 3) * 64;
  const unsigned short* wh = whi + (size_t)y*K*128;
  const unsigned short* wl = wlo + (size_t)y*K*128;
  float* outp = out; int ocol = 0;
  if (MODE == 0) outp = out + (size_t)y*N_NODES*128;
  if (MODE == 1) ocol = y*128;

  int a_row = tid >> 2, a_kg = tid & 3;
  int a_nrow = min(mbase + a_row, N_NODES-1);
  const float* a_src = A + (size_t)a_nrow*ASTR + a_kg*8;
  unsigned short* a_dh = Ah + a_row*PITCH + a_kg*8;
  unsigned short* a_dl = Al + a_row*PITCH + a_kg*8;

  f32x4 acc[2][4];
  #pragma unroll
  for (int mi=0;mi<2;++mi)
    #pragma unroll
    for (int ni=0;ni<4;++ni)
      acc[mi][ni] = (f32x4){0.f,0.f,0.f,0.f};

  int lr = lane & 15, lk = lane >> 4;

  for (int kt = 0; kt < K; kt += 32){
    #pragma unroll
    for (int i=0;i<2;++i){
      int s = tid + 256*i;
      int col = s >> 2, kg = s & 3;
      *(uint4*)(Bh + col*PITCH + kg*8) = *(const uint4*)(wh + (size_t)col*K + kt + kg*8);
      *(uint4*)(Bl + col*PITCH + kg*8) = *(const uint4*)(wl + (size_t)col*K + kt + kg*8);
    }
    {
      float4 f0 = *(const float4*)(a_src + kt);
      float4 f1 = *(const float4*)(a_src + kt + 4);
      float fv[8] = {f0.x,f0.y,f0.z,f0.w,f1.x,f1.y,f1.z,f1.w};
      unsigned short h8[8] __attribute__((aligned(16)));
      unsigned short l8[8] __attribute__((aligned(16)));
      #pragma unroll
      for (int i=0;i<8;++i) bsplit(fv[i], h8[i], l8[i]);
      *(uint4*)a_dh = *(const uint4*)h8;
      *(uint4*)a_dl = *(const uint4*)l8;
    }
    __syncthreads();
    short8 ah[2], al[2], bh4[4], bl4[4];
    #pragma unroll
    for (int mi=0;mi<2;++mi){
      int idx = (wm + mi*16 + lr)*PITCH + lk*8;
      ah[mi] = *(const short8*)(Ah + idx);
      al[mi] = *(const short8*)(Al + idx);
    }
    #pragma unroll
    for (int ni=0;ni<4;++ni){
      int idx = (wn + ni*16 + lr)*PITCH + lk*8;
      bh4[ni] = *(const short8*)(Bh + idx);
      bl4[ni] = *(const short8*)(Bl + idx);
    }
    #pragma unroll
    for (int mi=0;mi<2;++mi){
      #pragma unroll
      for (int ni=0;ni<4;++ni){
        acc[mi][ni] = __builtin_amdgcn_mfma_f32_16x16x32_bf16(ah[mi], bh4[ni], acc[mi][ni], 0,0,0);
        acc[mi][ni] = __builtin_amdgcn_mfma_f32_16x16x32_bf16(ah[mi], bl4[ni], acc[mi][ni], 0,0,0);
        acc[mi][ni] = __builtin_amdgcn_mfma_f32_16x16x32_bf16(al[mi], bh4[ni], acc[mi][ni], 0,0,0);
      }
    }
    __syncthreads();
  }

  #pragma unroll
  for (int mi=0;mi<2;++mi){
    #pragma unroll
    for (int ni=0;ni<4;++ni){
      int gcol = wn + ni*16 + lr;
      #pragma unroll
      for (int r=0;r<4;++r){
        int grow = mbase + wm + mi*16 + lk*4 + r;
        if (grow < N_NODES)
          outp[(size_t)grow*OSTR + ocol + gcol] = acc[mi][ni][r];
      }
    }
  }
}

// ---------------- mix GEMM with fused combine (A-staging) + fused BN partials ----------------
__global__ __launch_bounds__(256) void k_mix(
    const unsigned short* __restrict__ wh, const unsigned short* __restrict__ wl,
    const float* __restrict__ Yh, const float* __restrict__ Yamt,
    const float* __restrict__ amp, const float* __restrict__ att,
    const float* __restrict__ post_b, const float* __restrict__ mix_b,
    const float* __restrict__ snorm,
    float* __restrict__ tb, float* __restrict__ bnpart)
{
  __shared__ unsigned short Ah[64*PITCH], Al[64*PITCH], Bh[128*PITCH], Bl[128*PITCH];
  __shared__ float bns[2][128], bnq[2][128];
  int tid = threadIdx.x;
  int lane = tid & 63;
  int wv = tid >> 6;
  int wm = (wv>>1)*32, wn = (wv&1)*64;
  int mbase = blockIdx.x*64;

  int a_row = tid >> 2, a_kg = tid & 3;
  int a_nrow = min(mbase + a_row, N_NODES-1);
  float av = amp[a_nrow], tv2 = att[a_nrow];
  const float* yhp = Yh   + (size_t)a_nrow*128;
  const float* yap = Yamt + (size_t)a_nrow*384;
  unsigned short* a_dh = Ah + a_row*PITCH + a_kg*8;
  unsigned short* a_dl = Al + a_row*PITCH + a_kg*8;

  f32x4 acc[2][4];
  #pragma unroll
  for (int mi=0;mi<2;++mi)
    #pragma unroll
    for (int ni=0;ni<4;++ni)
      acc[mi][ni] = (f32x4){0.f,0.f,0.f,0.f};

  int lr = lane & 15, lk = lane >> 4;

  for (int kt = 0; kt < 128; kt += 32){
    #pragma unroll
    for (int i=0;i<2;++i){
      int s = tid + 256*i;
      int col = s >> 2, kg = s & 3;
      *(uint4*)(Bh + col*PITCH + kg*8) = *(const uint4*)(wh + (size_t)col*128 + kt + kg*8);
      *(uint4*)(Bl + col*PITCH + kg*8) = *(const uint4*)(wl + (size_t)col*128 + kt + kg*8);
    }
    {
      int c0 = kt + a_kg*8;
      float4 h0 = *(const float4*)(yhp + c0),       h1 = *(const float4*)(yhp + c0 + 4);
      float4 a0 = *(const float4*)(yap + c0),       a1 = *(const float4*)(yap + c0 + 4);
      float4 m0 = *(const float4*)(yap + 128 + c0), m1 = *(const float4*)(yap + 132 + c0);
      float4 t0 = *(const float4*)(yap + 256 + c0), t1 = *(const float4*)(yap + 260 + c0);
      float4 p0 = *(const float4*)(post_b + c0),    p1 = *(const float4*)(post_b + c0 + 4);
      float fv[8];
      fv[0] = leaky(h0.x + a0.x + av*m0.x + tv2*t0.x + p0.x);
      fv[1] = leaky(h0.y + a0.y + av*m0.y + tv2*t0.y + p0.y);
      fv[2] = leaky(h0.z + a0.z + av*m0.z + tv2*t0.z + p0.z);
      fv[3] = leaky(h0.w + a0.w + av*m0.w + tv2*t0.w + p0.w);
      fv[4] = leaky(h1.x + a1.x + av*m1.x + tv2*t1.x + p1.x);
      fv[5] = leaky(h1.y + a1.y + av*m1.y + tv2*t1.y + p1.y);
      fv[6] = leaky(h1.z + a1.z + av*m1.z + tv2*t1.z + p1.z);
      fv[7] = leaky(h1.w + a1.w + av*m1.w + tv2*t1.w + p1.w);
      unsigned short h8[8] __attribute__((aligned(16)));
      unsigned short l8[8] __attribute__((aligned(16)));
      #pragma unroll
      for (int i=0;i<8;++i) bsplit(fv[i], h8[i], l8[i]);
      *(uint4*)a_dh = *(const uint4*)h8;
      *(uint4*)a_dl = *(const uint4*)l8;
    }
    __syncthreads();
    short8 ah[2], al[2], bh4[4], bl4[4];
    #pragma unroll
    for (int mi=0;mi<2;++mi){
      int idx = (wm + mi*16 + lr)*PITCH + lk*8;
      ah[mi] = *(const short8*)(Ah + idx);
      al[mi] = *(const short8*)(Al + idx);
    }
    #pragma unroll
    for (int ni=0;ni<4;++ni){
      int idx = (wn + ni*16 + lr)*PITCH + lk*8;
      bh4[ni] = *(const short8*)(Bh + idx);
      bl4[ni] = *(const short8*)(Bl + idx);
    }
    #pragma unroll
    for (int mi=0;mi<2;++mi){
      #pragma unroll
      for (int ni=0;ni<4;++ni){
        acc[mi][ni] = __builtin_amdgcn_mfma_f32_16x16x32_bf16(ah[mi], bh4[ni], acc[mi][ni], 0,0,0);
        acc[mi][ni] = __builtin_amdgcn_mfma_f32_16x16x32_bf16(ah[mi], bl4[ni], acc[mi][ni], 0,0,0);
        acc[mi][ni] = __builtin_amdgcn_mfma_f32_16x16x32_bf16(al[mi], bh4[ni], acc[mi][ni], 0,0,0);
      }
    }
    __syncthreads();
  }

  float sn[2][4]; bool vld[2][4];
  #pragma unroll
  for (int mi=0;mi<2;++mi)
    #pragma unroll
    for (int r=0;r<4;++r){
      int grow = mbase + wm + mi*16 + lk*4 + r;
      vld[mi][r] = (grow < N_NODES);
      sn[mi][r] = vld[mi][r] ? snorm[grow] : 0.f;
    }
  int half = wv >> 1;
  #pragma unroll
  for (int ni=0;ni<4;++ni){
    int gcol = wn + ni*16 + lr;
    float bv = mix_b[gcol];
    float s = 0.f, q = 0.f;
    #pragma unroll
    for (int mi=0;mi<2;++mi){
      #pragma unroll
      for (int r=0;r<4;++r){
        if (vld[mi][r]){
          int grow = mbase + wm + mi*16 + lk*4 + r;
          float v = leaky(acc[mi][ni][r] + bv) * sn[mi][r];
          tb[(size_t)grow*128 + gcol] = v;
          s += v; q += v*v;
        }
      }
    }
    s += __shfl_xor(s, 16); s += __shfl_xor(s, 32);
    q += __shfl_xor(q, 16); q += __shfl_xor(q, 32);
    if (lk == 0){ bns[half][gcol] = s; bnq[half][gcol] = q; }
  }
  __syncthreads();
  if (tid < 128){
    bnpart[(size_t)blockIdx.x*256 + tid]       = bns[0][tid] + bns[1][tid];
    bnpart[(size_t)blockIdx.x*256 + 128 + tid] = bnq[0][tid] + bnq[1][tid];
  }
}

// ---------------- fused edge-message + aggregation (x2 unrolled gather) ----------------
__global__ __launch_bounds__(256) void k_fusedagg(
    const float* __restrict__ H1, const float* __restrict__ H2,
    const float* __restrict__ BW3,
    const int* __restrict__ srcS, const int* __restrict__ eaS,
    const int* __restrict__ off, const float* __restrict__ invd,
    float* __restrict__ agg)
{
  __shared__ float bw[4][128];
  int tid = threadIdx.x;
  bw[tid>>7][tid&127]     = BW3[tid];
  bw[2+(tid>>7)][tid&127] = BW3[256+tid];
  __syncthreads();

  int node = blockIdx.x*8 + (tid>>5);
  int q = tid & 31;
  float4 c4 = ((const float4*)(H1 + (size_t)node*HID))[q];
  int s = off[node], e = off[node+1];
  float4 sum = make_float4(0,0,0,0), sq = make_float4(0,0,0,0);
  float4 mx = make_float4(-3.4e38f,-3.4e38f,-3.4e38f,-3.4e38f);
  float4 mn = make_float4( 3.4e38f, 3.4e38f, 3.4e38f, 3.4e38f);

  #define FA_BODY(T,B) { \
    float vx = leaky(c4.x + T.x + B.x); \
    float vy = leaky(c4.y + T.y + B.y); \
    float vz = leaky(c4.z + T.z + B.z); \
    float vw = leaky(c4.w + T.w + B.w); \
    sum.x += vx; sum.y += vy; sum.z += vz; sum.w += vw; \
    sq.x += vx*vx; sq.y += vy*vy; sq.z += vz*vz; sq.w += vw*vw; \
    mx.x = fmaxf(mx.x, vx); mx.y = fmaxf(mx.y, vy); mx.z = fmaxf(mx.z, vz); mx.w = fmaxf(mx.w, vw); \
    mn.x = fminf(mn.x, vx); mn.y = fminf(mn.y, vy); mn.z = fminf(mn.z, vz); mn.w = fminf(mn.w, vw); }

  int i = s;
  for (; i + 1 < e; i += 2){
    int sv0 = srcS[i],   ev0 = eaS[i];
    int sv1 = srcS[i+1], ev1 = eaS[i+1];
    float4 t0 = ((const float4*)(H2 + (size_t)sv0*HID))[q];
    float4 t1 = ((const float4*)(H2 + (size_t)sv1*HID))[q];
    float4 b0 = ((const float4*)(&bw[ev0][0]))[q];
    float4 b1 = ((const float4*)(&bw[ev1][0]))[q];
    FA_BODY(t0,b0)
    FA_BODY(t1,b1)
  }
  if (i < e){
    int sv = srcS[i], ev = eaS[i];
    float4 t  = ((const float4*)(H2 + (size_t)sv*HID))[q];
    float4 b4 = ((const float4*)(&bw[ev][0]))[q];
    FA_BODY(t,b4)
  }
  #undef FA_BODY

  bool has = (e > s);
  float iv = invd[node];
  float4 mean = make_float4(sum.x*iv, sum.y*iv, sum.z*iv, sum.w*iv);
  float4 msq  = make_float4(sq.x*iv,  sq.y*iv,  sq.z*iv,  sq.w*iv);
  float4 sd;
  sd.x = has ? sqrtf(fmaxf(msq.x - mean.x*mean.x, 0.f) + EPS) : 0.f;
  sd.y = has ? sqrtf(fmaxf(msq.y - mean.y*mean.y, 0.f) + EPS) : 0.f;
  sd.z = has ? sqrtf(fmaxf(msq.z - mean.z*mean.z, 0.f) + EPS) : 0.f;
  sd.w = has ? sqrtf(fmaxf(msq.w - mean.w*mean.w, 0.f) + EPS) : 0.f;
  if (!has){ mx = make_float4(0,0,0,0); mn = make_float4(0,0,0,0); }
  size_t base = (size_t)node*512;
  ((float4*)(agg + base      ))[q] = mean;
  ((float4*)(agg + base + 128))[q] = mx;
  ((float4*)(agg + base + 256))[q] = mn;
  ((float4*)(agg + base + 384))[q] = sd;
}

// ---------------- BN finalize (parallel reduce of block partials) ----------------
__global__ __launch_bounds__(512) void k_bnfinal(const float* __restrict__ bnpart,
                                                 float* __restrict__ mu, float* __restrict__ rstd){
  __shared__ double ss[4][128], qq[4][128];
  int tid = threadIdx.x;
  int c = tid & 127, p = tid >> 7;
  double s = 0.0, q = 0.0;
  for (int b = p; b < MB64; b += 4){
    s += (double)bnpart[(size_t)b*256 + c];
    q += (double)bnpart[(size_t)b*256 + 128 + c];
  }
  ss[p][c] = s; qq[p][c] = q;
  __syncthreads();
  if (p == 0){
    double S = ss[0][c] + ss[1][c] + ss[2][c] + ss[3][c];
    double Q = qq[0][c] + qq[1][c] + qq[2][c] + qq[3][c];
    double mean = S / (double)N_NODES;
    double var  = Q / (double)N_NODES - mean*mean;
    mu[c] = (float)mean;
    rstd[c] = rsqrtf((float)var + EPS);
  }
}

__global__ void k_apply(const float* __restrict__ t, const float* __restrict__ mu,
                        const float* __restrict__ rstd, const float* __restrict__ gamma,
                        const float* __restrict__ beta, float* __restrict__ h){
  int idx = blockIdx.x*blockDim.x + threadIdx.x;
  if (idx < N_NODES*32){
    int n = idx >> 5, q = idx & 31;
    float4 tv = ((const float4*)t)[(size_t)n*32 + q];
    float4 hv = ((float4*)h)[(size_t)n*32 + q];
    float4 g4 = ((const float4*)gamma)[q], b4 = ((const float4*)beta)[q];
    float4 m4 = ((const float4*)mu)[q],    r4 = ((const float4*)rstd)[q];
    hv.x += g4.x*(tv.x-m4.x)*r4.x + b4.x;
    hv.y += g4.y*(tv.y-m4.y)*r4.y + b4.y;
    hv.z += g4.z*(tv.z-m4.z)*r4.z + b4.z;
    hv.w += g4.w*(tv.w-m4.w)*r4.w + b4.w;
    ((float4*)h)[(size_t)n*32 + q] = hv;
  }
}

// ---------------- fused mean-pool + MLP readout (one block per graph) ----------------
__global__ __launch_bounds__(128) void k_poolread(
    const int* __restrict__ goff, const float* __restrict__ h,
    const float* __restrict__ W1, const float* __restrict__ b1,
    const float* __restrict__ W2, const float* __restrict__ b2,
    const float* __restrict__ W3, const float* __restrict__ b3,
    float* __restrict__ out){
  __shared__ float gl[128];
  __shared__ float a1[64];
  __shared__ float a2[32];
  int g = blockIdx.x, tid = threadIdx.x;
  int s = goff[g], e = goff[g+1];
  float sum = 0.f;
  for (int r = s; r < e; ++r) sum += h[(size_t)r*128 + tid];
  gl[tid] = sum / fmaxf((float)(e - s), 1.f);
  __syncthreads();
  if (tid < 64){
    float s1 = b1[tid];
    for (int k = 0; k < 128; ++k) s1 = fmaf(gl[k], W1[k*64 + tid], s1);
    a1[tid] = fmaxf(s1, 0.f);
  }
  __syncthreads();
  if (tid < 32){
    float s2 = b2[tid];
    for (int k = 0; k < 64; ++k) s2 = fmaf(a1[k], W2[k*32 + tid], s2);
    a2[tid] = fmaxf(s2, 0.f);
  }
  __syncthreads();
  if (tid == 0){
    float s3 = b3[0];
    for (int k = 0; k < 32; ++k) s3 = fmaf(a2[k], W3[k], s3);
    out[g] = s3;
  }
}

// ---------------- launch ----------------
extern "C" void kernel_launch(void* const* d_in, const int* in_sizes, int n_in,
                              void* d_out, int out_size, void* d_ws, size_t ws_size,
                              hipStream_t stream) {
  const int*   x        = (const int*)  d_in[0];
  const int*   batch    = (const int*)  d_in[1];
  const int*   ei       = (const int*)  d_in[2];
  const float* snorm    = (const float*)d_in[3];
  const int*   eattr    = (const int*)  d_in[4];
  const float* atom_emb = (const float*)d_in[5];
  const float* bond_emb = (const float*)d_in[6];
  const float* pre_W    = (const float*)d_in[7];
  const float* pre_b    = (const float*)d_in[8];
  const float* post_W   = (const float*)d_in[9];
  const float* post_b   = (const float*)d_in[10];
  const float* mix_W    = (const float*)d_in[11];
  const float* mix_b    = (const float*)d_in[12];
  const float* bn_g     = (const float*)d_in[13];
  const float* bn_b     = (const float*)d_in[14];
  const float* rW1      = (const float*)d_in[15];
  const float* rb1      = (const float*)d_in[16];
  const float* rW2      = (const float*)d_in[17];
  const float* rb2      = (const float*)d_in[18];
  const float* rW3      = (const float*)d_in[19];
  const float* rb3      = (const float*)d_in[20];
  float* outp = (float*)d_out;

  const int* srcI = ei;            // edge_index[0]
  const int* dstI = ei + N_EDGES;  // edge_index[1]

  char* ws = (char*)d_ws;
  size_t o = 0;
  auto alloc = [&](size_t bytes)->char* {
    char* p = ws + o;
    o = (o + bytes + 255) & ~(size_t)255;
    return p;
  };
  int*    deg    = (int*)   alloc((size_t)N_NODES*4);
  int*    cursor = (int*)   alloc((size_t)N_NODES*4);
  int*    excl   = (int*)   alloc((size_t)SCANB*1024*4);
  int*    btot   = (int*)   alloc((size_t)SCANB*4);
  int*    off    = (int*)   alloc((size_t)(N_NODES+1)*4);
  int*    goff   = (int*)   alloc((size_t)(N_GRAPHS+1)*4);
  int*    srcS   = (int*)   alloc((size_t)N_EDGES*4);
  int*    eaS    = (int*)   alloc((size_t)N_EDGES*4);
  float*  invd   = (float*) alloc((size_t)N_NODES*4);
  float*  ampb   = (float*) alloc((size_t)N_NODES*4);
  float*  attb   = (float*) alloc((size_t)N_NODES*4);
  float*  h      = (float*) alloc((size_t)N_NODES*HID*4);
  float*  H3     = (float*) alloc((size_t)3*N_NODES*HID*4);   // H1 | H2 | Yh
  float*  Yamt   = (float*) alloc((size_t)N_NODES*384*4);
  float*  BW3all = (float*) alloc((size_t)NLAYERS*512*4);
  float*  agg    = (float*) alloc((size_t)N_NODES*512*4);
  float*  tb     = (float*) alloc((size_t)N_NODES*HID*4);
  unsigned short* whi = (unsigned short*)alloc((size_t)NLAYERS*262144*2);
  unsigned short* wlo = (unsigned short*)alloc((size_t)NLAYERS*262144*2);
  float*  bnpart = (float*) alloc((size_t)MB64*256*4);
  float*  mu     = (float*) alloc(128*4);
  float*  rstd   = (float*) alloc(128*4);

  // zero deg + cursor: cursor is 256B-aligned after deg, so cover the full span
  hipMemsetAsync(deg, 0, (size_t)((char*)cursor - (char*)deg) + (size_t)N_NODES*4, stream);
  k_count<<<(N_EDGES+255)/256, 256, 0, stream>>>(dstI, deg);
  k_scan1<<<SCANB, 1024, 0, stream>>>(deg, excl, btot);
  k_scan2<<<SCANB, 1024, 0, stream>>>(deg, excl, btot, off, invd, ampb, attb);
  k_fill<<<(N_EDGES+255)/256, 256, 0, stream>>>(srcI, dstI, eattr, off, cursor, srcS, eaS);
  k_goff<<<1, 512, 0, stream>>>(batch, goff);
  k_hinit<<<(N_NODES*32+255)/256, 256, 0, stream>>>(x, atom_emb, h);
  k_wt<<<dim3(32, NLAYERS*7), 256, 0, stream>>>(pre_W, post_W, mix_W, whi, wlo);
  k_bondall<<<NLAYERS, 512, 0, stream>>>(bond_emb, pre_W, pre_b, BW3all);

  float* H1 = H3;
  float* H2 = H3 + (size_t)N_NODES*HID;
  float* Yh = H3 + (size_t)2*N_NODES*HID;
  for (int l = 0; l < NLAYERS; ++l){
    const unsigned short* whl = whi + (size_t)l*262144;
    const unsigned short* wll = wlo + (size_t)l*262144;
    // triple head GEMM on h: H1, H2, Yh (heads innermost in 1-D grid)
    k_mf<0><<<MB64*3, 256, 0, stream>>>(whl, wll, h, H3);
    // fused edge message + aggregation
    k_fusedagg<<<N_NODES/8, 256, 0, stream>>>(H1, H2, BW3all + (size_t)l*512,
        srcS, eaS, off, invd, agg);
    // agg GEMM: Yamt = agg @ [W_a | W_m | W_t] (heads innermost)
    k_mf<1><<<MB64*3, 256, 0, stream>>>(whl + 49152, wll + 49152, agg, Yamt);
    // mix with fused combine + BN partials
    k_mix<<<MB64, 256, 0, stream>>>(whl + 245760, wll + 245760,
        Yh, Yamt, ampb, attb, post_b + (size_t)l*128, mix_b + (size_t)l*128,
        snorm, tb, bnpart);
    k_bnfinal<<<1, 512, 0, stream>>>(bnpart, mu, rstd);
    k_apply<<<(N_NODES*32+255)/256, 256, 0, stream>>>(tb, mu, rstd,
        bn_g + (size_t)l*128, bn_b + (size_t)l*128, h);
  }

  k_poolread<<<N_GRAPHS, 128, 0, stream>>>(goff, h, rW1, rb1, rW2, rb2, rW3, rb3, outp);
}

// Round 9
// 611.866 us; speedup vs baseline: 4.4396x; 1.0047x over previous
//
#include <hip/hip_runtime.h>
#include <math.h>

#define N_NODES 20000
#define N_EDGES 320000
#define N_GRAPHS 256
#define HID 128
#define NLAYERS 4
#define AVG_LOG 2.833213344056216f
#define EPS 1e-5f
#define MB64 313     // ceil(N_NODES/64)
#define NPAD 20032   // MB64*64, padded rows for bf16 planes
#define SCANB 20     // ceil(N_NODES/1024)
#define PITCH 40     // LDS row pitch for k_mix (u16)

typedef __attribute__((ext_vector_type(8))) short short8;
typedef __attribute__((ext_vector_type(4))) float f32x4;

static __device__ __forceinline__ float leaky(float v){ return v > 0.f ? v : 0.01f*v; }

// round-to-nearest-even fp32 -> (hi, lo) bf16 pair, f ~= hi + lo
static __device__ __forceinline__ void bsplit(float f, unsigned short& hi, unsigned short& lo){
  unsigned int u = __float_as_uint(f);
  unsigned int r = u + 0x7FFFu + ((u>>16)&1u);
  hi = (unsigned short)(r>>16);
  float hf = __uint_as_float(((unsigned int)hi)<<16);
  float l = f - hf;
  unsigned int v = __float_as_uint(l);
  unsigned int s = v + 0x7FFFu + ((v>>16)&1u);
  lo = (unsigned short)(s>>16);
}

static __device__ __forceinline__ void bsplit4(float4 f, ushort4& h, ushort4& l){
  bsplit(f.x, h.x, l.x); bsplit(f.y, h.y, l.y);
  bsplit(f.z, h.z, l.z); bsplit(f.w, h.w, l.w);
}

// async global -> LDS, 16B per lane (dest = wave-uniform base + lane*16)
static __device__ __forceinline__ void gload16(const void* g, void* l){
  __builtin_amdgcn_global_load_lds((const __attribute__((address_space(1))) void*)g,
                                   (__attribute__((address_space(3))) void*)l, 16, 0, 0);
}

// ---------------- CSR build ----------------
__global__ void k_count(const int* __restrict__ dst, int* __restrict__ deg){
  int e = blockIdx.x*blockDim.x + threadIdx.x;
  if (e < N_EDGES) atomicAdd(&deg[dst[e]], 1);
}

__global__ __launch_bounds__(1024) void k_scan1(const int* __restrict__ deg,
                                                int* __restrict__ excl, int* __restrict__ btot){
  __shared__ int buf[1024];
  int b = blockIdx.x, tid = threadIdx.x;
  int i = b*1024 + tid;
  int v = (i < N_NODES) ? deg[i] : 0;
  buf[tid] = v;
  __syncthreads();
  for (int ofs = 1; ofs < 1024; ofs <<= 1){
    int t = (tid >= ofs) ? buf[tid-ofs] : 0;
    __syncthreads();
    buf[tid] += t;
    __syncthreads();
  }
  excl[i] = buf[tid] - v;
  if (tid == 1023) btot[b] = buf[1023];
}

__global__ __launch_bounds__(1024) void k_scan2(
    const int* __restrict__ deg, const int* __restrict__ excl, const int* __restrict__ btot,
    int* __restrict__ off, float* __restrict__ invd,
    float* __restrict__ amp, float* __restrict__ att){
  __shared__ int carry_s;
  int b = blockIdx.x, tid = threadIdx.x;
  if (tid == 0){
    int c = 0;
    for (int j = 0; j < b; ++j) c += btot[j];
    carry_s = c;
  }
  __syncthreads();
  int i = b*1024 + tid;
  if (i <= N_NODES){
    off[i] = carry_s + excl[i];
    if (i < N_NODES){
      float d = (float)deg[i];
      invd[i] = 1.f / fmaxf(d, 1.f);
      float ld = log1pf(d);
      amp[i] = ld / AVG_LOG;
      att[i] = AVG_LOG / fmaxf(ld, EPS);
    }
  }
}

__global__ void k_fill(const int* __restrict__ src, const int* __restrict__ dst,
                       const int* __restrict__ eattr, const int* __restrict__ off,
                       int* __restrict__ cursor,
                       int* __restrict__ srcS, int* __restrict__ eaS){
  int e = blockIdx.x*blockDim.x + threadIdx.x;
  if (e < N_EDGES){
    int d = dst[e];
    int pos = off[d] + atomicAdd(&cursor[d], 1);
    srcS[pos] = src[e]; eaS[pos] = eattr[e];
  }
}

__global__ void k_goff(const int* __restrict__ batch, int* __restrict__ goff){
  int g = threadIdx.x;
  if (g <= N_GRAPHS){
    int lo = 0, hi = N_NODES;
    while (lo < hi){ int mid = (lo+hi)>>1; if (batch[mid] < g) lo = mid+1; else hi = mid; }
    goff[g] = lo;
  }
}

__global__ void k_hinit(const int* __restrict__ x, const float* __restrict__ atom_emb,
                        float* __restrict__ h,
                        unsigned short* __restrict__ h16h, unsigned short* __restrict__ h16l){
  int idx = blockIdx.x*blockDim.x + threadIdx.x;
  if (idx < N_NODES*32){
    int n = idx >> 5, q = idx & 31;
    float4 v = ((const float4*)atom_emb)[(size_t)x[n]*32 + q];
    ((float4*)h)[(size_t)n*32 + q] = v;
    ushort4 hh, ll; bsplit4(v, hh, ll);
    *(ushort4*)(h16h + (size_t)n*128 + q*4) = hh;
    *(ushort4*)(h16l + (size_t)n*128 + q*4) = ll;
  }
}

__global__ void k_bondall(const float* __restrict__ bond_emb, const float* __restrict__ pre_W,
                          const float* __restrict__ pre_b, float* __restrict__ BW3all){
  int l = blockIdx.x, tid = threadIdx.x;   // 4 blocks x 512
  int r = tid >> 7, c = tid & 127;
  const float* W3 = pre_W + (size_t)l*384*128 + 256*128;
  float s = pre_b[l*128 + c];
  for (int k = 0; k < 128; ++k) s = fmaf(bond_emb[r*128 + k], W3[k*128 + c], s);
  BW3all[l*512 + tid] = s;
}

// ---------------- weight pre-transpose + bf16 hi/lo split ----------------
__global__ void k_wt(const float* __restrict__ pre_W, const float* __restrict__ post_W,
                     const float* __restrict__ mix_W,
                     unsigned short* __restrict__ whi, unsigned short* __restrict__ wlo){
  int y = blockIdx.y; int l = y/7, j = y%7;
  int K = (j>=3 && j<6) ? 512 : 128;
  const float* src; size_t off;
  if (j < 2)      { src = pre_W  + (size_t)l*384*128  + (size_t)j*128*128;            off = (size_t)j*16384; }
  else if (j == 2){ src = post_W + (size_t)l*1664*128;                                off = 2*16384; }
  else if (j < 6) { src = post_W + (size_t)l*1664*128 + (size_t)(128+(j-3)*512)*128;  off = 49152 + (size_t)(j-3)*65536; }
  else            { src = mix_W  + (size_t)l*128*128;                                 off = 245760; }
  unsigned short* dh = whi + (size_t)l*262144 + off;
  unsigned short* dl = wlo + (size_t)l*262144 + off;
  int kq8 = K/8;
  int ntask = 128*kq8;
  int t = blockIdx.x*256 + threadIdx.x;
  if (t >= ntask) return;
  int c  = t / kq8;
  int k0 = (t % kq8)*8;
  unsigned short h8[8] __attribute__((aligned(16)));
  unsigned short l8[8] __attribute__((aligned(16)));
  #pragma unroll
  for (int i=0;i<8;++i) bsplit(src[(size_t)(k0+i)*128 + c], h8[i], l8[i]);
  *(uint4*)(dh + (size_t)c*K + k0) = *(const uint4*)h8;
  *(uint4*)(dl + (size_t)c*K + k0) = *(const uint4*)l8;
}

// ---------------- MFMA GEMM with global_load_lds staging ----------------
// MODE 0: K=128, A = h16 planes, out plane y of H3. MODE 1: K=512, A = agg16, out col-block y of Yamt.
// LDS linear [row][32] u16; k-chunk slot swizzled via global source address:
// kg = ls ^ (lq&3) ^ ((lq>>2)&3); read slot sl = lk ^ (lr&3) ^ ((lr>>2)&3).
template<int MODE>
__global__ __launch_bounds__(256) void k_mf16(
    const unsigned short* __restrict__ whi, const unsigned short* __restrict__ wlo,
    const unsigned short* __restrict__ Ahg, const unsigned short* __restrict__ Alg,
    float* __restrict__ out)
{
  const int K    = (MODE==1) ? 512 : 128;
  const int ASTR = (MODE==1) ? 512 : 128;
  const int OSTR = (MODE==1) ? 384 : 128;
  __shared__ unsigned short Ah[64*32], Al[64*32], Bh[128*32], Bl[128*32];
  int tid = threadIdx.x;
  int lane = tid & 63;
  int wv = tid >> 6;
  int wm = (wv>>1)*32, wn = (wv&1)*64;
  int y = blockIdx.x % 3;
  int mbase = (blockIdx.x / 3) * 64;
  const unsigned short* wh = whi + (size_t)y*K*128;
  const unsigned short* wl = wlo + (size_t)y*K*128;
  float* outp = out; int ocol = 0;
  if (MODE == 0) outp = out + (size_t)y*(size_t)N_NODES*128;
  if (MODE == 1) ocol = y*128;

  // per-lane DMA source setup
  int lq = lane >> 2, ls = lane & 3;
  int kg = ls ^ (lq & 3) ^ ((lq >> 2) & 3);           // swizzled k-chunk
  int a_row = wv*16 + lq;
  const unsigned short* agh = Ahg + (size_t)(mbase + a_row)*ASTR + kg*8;
  const unsigned short* agl = Alg + (size_t)(mbase + a_row)*ASTR + kg*8;
  unsigned short* a_ldsh = Ah + wv*512;
  unsigned short* a_ldsl = Al + wv*512;
  int b_col0 = (wv*2+0)*16 + lq;
  int b_col1 = (wv*2+1)*16 + lq;
  const unsigned short* bgh0 = wh + (size_t)b_col0*K + kg*8;
  const unsigned short* bgh1 = wh + (size_t)b_col1*K + kg*8;
  const unsigned short* bgl0 = wl + (size_t)b_col0*K + kg*8;
  const unsigned short* bgl1 = wl + (size_t)b_col1*K + kg*8;
  unsigned short* b_ldsh0 = Bh + (wv*2+0)*512;
  unsigned short* b_ldsh1 = Bh + (wv*2+1)*512;
  unsigned short* b_ldsl0 = Bl + (wv*2+0)*512;
  unsigned short* b_ldsl1 = Bl + (wv*2+1)*512;

  f32x4 acc[2][4];
  #pragma unroll
  for (int mi=0;mi<2;++mi)
    #pragma unroll
    for (int ni=0;ni<4;++ni)
      acc[mi][ni] = (f32x4){0.f,0.f,0.f,0.f};

  int lr = lane & 15, lk = lane >> 4;
  int sl = lk ^ (lr & 3) ^ ((lr >> 2) & 3);           // read slot

  for (int kt = 0; kt < K; kt += 32){
    gload16(agh + kt, a_ldsh);
    gload16(agl + kt, a_ldsl);
    gload16(bgh0 + kt, b_ldsh0);
    gload16(bgh1 + kt, b_ldsh1);
    gload16(bgl0 + kt, b_ldsl0);
    gload16(bgl1 + kt, b_ldsl1);
    __syncthreads();
    short8 ah[2], al2[2], bh4[4], bl4[4];
    #pragma unroll
    for (int mi=0;mi<2;++mi){
      int idx = (wm + mi*16 + lr)*32 + sl*8;
      ah[mi]  = *(const short8*)(Ah + idx);
      al2[mi] = *(const short8*)(Al + idx);
    }
    #pragma unroll
    for (int ni=0;ni<4;++ni){
      int idx = (wn + ni*16 + lr)*32 + sl*8;
      bh4[ni] = *(const short8*)(Bh + idx);
      bl4[ni] = *(const short8*)(Bl + idx);
    }
    #pragma unroll
    for (int mi=0;mi<2;++mi){
      #pragma unroll
      for (int ni=0;ni<4;++ni){
        acc[mi][ni] = __builtin_amdgcn_mfma_f32_16x16x32_bf16(ah[mi],  bh4[ni], acc[mi][ni], 0,0,0);
        acc[mi][ni] = __builtin_amdgcn_mfma_f32_16x16x32_bf16(ah[mi],  bl4[ni], acc[mi][ni], 0,0,0);
        acc[mi][ni] = __builtin_amdgcn_mfma_f32_16x16x32_bf16(al2[mi], bh4[ni], acc[mi][ni], 0,0,0);
      }
    }
    __syncthreads();
  }

  #pragma unroll
  for (int mi=0;mi<2;++mi){
    #pragma unroll
    for (int ni=0;ni<4;++ni){
      int gcol = wn + ni*16 + lr;
      #pragma unroll
      for (int r=0;r<4;++r){
        int grow = mbase + wm + mi*16 + lk*4 + r;
        if (grow < N_NODES)
          outp[(size_t)grow*OSTR + ocol + gcol] = acc[mi][ni][r];
      }
    }
  }
}

// ---------------- mix GEMM with fused combine (A-staging) + fused BN partials ----------------
__global__ __launch_bounds__(256) void k_mix(
    const unsigned short* __restrict__ wh, const unsigned short* __restrict__ wl,
    const float* __restrict__ Yh, const float* __restrict__ Yamt,
    const float* __restrict__ amp, const float* __restrict__ att,
    const float* __restrict__ post_b, const float* __restrict__ mix_b,
    const float* __restrict__ snorm,
    float* __restrict__ tb, float* __restrict__ bnpart)
{
  __shared__ unsigned short Ah[64*PITCH], Al[64*PITCH], Bh[128*PITCH], Bl[128*PITCH];
  __shared__ float bns[2][128], bnq[2][128];
  int tid = threadIdx.x;
  int lane = tid & 63;
  int wv = tid >> 6;
  int wm = (wv>>1)*32, wn = (wv&1)*64;
  int mbase = blockIdx.x*64;

  int a_row = tid >> 2, a_kg = tid & 3;
  int a_nrow = min(mbase + a_row, N_NODES-1);
  float av = amp[a_nrow], tv2 = att[a_nrow];
  const float* yhp = Yh   + (size_t)a_nrow*128;
  const float* yap = Yamt + (size_t)a_nrow*384;
  unsigned short* a_dh = Ah + a_row*PITCH + a_kg*8;
  unsigned short* a_dl = Al + a_row*PITCH + a_kg*8;

  f32x4 acc[2][4];
  #pragma unroll
  for (int mi=0;mi<2;++mi)
    #pragma unroll
    for (int ni=0;ni<4;++ni)
      acc[mi][ni] = (f32x4){0.f,0.f,0.f,0.f};

  int lr = lane & 15, lk = lane >> 4;

  for (int kt = 0; kt < 128; kt += 32){
    #pragma unroll
    for (int i=0;i<2;++i){
      int s = tid + 256*i;
      int col = s >> 2, kgg = s & 3;
      *(uint4*)(Bh + col*PITCH + kgg*8) = *(const uint4*)(wh + (size_t)col*128 + kt + kgg*8);
      *(uint4*)(Bl + col*PITCH + kgg*8) = *(const uint4*)(wl + (size_t)col*128 + kt + kgg*8);
    }
    {
      int c0 = kt + a_kg*8;
      float4 h0 = *(const float4*)(yhp + c0),       h1 = *(const float4*)(yhp + c0 + 4);
      float4 a0 = *(const float4*)(yap + c0),       a1 = *(const float4*)(yap + c0 + 4);
      float4 m0 = *(const float4*)(yap + 128 + c0), m1 = *(const float4*)(yap + 132 + c0);
      float4 t0 = *(const float4*)(yap + 256 + c0), t1 = *(const float4*)(yap + 260 + c0);
      float4 p0 = *(const float4*)(post_b + c0),    p1 = *(const float4*)(post_b + c0 + 4);
      float fv[8];
      fv[0] = leaky(h0.x + a0.x + av*m0.x + tv2*t0.x + p0.x);
      fv[1] = leaky(h0.y + a0.y + av*m0.y + tv2*t0.y + p0.y);
      fv[2] = leaky(h0.z + a0.z + av*m0.z + tv2*t0.z + p0.z);
      fv[3] = leaky(h0.w + a0.w + av*m0.w + tv2*t0.w + p0.w);
      fv[4] = leaky(h1.x + a1.x + av*m1.x + tv2*t1.x + p1.x);
      fv[5] = leaky(h1.y + a1.y + av*m1.y + tv2*t1.y + p1.y);
      fv[6] = leaky(h1.z + a1.z + av*m1.z + tv2*t1.z + p1.z);
      fv[7] = leaky(h1.w + a1.w + av*m1.w + tv2*t1.w + p1.w);
      unsigned short h8[8] __attribute__((aligned(16)));
      unsigned short l8[8] __attribute__((aligned(16)));
      #pragma unroll
      for (int i=0;i<8;++i) bsplit(fv[i], h8[i], l8[i]);
      *(uint4*)a_dh = *(const uint4*)h8;
      *(uint4*)a_dl = *(const uint4*)l8;
    }
    __syncthreads();
    short8 ah[2], al2[2], bh4[4], bl4[4];
    #pragma unroll
    for (int mi=0;mi<2;++mi){
      int idx = (wm + mi*16 + lr)*PITCH + lk*8;
      ah[mi]  = *(const short8*)(Ah + idx);
      al2[mi] = *(const short8*)(Al + idx);
    }
    #pragma unroll
    for (int ni=0;ni<4;++ni){
      int idx = (wn + ni*16 + lr)*PITCH + lk*8;
      bh4[ni] = *(const short8*)(Bh + idx);
      bl4[ni] = *(const short8*)(Bl + idx);
    }
    #pragma unroll
    for (int mi=0;mi<2;++mi){
      #pragma unroll
      for (int ni=0;ni<4;++ni){
        acc[mi][ni] = __builtin_amdgcn_mfma_f32_16x16x32_bf16(ah[mi],  bh4[ni], acc[mi][ni], 0,0,0);
        acc[mi][ni] = __builtin_amdgcn_mfma_f32_16x16x32_bf16(ah[mi],  bl4[ni], acc[mi][ni], 0,0,0);
        acc[mi][ni] = __builtin_amdgcn_mfma_f32_16x16x32_bf16(al2[mi], bh4[ni], acc[mi][ni], 0,0,0);
      }
    }
    __syncthreads();
  }

  float sn[2][4]; bool vld[2][4];
  #pragma unroll
  for (int mi=0;mi<2;++mi)
    #pragma unroll
    for (int r=0;r<4;++r){
      int grow = mbase + wm + mi*16 + lk*4 + r;
      vld[mi][r] = (grow < N_NODES);
      sn[mi][r] = vld[mi][r] ? snorm[grow] : 0.f;
    }
  int half = wv >> 1;
  #pragma unroll
  for (int ni=0;ni<4;++ni){
    int gcol = wn + ni*16 + lr;
    float bv = mix_b[gcol];
    float s = 0.f, q = 0.f;
    #pragma unroll
    for (int mi=0;mi<2;++mi){
      #pragma unroll
      for (int r=0;r<4;++r){
        if (vld[mi][r]){
          int grow = mbase + wm + mi*16 + lk*4 + r;
          float v = leaky(acc[mi][ni][r] + bv) * sn[mi][r];
          tb[(size_t)grow*128 + gcol] = v;
          s += v; q += v*v;
        }
      }
    }
    s += __shfl_xor(s, 16); s += __shfl_xor(s, 32);
    q += __shfl_xor(q, 16); q += __shfl_xor(q, 32);
    if (lk == 0){ bns[half][gcol] = s; bnq[half][gcol] = q; }
  }
  __syncthreads();
  if (tid < 128){
    bnpart[(size_t)blockIdx.x*256 + tid]       = bns[0][tid] + bns[1][tid];
    bnpart[(size_t)blockIdx.x*256 + 128 + tid] = bnq[0][tid] + bnq[1][tid];
  }
}

// ---------------- fused edge-message + aggregation -> bf16 hi/lo planes ----------------
__global__ __launch_bounds__(256) void k_fusedagg(
    const float* __restrict__ H1, const float* __restrict__ H2,
    const float* __restrict__ BW3,
    const int* __restrict__ srcS, const int* __restrict__ eaS,
    const int* __restrict__ off, const float* __restrict__ invd,
    unsigned short* __restrict__ aggh, unsigned short* __restrict__ aggl)
{
  __shared__ float bw[4][128];
  int tid = threadIdx.x;
  bw[tid>>7][tid&127]     = BW3[tid];
  bw[2+(tid>>7)][tid&127] = BW3[256+tid];
  __syncthreads();

  int node = blockIdx.x*8 + (tid>>5);
  int q = tid & 31;
  float4 c4 = ((const float4*)(H1 + (size_t)node*HID))[q];
  int s = off[node], e = off[node+1];
  float4 sum = make_float4(0,0,0,0), sq = make_float4(0,0,0,0);
  float4 mx = make_float4(-3.4e38f,-3.4e38f,-3.4e38f,-3.4e38f);
  float4 mn = make_float4( 3.4e38f, 3.4e38f, 3.4e38f, 3.4e38f);

  #define FA_BODY(T,B) { \
    float vx = leaky(c4.x + T.x + B.x); \
    float vy = leaky(c4.y + T.y + B.y); \
    float vz = leaky(c4.z + T.z + B.z); \
    float vw = leaky(c4.w + T.w + B.w); \
    sum.x += vx; sum.y += vy; sum.z += vz; sum.w += vw; \
    sq.x += vx*vx; sq.y += vy*vy; sq.z += vz*vz; sq.w += vw*vw; \
    mx.x = fmaxf(mx.x, vx); mx.y = fmaxf(mx.y, vy); mx.z = fmaxf(mx.z, vz); mx.w = fmaxf(mx.w, vw); \
    mn.x = fminf(mn.x, vx); mn.y = fminf(mn.y, vy); mn.z = fminf(mn.z, vz); mn.w = fminf(mn.w, vw); }

  int i = s;
  for (; i + 1 < e; i += 2){
    int sv0 = srcS[i],   ev0 = eaS[i];
    int sv1 = srcS[i+1], ev1 = eaS[i+1];
    float4 t0 = ((const float4*)(H2 + (size_t)sv0*HID))[q];
    float4 t1 = ((const float4*)(H2 + (size_t)sv1*HID))[q];
    float4 b0 = ((const float4*)(&bw[ev0][0]))[q];
    float4 b1 = ((const float4*)(&bw[ev1][0]))[q];
    FA_BODY(t0,b0)
    FA_BODY(t1,b1)
  }
  if (i < e){
    int sv = srcS[i], ev = eaS[i];
    float4 t  = ((const float4*)(H2 + (size_t)sv*HID))[q];
    float4 b4 = ((const float4*)(&bw[ev][0]))[q];
    FA_BODY(t,b4)
  }
  #undef FA_BODY

  bool has = (e > s);
  float iv = invd[node];
  float4 mean = make_float4(sum.x*iv, sum.y*iv, sum.z*iv, sum.w*iv);
  float4 msq  = make_float4(sq.x*iv,  sq.y*iv,  sq.z*iv,  sq.w*iv);
  float4 sd;
  sd.x = has ? sqrtf(fmaxf(msq.x - mean.x*mean.x, 0.f) + EPS) : 0.f;
  sd.y = has ? sqrtf(fmaxf(msq.y - mean.y*mean.y, 0.f) + EPS) : 0.f;
  sd.z = has ? sqrtf(fmaxf(msq.z - mean.z*mean.z, 0.f) + EPS) : 0.f;
  sd.w = has ? sqrtf(fmaxf(msq.w - mean.w*mean.w, 0.f) + EPS) : 0.f;
  if (!has){ mx = make_float4(0,0,0,0); mn = make_float4(0,0,0,0); }
  size_t base = (size_t)node*512 + q*4;
  ushort4 hh, ll;
  bsplit4(mean, hh, ll);
  *(ushort4*)(aggh + base      ) = hh; *(ushort4*)(aggl + base      ) = ll;
  bsplit4(mx, hh, ll);
  *(ushort4*)(aggh + base + 128) = hh; *(ushort4*)(aggl + base + 128) = ll;
  bsplit4(mn, hh, ll);
  *(ushort4*)(aggh + base + 256) = hh; *(ushort4*)(aggl + base + 256) = ll;
  bsplit4(sd, hh, ll);
  *(ushort4*)(aggh + base + 384) = hh; *(ushort4*)(aggl + base + 384) = ll;
}

// ---------------- BN finalize ----------------
__global__ __launch_bounds__(512) void k_bnfinal(const float* __restrict__ bnpart,
                                                 float* __restrict__ mu, float* __restrict__ rstd){
  __shared__ double ss[4][128], qq[4][128];
  int tid = threadIdx.x;
  int c = tid & 127, p = tid >> 7;
  double s = 0.0, q = 0.0;
  for (int b = p; b < MB64; b += 4){
    s += (double)bnpart[(size_t)b*256 + c];
    q += (double)bnpart[(size_t)b*256 + 128 + c];
  }
  ss[p][c] = s; qq[p][c] = q;
  __syncthreads();
  if (p == 0){
    double S = ss[0][c] + ss[1][c] + ss[2][c] + ss[3][c];
    double Q = qq[0][c] + qq[1][c] + qq[2][c] + qq[3][c];
    double mean = S / (double)N_NODES;
    double var  = Q / (double)N_NODES - mean*mean;
    mu[c] = (float)mean;
    rstd[c] = rsqrtf((float)var + EPS);
  }
}

// BN apply + residual; also emit updated h as bf16 hi/lo planes
__global__ void k_apply(const float* __restrict__ t, const float* __restrict__ mu,
                        const float* __restrict__ rstd, const float* __restrict__ gamma,
                        const float* __restrict__ beta, float* __restrict__ h,
                        unsigned short* __restrict__ h16h, unsigned short* __restrict__ h16l){
  int idx = blockIdx.x*blockDim.x + threadIdx.x;
  if (idx < N_NODES*32){
    int n = idx >> 5, q = idx & 31;
    float4 tv = ((const float4*)t)[(size_t)n*32 + q];
    float4 hv = ((float4*)h)[(size_t)n*32 + q];
    float4 g4 = ((const float4*)gamma)[q], b4 = ((const float4*)beta)[q];
    float4 m4 = ((const float4*)mu)[q],    r4 = ((const float4*)rstd)[q];
    hv.x += g4.x*(tv.x-m4.x)*r4.x + b4.x;
    hv.y += g4.y*(tv.y-m4.y)*r4.y + b4.y;
    hv.z += g4.z*(tv.z-m4.z)*r4.z + b4.z;
    hv.w += g4.w*(tv.w-m4.w)*r4.w + b4.w;
    ((float4*)h)[(size_t)n*32 + q] = hv;
    ushort4 hh, ll; bsplit4(hv, hh, ll);
    *(ushort4*)(h16h + (size_t)n*128 + q*4) = hh;
    *(ushort4*)(h16l + (size_t)n*128 + q*4) = ll;
  }
}

// ---------------- fused mean-pool + MLP readout ----------------
__global__ __launch_bounds__(128) void k_poolread(
    const int* __restrict__ goff, const float* __restrict__ h,
    const float* __restrict__ W1, const float* __restrict__ b1,
    const float* __restrict__ W2, const float* __restrict__ b2,
    const float* __restrict__ W3, const float* __restrict__ b3,
    float* __restrict__ out){
  __shared__ float gl[128];
  __shared__ float a1[64];
  __shared__ float a2[32];
  int g = blockIdx.x, tid = threadIdx.x;
  int s = goff[g], e = goff[g+1];
  float sum = 0.f;
  for (int r = s; r < e; ++r) sum += h[(size_t)r*128 + tid];
  gl[tid] = sum / fmaxf((float)(e - s), 1.f);
  __syncthreads();
  if (tid < 64){
    float s1 = b1[tid];
    for (int k = 0; k < 128; ++k) s1 = fmaf(gl[k], W1[k*64 + tid], s1);
    a1[tid] = fmaxf(s1, 0.f);
  }
  __syncthreads();
  if (tid < 32){
    float s2 = b2[tid];
    for (int k = 0; k < 64; ++k) s2 = fmaf(a1[k], W2[k*32 + tid], s2);
    a2[tid] = fmaxf(s2, 0.f);
  }
  __syncthreads();
  if (tid == 0){
    float s3 = b3[0];
    for (int k = 0; k < 32; ++k) s3 = fmaf(a2[k], W3[k], s3);
    out[g] = s3;
  }
}

// ---------------- launch ----------------
extern "C" void kernel_launch(void* const* d_in, const int* in_sizes, int n_in,
                              void* d_out, int out_size, void* d_ws, size_t ws_size,
                              hipStream_t stream) {
  const int*   x        = (const int*)  d_in[0];
  const int*   batch    = (const int*)  d_in[1];
  const int*   ei       = (const int*)  d_in[2];
  const float* snorm    = (const float*)d_in[3];
  const int*   eattr    = (const int*)  d_in[4];
  const float* atom_emb = (const float*)d_in[5];
  const float* bond_emb = (const float*)d_in[6];
  const float* pre_W    = (const float*)d_in[7];
  const float* pre_b    = (const float*)d_in[8];
  const float* post_W   = (const float*)d_in[9];
  const float* post_b   = (const float*)d_in[10];
  const float* mix_W    = (const float*)d_in[11];
  const float* mix_b    = (const float*)d_in[12];
  const float* bn_g     = (const float*)d_in[13];
  const float* bn_b     = (const float*)d_in[14];
  const float* rW1      = (const float*)d_in[15];
  const float* rb1      = (const float*)d_in[16];
  const float* rW2      = (const float*)d_in[17];
  const float* rb2      = (const float*)d_in[18];
  const float* rW3      = (const float*)d_in[19];
  const float* rb3      = (const float*)d_in[20];
  float* outp = (float*)d_out;

  const int* srcI = ei;            // edge_index[0]
  const int* dstI = ei + N_EDGES;  // edge_index[1]

  char* ws = (char*)d_ws;
  size_t o = 0;
  auto alloc = [&](size_t bytes)->char* {
    char* p = ws + o;
    o = (o + bytes + 255) & ~(size_t)255;
    return p;
  };
  int*    deg    = (int*)   alloc((size_t)N_NODES*4);
  int*    cursor = (int*)   alloc((size_t)N_NODES*4);
  int*    excl   = (int*)   alloc((size_t)SCANB*1024*4);
  int*    btot   = (int*)   alloc((size_t)SCANB*4);
  int*    off    = (int*)   alloc((size_t)(N_NODES+1)*4);
  int*    goff   = (int*)   alloc((size_t)(N_GRAPHS+1)*4);
  int*    srcS   = (int*)   alloc((size_t)N_EDGES*4);
  int*    eaS    = (int*)   alloc((size_t)N_EDGES*4);
  float*  invd   = (float*) alloc((size_t)N_NODES*4);
  float*  ampb   = (float*) alloc((size_t)N_NODES*4);
  float*  attb   = (float*) alloc((size_t)N_NODES*4);
  float*  h      = (float*) alloc((size_t)N_NODES*HID*4);
  float*  H3     = (float*) alloc((size_t)3*N_NODES*HID*4);   // H1 | H2 | Yh
  float*  Yamt   = (float*) alloc((size_t)N_NODES*384*4);
  float*  BW3all = (float*) alloc((size_t)NLAYERS*512*4);
  float*  tb     = (float*) alloc((size_t)N_NODES*HID*4);
  unsigned short* whi  = (unsigned short*)alloc((size_t)NLAYERS*262144*2);
  unsigned short* wlo  = (unsigned short*)alloc((size_t)NLAYERS*262144*2);
  unsigned short* h16h = (unsigned short*)alloc((size_t)NPAD*128*2);
  unsigned short* h16l = (unsigned short*)alloc((size_t)NPAD*128*2);
  unsigned short* aggh = (unsigned short*)alloc((size_t)NPAD*512*2);
  unsigned short* aggl = (unsigned short*)alloc((size_t)NPAD*512*2);
  float*  bnpart = (float*) alloc((size_t)MB64*256*4);
  float*  mu     = (float*) alloc(128*4);
  float*  rstd   = (float*) alloc(128*4);

  // zero deg + cursor: cursor is 256B-aligned after deg, so cover the full span
  hipMemsetAsync(deg, 0, (size_t)((char*)cursor - (char*)deg) + (size_t)N_NODES*4, stream);
  k_count<<<(N_EDGES+255)/256, 256, 0, stream>>>(dstI, deg);
  k_scan1<<<SCANB, 1024, 0, stream>>>(deg, excl, btot);
  k_scan2<<<SCANB, 1024, 0, stream>>>(deg, excl, btot, off, invd, ampb, attb);
  k_fill<<<(N_EDGES+255)/256, 256, 0, stream>>>(srcI, dstI, eattr, off, cursor, srcS, eaS);
  k_goff<<<1, 512, 0, stream>>>(batch, goff);
  k_hinit<<<(N_NODES*32+255)/256, 256, 0, stream>>>(x, atom_emb, h, h16h, h16l);
  k_wt<<<dim3(32, NLAYERS*7), 256, 0, stream>>>(pre_W, post_W, mix_W, whi, wlo);
  k_bondall<<<NLAYERS, 512, 0, stream>>>(bond_emb, pre_W, pre_b, BW3all);

  float* H1 = H3;
  float* H2 = H3 + (size_t)N_NODES*HID;
  float* Yh = H3 + (size_t)2*N_NODES*HID;
  for (int l = 0; l < NLAYERS; ++l){
    const unsigned short* whl = whi + (size_t)l*262144;
    const unsigned short* wll = wlo + (size_t)l*262144;
    // triple head GEMM on h16: H1, H2, Yh
    k_mf16<0><<<MB64*3, 256, 0, stream>>>(whl, wll, h16h, h16l, H3);
    // fused edge message + aggregation -> agg16 planes
    k_fusedagg<<<N_NODES/8, 256, 0, stream>>>(H1, H2, BW3all + (size_t)l*512,
        srcS, eaS, off, invd, aggh, aggl);
    // agg GEMM: Yamt = agg @ [W_a | W_m | W_t]
    k_mf16<1><<<MB64*3, 256, 0, stream>>>(whl + 49152, wll + 49152, aggh, aggl, Yamt);
    // mix with fused combine + BN partials
    k_mix<<<MB64, 256, 0, stream>>>(whl + 245760, wll + 245760,
        Yh, Yamt, ampb, attb, post_b + (size_t)l*128, mix_b + (size_t)l*128,
        snorm, tb, bnpart);
    k_bnfinal<<<1, 512, 0, stream>>>(bnpart, mu, rstd);
    k_apply<<<(N_NODES*32+255)/256, 256, 0, stream>>>(tb, mu, rstd,
        bn_g + (size_t)l*128, bn_b + (size_t)l*128, h, h16h, h16l);
  }

  k_poolread<<<N_GRAPHS, 128, 0, stream>>>(goff, h, rW1, rb1, rW2, rb2, rW3, rb3, outp);
}